// Round 2
// baseline (1021.660 us; speedup 1.0000x reference)
//
#include <hip/hip_runtime.h>
#include <hip/hip_bf16.h>
#include <math.h>
#include <stdint.h>

#define HID 256
#define HEADS 8
#define BN_EPS 1e-5f
#define NEG 0.2f
#define CAP 192      // max edges cached in LDS per node (Poisson(16) graph: never exceeded; fallback exists)
#define SCSTR 196    // row stride for sc_lds: 196%32==4 -> 8 heads map to distinct banks

__device__ __forceinline__ float lrelu(float x) { return x > 0.f ? x : NEG * x; }
__device__ __forceinline__ float eluf(float x)  { return x > 0.f ? x : expm1f(x); }

// ---------------- CSR build ----------------

__global__ __launch_bounds__(256) void degree_kernel(const int* __restrict__ ei,
                                                     int* __restrict__ deg,
                                                     int E, int EE) {
    int e = blockIdx.x * 256 + threadIdx.x;
    if (e >= EE) return;
    int d = (e < E) ? ei[E + e] : (e - E);
    atomicAdd(&deg[d], 1);
}

__global__ __launch_bounds__(1024) void scan_kernel(const int* __restrict__ deg,
                                                    int* __restrict__ offs, int N) {
    __shared__ int part[1024];
    int t = threadIdx.x;
    int chunk = (N + 1023) >> 10;
    int c0 = t * chunk;
    int c1 = min(c0 + chunk, N);
    int s = 0;
    for (int j = c0; j < c1; ++j) s += deg[j];
    part[t] = s;
    __syncthreads();
    for (int d = 1; d < 1024; d <<= 1) {
        int vv = (t >= d) ? part[t - d] : 0;
        __syncthreads();
        part[t] += vv;
        __syncthreads();
    }
    int run = part[t] - s;
    for (int j = c0; j < c1; ++j) { offs[j] = run; run += deg[j]; }
    if (t == 1023) offs[N] = part[1023];
}

__global__ __launch_bounds__(256) void scatter_kernel(const int* __restrict__ ei,
                                                      const int* __restrict__ offs,
                                                      int* __restrict__ cur,
                                                      int* __restrict__ csr_src,
                                                      int E, int EE) {
    int e = blockIdx.x * 256 + threadIdx.x;
    if (e >= EE) return;
    int s = (e < E) ? ei[e] : (e - E);
    int d = (e < E) ? ei[E + e] : (e - E);
    int pos = offs[d] + atomicAdd(&cur[d], 1);
    csr_src[pos] = s;
}

// ---------------- BN-fold precompute: W' = s .* W ; c = (b - m.*s) @ W ----------------

__global__ __launch_bounds__(256) void fold_w_kernel(const float* __restrict__ W,
                                                     const float* __restrict__ g,
                                                     const float* __restrict__ b,
                                                     const float* __restrict__ m,
                                                     const float* __restrict__ v,
                                                     float* __restrict__ Wp) {
    int k = blockIdx.x;
    int j = threadIdx.x;
    float s = g[k] * rsqrtf(v[k] + BN_EPS);
    Wp[(size_t)k * HID + j] = W[(size_t)k * HID + j] * s;
}

__global__ __launch_bounds__(256) void fold_c_kernel(const float* __restrict__ W,
                                                     const float* __restrict__ g,
                                                     const float* __restrict__ b,
                                                     const float* __restrict__ m,
                                                     const float* __restrict__ v,
                                                     float* __restrict__ cvec, int K) {
    int j = threadIdx.x;
    float acc = 0.f;
    for (int k = 0; k < K; ++k) {
        float s = g[k] * rsqrtf(v[k] + BN_EPS);
        acc = fmaf(b[k] - m[k] * s, W[(size_t)k * HID + j], acc);
    }
    cvec[j] = acc;
}

// ---------------- GEMM: h = in @ W' + c ; s_src/s_dst dots ; h stored bf16 ----------------
// Row activations are wave-uniform -> scalar (s_load) reads; no LDS in the FMA loop.
template <int K>
__global__ __launch_bounds__(256) void gemm_kernel(
    const float* __restrict__ in, const float* __restrict__ Wp,
    const float* __restrict__ cvec,
    const float* __restrict__ a_src, const float* __restrict__ a_dst,
    __hip_bfloat16* __restrict__ h, float* __restrict__ s_src,
    float* __restrict__ s_dst, int N) {
    const int NPB = 32;
    int tid = threadIdx.x;
    int base = blockIdx.x * NPB;

    float cv = cvec[tid];
    float acc[NPB];
#pragma unroll
    for (int i = 0; i < NPB; ++i) acc[i] = cv;

    for (int k = 0; k < K; k += 4) {
        float w0 = Wp[(size_t)(k + 0) * HID + tid];
        float w1 = Wp[(size_t)(k + 1) * HID + tid];
        float w2 = Wp[(size_t)(k + 2) * HID + tid];
        float w3 = Wp[(size_t)(k + 3) * HID + tid];
#pragma unroll
        for (int i = 0; i < NPB; ++i) {
            int node = min(base + i, N - 1);           // uniform -> scalar loads
            float4 r = *(const float4*)&in[(size_t)node * K + k];
            acc[i] = fmaf(r.x, w0, acc[i]);
            acc[i] = fmaf(r.y, w1, acc[i]);
            acc[i] = fmaf(r.z, w2, acc[i]);
            acc[i] = fmaf(r.w, w3, acc[i]);
        }
    }

    float as = a_src[tid], ad = a_dst[tid];
#pragma unroll
    for (int i = 0; i < NPB; ++i) {
        int node = base + i;
        if (node < N) h[(size_t)node * HID + tid] = __float2bfloat16(acc[i]);
        float vs = acc[i] * as;
        float vd = acc[i] * ad;
#pragma unroll
        for (int msk = 16; msk >= 1; msk >>= 1) {
            vs += __shfl_xor(vs, msk);
            vd += __shfl_xor(vd, msk);
        }
        if ((tid & 31) == 0 && node < N) {
            s_src[node * HEADS + (tid >> 5)] = vs;
            s_dst[node * HEADS + (tid >> 5)] = vd;
        }
    }
}

// ---------------- per-dst segment softmax + aggregation + bias + ELU ----------------
__global__ __launch_bounds__(256) void agg_kernel(
    const __hip_bfloat16* __restrict__ h, const float* __restrict__ s_src,
    const float* __restrict__ s_dst, const int* __restrict__ offs,
    const int* __restrict__ csr_src, const float* __restrict__ bias,
    float* __restrict__ outp, int N) {
    int vtx = blockIdx.x;
    int beg = offs[vtx], end = offs[vtx + 1];
    int deg = end - beg;
    __shared__ float sc_lds[HEADS * SCSTR];   // scores then alphas, [head][e]
    __shared__ int   u_lds[CAP];
    __shared__ float mxs[HEADS], invs[HEADS];
    int tid = threadIdx.x;
    int head = tid >> 5, el = tid & 31;
    float sdv = s_dst[vtx * HEADS + head];

    // pass 1: online max/sum per head; cache u and raw scores in LDS
    float mval = -3.0e38f, sval = 0.f;
    for (int e = el; e < deg; e += 32) {
        int u = csr_src[beg + e];
        if (head == 0 && e < CAP) u_lds[e] = u;
        float sc = lrelu(s_src[u * HEADS + head] + sdv);
        if (e < CAP) sc_lds[head * SCSTR + e] = sc;
        float nm = fmaxf(mval, sc);
        sval = sval * __expf(mval - nm) + __expf(sc - nm);
        mval = nm;
    }
#pragma unroll
    for (int msk = 16; msk >= 1; msk >>= 1) {
        float om = __shfl_xor(mval, msk);
        float os = __shfl_xor(sval, msk);
        float nm = fmaxf(mval, om);
        sval = sval * __expf(mval - nm) + os * __expf(om - nm);
        mval = nm;
    }
    if (el == 0) { mxs[head] = mval; invs[head] = 1.f / sval; }
    __syncthreads();

    // normalize scores -> alphas, each (edge,head) exactly once
    int dc = min(deg, CAP);
    for (int idx = tid; idx < dc * HEADS; idx += 256) {
        int e = idx >> 3, hh = idx & 7;
        float scv = sc_lds[hh * SCSTR + e];
        sc_lds[hh * SCSTR + e] = __expf(scv - mxs[hh]) * invs[hh];
    }
    __syncthreads();

    // pass 2: pure weighted gather; thread owns column tid
    float acc = 0.f;
#pragma unroll 4
    for (int e = 0; e < dc; ++e) {
        int u = u_lds[e];
        float al = sc_lds[head * SCSTR + e];
        float hv = __bfloat162float(h[(size_t)u * HID + tid]);
        acc = fmaf(al, hv, acc);
    }
    if (deg > CAP) {  // fallback (never for this graph, correctness for any)
        float mh = mxs[head], inv = invs[head];
        for (int e = CAP; e < deg; ++e) {
            int u = csr_src[beg + e];
            float sc = lrelu(s_src[u * HEADS + head] + sdv);
            float al = __expf(sc - mh) * inv;
            acc = fmaf(al, __bfloat162float(h[(size_t)u * HID + tid]), acc);
        }
    }
    outp[(size_t)vtx * HID + tid] = eluf(acc + bias[tid]);
}

// ---------------- head: bn3 affine + skip GEMM + p1/relu + p2 ----------------
__global__ __launch_bounds__(256) void final_kernel(
    const float* __restrict__ t_in, const float* __restrict__ x,
    const float* __restrict__ g3, const float* __restrict__ b3,
    const float* __restrict__ m3, const float* __restrict__ v3,
    const float* __restrict__ skip_W, const float* __restrict__ skip_b,
    const float* __restrict__ p1_W, const float* __restrict__ p1_b,
    const float* __restrict__ p2_W, const float* __restrict__ p2_b,
    float* __restrict__ outp, int N) {
    const int NPB = 32;
    __shared__ float f3[NPB][HID + 1];
    __shared__ float xr[NPB][64];
    int tid = threadIdx.x;
    int base = blockIdx.x * NPB;

    for (int idx = tid; idx < NPB * 64; idx += 256) {
        int r = idx >> 6, k = idx & 63;
        int node = base + r;
        xr[r][k] = (node < N) ? x[(size_t)node * 64 + k] : 0.f;
    }
    __syncthreads();

    float acc[NPB];
#pragma unroll
    for (int i = 0; i < NPB; ++i) acc[i] = 0.f;
    for (int k = 0; k < 64; ++k) {
        float wv = skip_W[(size_t)k * HID + tid];
#pragma unroll
        for (int i = 0; i < NPB; ++i) acc[i] = fmaf(xr[i][k], wv, acc[i]);
    }

    float sc3 = g3[tid] * rsqrtf(v3[tid] + BN_EPS);
    float mm = m3[tid], b3v = b3[tid], sb = skip_b[tid];
    for (int i = 0; i < NPB; ++i) {
        int node = base + i;
        float t = 0.f;
        if (node < N) t = t_in[(size_t)node * HID + tid];   // already elu(agg2+b2)
        t = (t - mm) * sc3 + b3v;
        f3[i][tid] = t + acc[i] + sb;
    }
    __syncthreads();

    int node = tid >> 3, r = tid & 7;
    float po = 0.f;
#pragma unroll
    for (int q = 0; q < 4; ++q) {
        int j = q * 8 + r;
        float z = p1_b[j];
        for (int c = 0; c < HID; ++c) z = fmaf(f3[node][c], p1_W[c * 32 + j], z);
        z = fmaxf(z, 0.f);
        po = fmaf(z, p2_W[j], po);
    }
#pragma unroll
    for (int msk = 4; msk >= 1; msk >>= 1) po += __shfl_xor(po, msk);
    int gn = base + node;
    if (r == 0 && gn < N) outp[gn] = po + p2_b[0];
}

// ---------------- launch ----------------

extern "C" void kernel_launch(void* const* d_in, const int* in_sizes, int n_in,
                              void* d_out, int out_size, void* d_ws, size_t ws_size,
                              hipStream_t stream) {
    const float* x      = (const float*)d_in[0];
    const int*   ei     = (const int*)  d_in[1];
    const float* bn1_g  = (const float*)d_in[2];
    const float* bn1_b  = (const float*)d_in[3];
    const float* bn1_m  = (const float*)d_in[4];
    const float* bn1_v  = (const float*)d_in[5];
    const float* W1     = (const float*)d_in[6];
    const float* a1_src = (const float*)d_in[7];
    const float* a1_dst = (const float*)d_in[8];
    const float* b1     = (const float*)d_in[9];
    const float* bn2_g  = (const float*)d_in[10];
    const float* bn2_b  = (const float*)d_in[11];
    const float* bn2_m  = (const float*)d_in[12];
    const float* bn2_v  = (const float*)d_in[13];
    const float* W2     = (const float*)d_in[14];
    const float* a2_src = (const float*)d_in[15];
    const float* a2_dst = (const float*)d_in[16];
    const float* b2     = (const float*)d_in[17];
    const float* bn3_g  = (const float*)d_in[18];
    const float* bn3_b  = (const float*)d_in[19];
    const float* bn3_m  = (const float*)d_in[20];
    const float* bn3_v  = (const float*)d_in[21];
    const float* skip_W = (const float*)d_in[22];
    const float* skip_b = (const float*)d_in[23];
    const float* p1_W   = (const float*)d_in[24];
    const float* p1_b   = (const float*)d_in[25];
    const float* p2_W   = (const float*)d_in[26];
    const float* p2_b   = (const float*)d_in[27];

    int N = in_sizes[0] / 64;
    int E = in_sizes[1] / 2;
    int EE = E + N;

    uintptr_t w = (uintptr_t)d_ws;
    auto carve = [&](size_t bytes) -> void* {
        uintptr_t p = w;
        w += (bytes + 255) & ~(size_t)255;
        return (void*)p;
    };
    int*   deg  = (int*)carve((size_t)N * 4);
    int*   cur  = (int*)carve((size_t)N * 4);
    int*   offs = (int*)carve(((size_t)N + 1) * 4);
    int*   csr  = (int*)carve((size_t)EE * 4);
    float* ssrc = (float*)carve((size_t)N * HEADS * 4);
    float* sdst = (float*)carve((size_t)N * HEADS * 4);
    float* Wp1  = (float*)carve((size_t)64 * HID * 4);
    float* c1   = (float*)carve((size_t)HID * 4);
    float* Wp2  = (float*)carve((size_t)HID * HID * 4);
    float* c2   = (float*)carve((size_t)HID * 4);
    __hip_bfloat16* hbf = (__hip_bfloat16*)carve((size_t)N * HID * 2);
    float* tbuf = (float*)carve((size_t)N * HID * 4);

    hipMemsetAsync(deg, 0, (size_t)N * 4, stream);
    hipMemsetAsync(cur, 0, (size_t)N * 4, stream);

    // BN folds
    fold_w_kernel<<<64, 256, 0, stream>>>(W1, bn1_g, bn1_b, bn1_m, bn1_v, Wp1);
    fold_c_kernel<<<1, 256, 0, stream>>>(W1, bn1_g, bn1_b, bn1_m, bn1_v, c1, 64);
    fold_w_kernel<<<HID, 256, 0, stream>>>(W2, bn2_g, bn2_b, bn2_m, bn2_v, Wp2);
    fold_c_kernel<<<1, 256, 0, stream>>>(W2, bn2_g, bn2_b, bn2_m, bn2_v, c2, HID);

    // CSR
    int eblk = (EE + 255) / 256;
    degree_kernel<<<eblk, 256, 0, stream>>>(ei, deg, E, EE);
    scan_kernel<<<1, 1024, 0, stream>>>(deg, offs, N);
    scatter_kernel<<<eblk, 256, 0, stream>>>(ei, offs, cur, csr, E, EE);

    int gblk = (N + 31) / 32;
    // layer 1
    gemm_kernel<64><<<gblk, 256, 0, stream>>>(x, Wp1, c1, a1_src, a1_dst,
                                              hbf, ssrc, sdst, N);
    agg_kernel<<<N, 256, 0, stream>>>(hbf, ssrc, sdst, offs, csr, b1, tbuf, N);

    // layer 2
    gemm_kernel<HID><<<gblk, 256, 0, stream>>>(tbuf, Wp2, c2, a2_src, a2_dst,
                                               hbf, ssrc, sdst, N);
    agg_kernel<<<N, 256, 0, stream>>>(hbf, ssrc, sdst, offs, csr, b2, tbuf, N);

    // head
    final_kernel<<<gblk, 256, 0, stream>>>(
        tbuf, x, bn3_g, bn3_b, bn3_m, bn3_v, skip_W, skip_b,
        p1_W, p1_b, p2_W, p2_b, (float*)d_out, N);
}

// Round 3
// 788.524 us; speedup vs baseline: 1.2957x; 1.2957x over previous
//
#include <hip/hip_runtime.h>
#include <hip/hip_bf16.h>
#include <math.h>
#include <stdint.h>

#define HID 256
#define HEADS 8
#define BN_EPS 1e-5f
#define NEG 0.2f
#define CAP 192      // max edges cached in LDS per node
#define SCSTR 196

__device__ __forceinline__ float lrelu(float x) { return x > 0.f ? x : NEG * x; }
__device__ __forceinline__ float eluf(float x)  { return x > 0.f ? x : expm1f(x); }

// ---------------- CSR build ----------------

__global__ __launch_bounds__(256) void degree_kernel(const int* __restrict__ ei,
                                                     int* __restrict__ deg,
                                                     int E, int EE) {
    int e = blockIdx.x * 256 + threadIdx.x;
    if (e >= EE) return;
    int d = (e < E) ? ei[E + e] : (e - E);
    atomicAdd(&deg[d], 1);
}

__global__ __launch_bounds__(1024) void scan_kernel(const int* __restrict__ deg,
                                                    int* __restrict__ offs, int N) {
    __shared__ int part[1024];
    int t = threadIdx.x;
    int chunk = (N + 1023) >> 10;
    int c0 = t * chunk;
    int c1 = min(c0 + chunk, N);
    int s = 0;
    for (int j = c0; j < c1; ++j) s += deg[j];
    part[t] = s;
    __syncthreads();
    for (int d = 1; d < 1024; d <<= 1) {
        int vv = (t >= d) ? part[t - d] : 0;
        __syncthreads();
        part[t] += vv;
        __syncthreads();
    }
    int run = part[t] - s;
    for (int j = c0; j < c1; ++j) { offs[j] = run; run += deg[j]; }
    if (t == 1023) offs[N] = part[1023];
}

__global__ __launch_bounds__(256) void scatter_kernel(const int* __restrict__ ei,
                                                      const int* __restrict__ offs,
                                                      int* __restrict__ cur,
                                                      int* __restrict__ csr_src,
                                                      int E, int EE) {
    int e = blockIdx.x * 256 + threadIdx.x;
    if (e >= EE) return;
    int s = (e < E) ? ei[e] : (e - E);
    int d = (e < E) ? ei[E + e] : (e - E);
    int pos = offs[d] + atomicAdd(&cur[d], 1);
    csr_src[pos] = s;
}

// ---------------- BN-fold precompute: W' = s .* W ; c = (b - m.*s) @ W ----------------

__global__ __launch_bounds__(256) void fold_w_kernel(const float* __restrict__ W,
                                                     const float* __restrict__ g,
                                                     const float* __restrict__ v,
                                                     float* __restrict__ Wp) {
    int k = blockIdx.x;
    int j = threadIdx.x;
    float s = g[k] * rsqrtf(v[k] + BN_EPS);
    Wp[(size_t)k * HID + j] = W[(size_t)k * HID + j] * s;
}

__global__ __launch_bounds__(256) void fold_c_kernel(const float* __restrict__ W,
                                                     const float* __restrict__ g,
                                                     const float* __restrict__ b,
                                                     const float* __restrict__ m,
                                                     const float* __restrict__ v,
                                                     float* __restrict__ cvec, int K) {
    int j = threadIdx.x;
    float acc = 0.f;
    for (int k = 0; k < K; ++k) {
        float s = g[k] * rsqrtf(v[k] + BN_EPS);
        acc = fmaf(b[k] - m[k] * s, W[(size_t)k * HID + j], acc);
    }
    cvec[j] = acc;
}

// ---------------- tiled GEMM: h = in @ W' + c ; s dots ; h stored bf16 ----------------
// Block: 64 rows x 256 cols. Wave w: rows w*16..+15. Lane l: cols 4l..4l+3.
// A-chunk [64][64] in LDS (wave-uniform broadcast reads); W streamed float4 from L2.
template <int K>
__global__ __launch_bounds__(256) void gemm_kernel(
    const float* __restrict__ in, const float* __restrict__ Wp,
    const float* __restrict__ cvec,
    const float* __restrict__ a_src, const float* __restrict__ a_dst,
    __hip_bfloat16* __restrict__ h, float* __restrict__ s_src,
    float* __restrict__ s_dst, int N) {
    __shared__ float A[64 * 64];
    int tid = threadIdx.x;
    int w = tid >> 6, l = tid & 63;
    int base = blockIdx.x * 64;

    float4 cv = ((const float4*)cvec)[l];
    float4 acc[16];
#pragma unroll
    for (int i = 0; i < 16; ++i) acc[i] = cv;

    const float4* WpV = (const float4*)Wp;

    for (int kc = 0; kc < K; kc += 64) {
        // stage A[64][64]: thread -> row tid/4, 16-float quarter (tid&3)
        {
            int r = tid >> 2, q = tid & 3;
            int node = min(base + r, N - 1);
            const float4* srcp = (const float4*)&in[(size_t)node * K + kc + q * 16];
            float4* dstp = (float4*)&A[r * 64 + q * 16];
#pragma unroll
            for (int j = 0; j < 4; ++j) dstp[j] = srcp[j];
        }
        __syncthreads();

#pragma unroll 4
        for (int k4 = 0; k4 < 16; ++k4) {
            int kg = (kc + k4 * 4) * 64;  // float4-row index: k*256 floats / 4
            float4 w0 = WpV[kg + l];
            float4 w1 = WpV[kg + 64 + l];
            float4 w2 = WpV[kg + 128 + l];
            float4 w3 = WpV[kg + 192 + l];
#pragma unroll
            for (int i = 0; i < 16; ++i) {
                float4 a = *(const float4*)&A[(w * 16 + i) * 64 + k4 * 4];
                acc[i].x = fmaf(a.x, w0.x, acc[i].x);
                acc[i].y = fmaf(a.x, w0.y, acc[i].y);
                acc[i].z = fmaf(a.x, w0.z, acc[i].z);
                acc[i].w = fmaf(a.x, w0.w, acc[i].w);
                acc[i].x = fmaf(a.y, w1.x, acc[i].x);
                acc[i].y = fmaf(a.y, w1.y, acc[i].y);
                acc[i].z = fmaf(a.y, w1.z, acc[i].z);
                acc[i].w = fmaf(a.y, w1.w, acc[i].w);
                acc[i].x = fmaf(a.z, w2.x, acc[i].x);
                acc[i].y = fmaf(a.z, w2.y, acc[i].y);
                acc[i].z = fmaf(a.z, w2.z, acc[i].z);
                acc[i].w = fmaf(a.z, w2.w, acc[i].w);
                acc[i].x = fmaf(a.w, w3.x, acc[i].x);
                acc[i].y = fmaf(a.w, w3.y, acc[i].y);
                acc[i].z = fmaf(a.w, w3.z, acc[i].z);
                acc[i].w = fmaf(a.w, w3.w, acc[i].w);
            }
        }
        __syncthreads();
    }

    // epilogue: bf16 h store (packed 8B) + attention dots (3-hop shfl within 8 lanes)
    float4 as = ((const float4*)a_src)[l];
    float4 ad = ((const float4*)a_dst)[l];
#pragma unroll
    for (int i = 0; i < 16; ++i) {
        int node = base + w * 16 + i;
        float4 a4 = acc[i];
        if (node < N) {
            union { ushort4 u; __hip_bfloat16 bv[4]; } pk;
            pk.bv[0] = __float2bfloat16(a4.x);
            pk.bv[1] = __float2bfloat16(a4.y);
            pk.bv[2] = __float2bfloat16(a4.z);
            pk.bv[3] = __float2bfloat16(a4.w);
            *(ushort4*)&h[(size_t)node * HID + 4 * l] = pk.u;
        }
        float vs = a4.x * as.x + a4.y * as.y + a4.z * as.z + a4.w * as.w;
        float vd = a4.x * ad.x + a4.y * ad.y + a4.z * ad.z + a4.w * ad.w;
        vs += __shfl_xor(vs, 4); vs += __shfl_xor(vs, 2); vs += __shfl_xor(vs, 1);
        vd += __shfl_xor(vd, 4); vd += __shfl_xor(vd, 2); vd += __shfl_xor(vd, 1);
        if ((l & 7) == 0 && node < N) {
            s_src[node * HEADS + (l >> 3)] = vs;
            s_dst[node * HEADS + (l >> 3)] = vd;
        }
    }
}

// ---------------- per-dst segment softmax + aggregation + bias + ELU ----------------
__global__ __launch_bounds__(256) void agg_kernel(
    const __hip_bfloat16* __restrict__ h, const float* __restrict__ s_src,
    const float* __restrict__ s_dst, const int* __restrict__ offs,
    const int* __restrict__ csr_src, const float* __restrict__ bias,
    float* __restrict__ outp, int N) {
    int vtx = blockIdx.x;
    int beg = offs[vtx], end = offs[vtx + 1];
    int deg = end - beg;
    __shared__ float sc_lds[HEADS * SCSTR];
    __shared__ int   u_lds[CAP];
    __shared__ float mxs[HEADS], invs[HEADS];
    int tid = threadIdx.x;
    int head = tid >> 5, el = tid & 31;
    float sdv = s_dst[vtx * HEADS + head];

    float mval = -3.0e38f, sval = 0.f;
    for (int e = el; e < deg; e += 32) {
        int u = csr_src[beg + e];
        if (head == 0 && e < CAP) u_lds[e] = u;
        float sc = lrelu(s_src[u * HEADS + head] + sdv);
        if (e < CAP) sc_lds[head * SCSTR + e] = sc;
        float nm = fmaxf(mval, sc);
        sval = sval * __expf(mval - nm) + __expf(sc - nm);
        mval = nm;
    }
#pragma unroll
    for (int msk = 16; msk >= 1; msk >>= 1) {
        float om = __shfl_xor(mval, msk);
        float os = __shfl_xor(sval, msk);
        float nm = fmaxf(mval, om);
        sval = sval * __expf(mval - nm) + os * __expf(om - nm);
        mval = nm;
    }
    if (el == 0) { mxs[head] = mval; invs[head] = 1.f / sval; }
    __syncthreads();

    int dc = min(deg, CAP);
    for (int idx = tid; idx < dc * HEADS; idx += 256) {
        int e = idx >> 3, hh = idx & 7;
        float scv = sc_lds[hh * SCSTR + e];
        sc_lds[hh * SCSTR + e] = __expf(scv - mxs[hh]) * invs[hh];
    }
    __syncthreads();

    float acc = 0.f;
#pragma unroll 4
    for (int e = 0; e < dc; ++e) {
        int u = u_lds[e];
        float al = sc_lds[head * SCSTR + e];
        float hv = __bfloat162float(h[(size_t)u * HID + tid]);
        acc = fmaf(al, hv, acc);
    }
    if (deg > CAP) {
        float mh = mxs[head], inv = invs[head];
        for (int e = CAP; e < deg; ++e) {
            int u = csr_src[beg + e];
            float sc = lrelu(s_src[u * HEADS + head] + sdv);
            float al = __expf(sc - mh) * inv;
            acc = fmaf(al, __bfloat162float(h[(size_t)u * HID + tid]), acc);
        }
    }
    outp[(size_t)vtx * HID + tid] = eluf(acc + bias[tid]);
}

// ---------------- head: bn3 affine + skip GEMM + p1/relu + p2 ----------------
__global__ __launch_bounds__(256) void final_kernel(
    const float* __restrict__ t_in, const float* __restrict__ x,
    const float* __restrict__ g3, const float* __restrict__ b3,
    const float* __restrict__ m3, const float* __restrict__ v3,
    const float* __restrict__ skip_W, const float* __restrict__ skip_b,
    const float* __restrict__ p1_W, const float* __restrict__ p1_b,
    const float* __restrict__ p2_W, const float* __restrict__ p2_b,
    float* __restrict__ outp, int N) {
    const int NPB = 32;
    __shared__ float f3[NPB][HID + 1];
    __shared__ float xr[NPB][64];
    int tid = threadIdx.x;
    int base = blockIdx.x * NPB;

    for (int idx = tid; idx < NPB * 64; idx += 256) {
        int r = idx >> 6, k = idx & 63;
        int node = base + r;
        xr[r][k] = (node < N) ? x[(size_t)node * 64 + k] : 0.f;
    }
    __syncthreads();

    float acc[NPB];
#pragma unroll
    for (int i = 0; i < NPB; ++i) acc[i] = 0.f;
    for (int k = 0; k < 64; ++k) {
        float wv = skip_W[(size_t)k * HID + tid];
#pragma unroll
        for (int i = 0; i < NPB; ++i) acc[i] = fmaf(xr[i][k], wv, acc[i]);
    }

    float sc3 = g3[tid] * rsqrtf(v3[tid] + BN_EPS);
    float mm = m3[tid], b3v = b3[tid], sb = skip_b[tid];
    for (int i = 0; i < NPB; ++i) {
        int node = base + i;
        float t = 0.f;
        if (node < N) t = t_in[(size_t)node * HID + tid];
        t = (t - mm) * sc3 + b3v;
        f3[i][tid] = t + acc[i] + sb;
    }
    __syncthreads();

    int node = tid >> 3, r = tid & 7;
    float po = 0.f;
#pragma unroll
    for (int q = 0; q < 4; ++q) {
        int j = q * 8 + r;
        float z = p1_b[j];
        for (int c = 0; c < HID; ++c) z = fmaf(f3[node][c], p1_W[c * 32 + j], z);
        z = fmaxf(z, 0.f);
        po = fmaf(z, p2_W[j], po);
    }
#pragma unroll
    for (int msk = 4; msk >= 1; msk >>= 1) po += __shfl_xor(po, msk);
    int gn = base + node;
    if (r == 0 && gn < N) outp[gn] = po + p2_b[0];
}

// ---------------- launch ----------------

extern "C" void kernel_launch(void* const* d_in, const int* in_sizes, int n_in,
                              void* d_out, int out_size, void* d_ws, size_t ws_size,
                              hipStream_t stream) {
    const float* x      = (const float*)d_in[0];
    const int*   ei     = (const int*)  d_in[1];
    const float* bn1_g  = (const float*)d_in[2];
    const float* bn1_b  = (const float*)d_in[3];
    const float* bn1_m  = (const float*)d_in[4];
    const float* bn1_v  = (const float*)d_in[5];
    const float* W1     = (const float*)d_in[6];
    const float* a1_src = (const float*)d_in[7];
    const float* a1_dst = (const float*)d_in[8];
    const float* b1     = (const float*)d_in[9];
    const float* bn2_g  = (const float*)d_in[10];
    const float* bn2_b  = (const float*)d_in[11];
    const float* bn2_m  = (const float*)d_in[12];
    const float* bn2_v  = (const float*)d_in[13];
    const float* W2     = (const float*)d_in[14];
    const float* a2_src = (const float*)d_in[15];
    const float* a2_dst = (const float*)d_in[16];
    const float* b2     = (const float*)d_in[17];
    const float* bn3_g  = (const float*)d_in[18];
    const float* bn3_b  = (const float*)d_in[19];
    const float* bn3_m  = (const float*)d_in[20];
    const float* bn3_v  = (const float*)d_in[21];
    const float* skip_W = (const float*)d_in[22];
    const float* skip_b = (const float*)d_in[23];
    const float* p1_W   = (const float*)d_in[24];
    const float* p1_b   = (const float*)d_in[25];
    const float* p2_W   = (const float*)d_in[26];
    const float* p2_b   = (const float*)d_in[27];

    int N = in_sizes[0] / 64;
    int E = in_sizes[1] / 2;
    int EE = E + N;

    uintptr_t w = (uintptr_t)d_ws;
    auto carve = [&](size_t bytes) -> void* {
        uintptr_t p = w;
        w += (bytes + 255) & ~(size_t)255;
        return (void*)p;
    };
    int*   deg  = (int*)carve((size_t)N * 4);
    int*   cur  = (int*)carve((size_t)N * 4);
    int*   offs = (int*)carve(((size_t)N + 1) * 4);
    int*   csr  = (int*)carve((size_t)EE * 4);
    float* ssrc = (float*)carve((size_t)N * HEADS * 4);
    float* sdst = (float*)carve((size_t)N * HEADS * 4);
    float* Wp1  = (float*)carve((size_t)64 * HID * 4);
    float* c1   = (float*)carve((size_t)HID * 4);
    float* Wp2  = (float*)carve((size_t)HID * HID * 4);
    float* c2   = (float*)carve((size_t)HID * 4);
    __hip_bfloat16* hbf = (__hip_bfloat16*)carve((size_t)N * HID * 2);
    float* tbuf = (float*)carve((size_t)N * HID * 4);

    hipMemsetAsync(deg, 0, (size_t)N * 4, stream);
    hipMemsetAsync(cur, 0, (size_t)N * 4, stream);

    // BN folds
    fold_w_kernel<<<64, 256, 0, stream>>>(W1, bn1_g, bn1_v, Wp1);
    fold_c_kernel<<<1, 256, 0, stream>>>(W1, bn1_g, bn1_b, bn1_m, bn1_v, c1, 64);
    fold_w_kernel<<<HID, 256, 0, stream>>>(W2, bn2_g, bn2_v, Wp2);
    fold_c_kernel<<<1, 256, 0, stream>>>(W2, bn2_g, bn2_b, bn2_m, bn2_v, c2, HID);

    // CSR
    int eblk = (EE + 255) / 256;
    degree_kernel<<<eblk, 256, 0, stream>>>(ei, deg, E, EE);
    scan_kernel<<<1, 1024, 0, stream>>>(deg, offs, N);
    scatter_kernel<<<eblk, 256, 0, stream>>>(ei, offs, cur, csr, E, EE);

    int gblk = (N + 63) / 64;
    // layer 1
    gemm_kernel<64><<<gblk, 256, 0, stream>>>(x, Wp1, c1, a1_src, a1_dst,
                                              hbf, ssrc, sdst, N);
    agg_kernel<<<N, 256, 0, stream>>>(hbf, ssrc, sdst, offs, csr, b1, tbuf, N);

    // layer 2
    gemm_kernel<HID><<<gblk, 256, 0, stream>>>(tbuf, Wp2, c2, a2_src, a2_dst,
                                               hbf, ssrc, sdst, N);
    agg_kernel<<<N, 256, 0, stream>>>(hbf, ssrc, sdst, offs, csr, b2, tbuf, N);

    // head
    int fblk = (N + 31) / 32;
    final_kernel<<<fblk, 256, 0, stream>>>(
        tbuf, x, bn3_g, bn3_b, bn3_m, bn3_v, skip_W, skip_b,
        p1_W, p1_b, p2_W, p2_b, (float*)d_out, N);
}

// Round 4
// 653.534 us; speedup vs baseline: 1.5633x; 1.2066x over previous
//
#include <hip/hip_runtime.h>
#include <hip/hip_bf16.h>
#include <math.h>
#include <stdint.h>

#define HID 256
#define HEADS 8
#define BN_EPS 1e-5f
#define NEG 0.2f
#define CAP 192
#define SCSTR 196

typedef short sv8  __attribute__((ext_vector_type(8)));
typedef float f32x4 __attribute__((ext_vector_type(4)));

__device__ __forceinline__ float lrelu(float x) { return x > 0.f ? x : NEG * x; }
__device__ __forceinline__ float eluf(float x)  { return x > 0.f ? x : expm1f(x); }

__device__ __forceinline__ unsigned short f2bf(float f) {
    unsigned int u = __float_as_uint(f);
    u = (u + 0x7fffu + ((u >> 16) & 1u)) >> 16;   // RNE
    return (unsigned short)u;
}
__device__ __forceinline__ unsigned int pk2(float lo, float hi) {
    return (unsigned int)f2bf(lo) | ((unsigned int)f2bf(hi) << 16);
}

// ---------------- CSR build ----------------

__global__ __launch_bounds__(256) void degree_kernel(const int* __restrict__ ei,
                                                     int* __restrict__ deg,
                                                     int E, int EE) {
    int e = blockIdx.x * 256 + threadIdx.x;
    if (e >= EE) return;
    int d = (e < E) ? ei[E + e] : (e - E);
    atomicAdd(&deg[d], 1);
}

__global__ __launch_bounds__(1024) void scan_kernel(const int* __restrict__ deg,
                                                    int* __restrict__ offs, int N) {
    __shared__ int part[1024];
    int t = threadIdx.x;
    int chunk = (N + 1023) >> 10;
    int c0 = t * chunk;
    int c1 = min(c0 + chunk, N);
    int s = 0;
    for (int j = c0; j < c1; ++j) s += deg[j];
    part[t] = s;
    __syncthreads();
    for (int d = 1; d < 1024; d <<= 1) {
        int vv = (t >= d) ? part[t - d] : 0;
        __syncthreads();
        part[t] += vv;
        __syncthreads();
    }
    int run = part[t] - s;
    for (int j = c0; j < c1; ++j) { offs[j] = run; run += deg[j]; }
    if (t == 1023) offs[N] = part[1023];
}

__global__ __launch_bounds__(256) void scatter_kernel(const int* __restrict__ ei,
                                                      const int* __restrict__ offs,
                                                      int* __restrict__ cur,
                                                      int* __restrict__ csr_src,
                                                      int E, int EE) {
    int e = blockIdx.x * 256 + threadIdx.x;
    if (e >= EE) return;
    int s = (e < E) ? ei[e] : (e - E);
    int d = (e < E) ? ei[E + e] : (e - E);
    int pos = offs[d] + atomicAdd(&cur[d], 1);
    csr_src[pos] = s;
}

// ---------------- W' fragment pregen: BN-scale + bf16 + MFMA A-operand order ----
// frag layout: tile = ktile*16 + coltile; lane l holds W'[k0+8*(l>>4)+j][c0+(l&15)]
__global__ __launch_bounds__(64) void wfrag_kernel(const float* __restrict__ W,
                                                   const float* __restrict__ g,
                                                   const float* __restrict__ v,
                                                   unsigned short* __restrict__ frag) {
    int tile = blockIdx.x;
    int ct = tile & 15, kt = tile >> 4;
    int l = threadIdx.x;
    int c = ct * 16 + (l & 15);
    int k0 = kt * 32 + (l >> 4) * 8;
    float val[8];
#pragma unroll
    for (int j = 0; j < 8; ++j) {
        float s = g[k0 + j] * rsqrtf(v[k0 + j] + BN_EPS);
        val[j] = W[(size_t)(k0 + j) * HID + c] * s;
    }
    uint4 o;
    o.x = pk2(val[0], val[1]);
    o.y = pk2(val[2], val[3]);
    o.z = pk2(val[4], val[5]);
    o.w = pk2(val[6], val[7]);
    *(uint4*)&frag[((size_t)tile * 64 + l) * 8] = o;
}

__global__ __launch_bounds__(256) void fold_c_kernel(const float* __restrict__ W,
                                                     const float* __restrict__ g,
                                                     const float* __restrict__ b,
                                                     const float* __restrict__ m,
                                                     const float* __restrict__ v,
                                                     float* __restrict__ cvec, int K) {
    int j = threadIdx.x;
    float acc = 0.f;
    for (int k = 0; k < K; ++k) {
        float s = g[k] * rsqrtf(v[k] + BN_EPS);
        acc = fmaf(b[k] - m[k] * s, W[(size_t)k * HID + j], acc);
    }
    cvec[j] = acc;
}

// ---------------- MFMA GEMM (swapped): D[wcol][node] = W'^T-op x X-op ----------------
// Block: 64 nodes x 256 wcols, 4 waves; wave w owns wcols 64w..64w+63.
// A-op = wfrag (global, coalesced b128). B-op = X staged bf16 in LDS, fragment order.
template <int K>
__global__ __launch_bounds__(256) void gemm_mfma(
    const float* __restrict__ in, const unsigned short* __restrict__ wfrag,
    const float* __restrict__ cvec,
    const float* __restrict__ a_src, const float* __restrict__ a_dst,
    unsigned short* __restrict__ h, float* __restrict__ s_src,
    float* __restrict__ s_dst, int N) {
    constexpr int KT = K / 32;       // k-tiles
    constexpr int OPR = K / 8;       // octets per row
    __shared__ unsigned short xfrag[KT * 4 * 64 * 8];
    int tid = threadIdx.x;
    int w = tid >> 6, l = tid & 63;
    int gg = l >> 4, li = l & 15;
    int base = blockIdx.x * 64;

    // stage X -> bf16 fragments in LDS
    for (int id = tid; id < 64 * OPR; id += 256) {
        int r = id / OPR, o = id % OPR;
        int node = min(base + r, N - 1);
        const float* p = &in[(size_t)node * K + o * 8];
        float4 f0 = *(const float4*)p;
        float4 f1 = *(const float4*)(p + 4);
        uint4 pkv;
        pkv.x = pk2(f0.x, f0.y);
        pkv.y = pk2(f0.z, f0.w);
        pkv.z = pk2(f1.x, f1.y);
        pkv.w = pk2(f1.z, f1.w);
        int kt = o >> 2, og = o & 3, nt = r >> 4;
        *(uint4*)&xfrag[(((kt * 4 + nt) * 64) + (r & 15) + 16 * og) * 8] = pkv;
    }
    __syncthreads();

    f32x4 acc[4][4];
#pragma unroll
    for (int mm = 0; mm < 4; ++mm) {
        float4 cv = *(const float4*)&cvec[64 * w + 16 * mm + 4 * gg];
#pragma unroll
        for (int nn = 0; nn < 4; ++nn) {
            acc[mm][nn][0] = cv.x; acc[mm][nn][1] = cv.y;
            acc[mm][nn][2] = cv.z; acc[mm][nn][3] = cv.w;
        }
    }

    for (int ks = 0; ks < KT; ++ks) {
        sv8 a[4], b[4];
#pragma unroll
        for (int mm = 0; mm < 4; ++mm)
            a[mm] = *(const sv8*)&wfrag[((size_t)(ks * 16 + w * 4 + mm) * 64 + l) * 8];
#pragma unroll
        for (int nn = 0; nn < 4; ++nn)
            b[nn] = *(const sv8*)&xfrag[((ks * 4 + nn) * 64 + l) * 8];
#pragma unroll
        for (int mm = 0; mm < 4; ++mm)
#pragma unroll
            for (int nn = 0; nn < 4; ++nn)
                acc[mm][nn] = __builtin_amdgcn_mfma_f32_16x16x32_bf16(
                    a[mm], b[nn], acc[mm][nn], 0, 0, 0);
    }

    // epilogue: h (packed 8B) + per-head attention dots
    float svp[4][2], sdp[4][2];
#pragma unroll
    for (int nn = 0; nn < 4; ++nn) { svp[nn][0]=0.f; svp[nn][1]=0.f; sdp[nn][0]=0.f; sdp[nn][1]=0.f; }

#pragma unroll
    for (int mm = 0; mm < 4; ++mm) {
        int cb = 64 * w + 16 * mm + 4 * gg;
        float4 as4 = *(const float4*)&a_src[cb];
        float4 ad4 = *(const float4*)&a_dst[cb];
        int hp = mm >> 1;
#pragma unroll
        for (int nn = 0; nn < 4; ++nn) {
            f32x4 A = acc[mm][nn];
            svp[nn][hp] += A[0]*as4.x + A[1]*as4.y + A[2]*as4.z + A[3]*as4.w;
            sdp[nn][hp] += A[0]*ad4.x + A[1]*ad4.y + A[2]*ad4.z + A[3]*ad4.w;
            int node = base + 16 * nn + li;
            if (node < N) {
                ushort4 pkv;
                pkv.x = f2bf(A[0]); pkv.y = f2bf(A[1]);
                pkv.z = f2bf(A[2]); pkv.w = f2bf(A[3]);
                *(ushort4*)&h[(size_t)node * HID + cb] = pkv;
            }
        }
    }
    // sum the 4 g-groups (lanes l, l^16, l^32, l^48 share node, differ in wcol set)
#pragma unroll
    for (int nn = 0; nn < 4; ++nn)
#pragma unroll
        for (int hp = 0; hp < 2; ++hp) {
            svp[nn][hp] += __shfl_xor(svp[nn][hp], 16);
            svp[nn][hp] += __shfl_xor(svp[nn][hp], 32);
            sdp[nn][hp] += __shfl_xor(sdp[nn][hp], 16);
            sdp[nn][hp] += __shfl_xor(sdp[nn][hp], 32);
        }
    if (gg == 0) {
#pragma unroll
        for (int nn = 0; nn < 4; ++nn) {
            int node = base + 16 * nn + li;
            if (node < N) {
#pragma unroll
                for (int hp = 0; hp < 2; ++hp) {
                    s_src[node * HEADS + 2 * w + hp] = svp[nn][hp];
                    s_dst[node * HEADS + 2 * w + hp] = sdp[nn][hp];
                }
            }
        }
    }
}

// ---------------- per-dst segment softmax + aggregation + bias + ELU ----------------
__global__ __launch_bounds__(256) void agg_kernel(
    const __hip_bfloat16* __restrict__ h, const float* __restrict__ s_src,
    const float* __restrict__ s_dst, const int* __restrict__ offs,
    const int* __restrict__ csr_src, const float* __restrict__ bias,
    float* __restrict__ outp, int N) {
    int vtx = blockIdx.x;
    int beg = offs[vtx], end = offs[vtx + 1];
    int deg = end - beg;
    __shared__ float sc_lds[HEADS * SCSTR];
    __shared__ int   u_lds[CAP];
    __shared__ float mxs[HEADS], invs[HEADS];
    int tid = threadIdx.x;
    int head = tid >> 5, el = tid & 31;
    float sdv = s_dst[vtx * HEADS + head];

    float mval = -3.0e38f, sval = 0.f;
    for (int e = el; e < deg; e += 32) {
        int u = csr_src[beg + e];
        if (head == 0 && e < CAP) u_lds[e] = u;
        float sc = lrelu(s_src[u * HEADS + head] + sdv);
        if (e < CAP) sc_lds[head * SCSTR + e] = sc;
        float nm = fmaxf(mval, sc);
        sval = sval * __expf(mval - nm) + __expf(sc - nm);
        mval = nm;
    }
#pragma unroll
    for (int msk = 16; msk >= 1; msk >>= 1) {
        float om = __shfl_xor(mval, msk);
        float os = __shfl_xor(sval, msk);
        float nm = fmaxf(mval, om);
        sval = sval * __expf(mval - nm) + os * __expf(om - nm);
        mval = nm;
    }
    if (el == 0) { mxs[head] = mval; invs[head] = 1.f / sval; }
    __syncthreads();

    int dc = min(deg, CAP);
    for (int idx = tid; idx < dc * HEADS; idx += 256) {
        int e = idx >> 3, hh = idx & 7;
        float scv = sc_lds[hh * SCSTR + e];
        sc_lds[hh * SCSTR + e] = __expf(scv - mxs[hh]) * invs[hh];
    }
    __syncthreads();

    float acc = 0.f;
#pragma unroll 4
    for (int e = 0; e < dc; ++e) {
        int u = u_lds[e];
        float al = sc_lds[head * SCSTR + e];
        float hv = __bfloat162float(h[(size_t)u * HID + tid]);
        acc = fmaf(al, hv, acc);
    }
    if (deg > CAP) {
        float mh = mxs[head], inv = invs[head];
        for (int e = CAP; e < deg; ++e) {
            int u = csr_src[beg + e];
            float sc = lrelu(s_src[u * HEADS + head] + sdv);
            float al = __expf(sc - mh) * inv;
            acc = fmaf(al, __bfloat162float(h[(size_t)u * HID + tid]), acc);
        }
    }
    outp[(size_t)vtx * HID + tid] = eluf(acc + bias[tid]);
}

// ---------------- head: bn3 affine + skip GEMM + p1/relu + p2 ----------------
__global__ __launch_bounds__(256) void final_kernel(
    const float* __restrict__ t_in, const float* __restrict__ x,
    const float* __restrict__ g3, const float* __restrict__ b3,
    const float* __restrict__ m3, const float* __restrict__ v3,
    const float* __restrict__ skip_W, const float* __restrict__ skip_b,
    const float* __restrict__ p1_W, const float* __restrict__ p1_b,
    const float* __restrict__ p2_W, const float* __restrict__ p2_b,
    float* __restrict__ outp, int N) {
    const int NPB = 32;
    __shared__ float f3[NPB][HID + 1];
    __shared__ float xr[NPB][64];
    int tid = threadIdx.x;
    int base = blockIdx.x * NPB;

    for (int idx = tid; idx < NPB * 64; idx += 256) {
        int r = idx >> 6, k = idx & 63;
        int node = base + r;
        xr[r][k] = (node < N) ? x[(size_t)node * 64 + k] : 0.f;
    }
    __syncthreads();

    float acc[NPB];
#pragma unroll
    for (int i = 0; i < NPB; ++i) acc[i] = 0.f;
    for (int k = 0; k < 64; ++k) {
        float wv = skip_W[(size_t)k * HID + tid];
#pragma unroll
        for (int i = 0; i < NPB; ++i) acc[i] = fmaf(xr[i][k], wv, acc[i]);
    }

    float sc3 = g3[tid] * rsqrtf(v3[tid] + BN_EPS);
    float mm = m3[tid], b3v = b3[tid], sb = skip_b[tid];
    for (int i = 0; i < NPB; ++i) {
        int node = base + i;
        float t = 0.f;
        if (node < N) t = t_in[(size_t)node * HID + tid];
        t = (t - mm) * sc3 + b3v;
        f3[i][tid] = t + acc[i] + sb;
    }
    __syncthreads();

    int node = tid >> 3, r = tid & 7;
    float po = 0.f;
#pragma unroll
    for (int q = 0; q < 4; ++q) {
        int j = q * 8 + r;
        float z = p1_b[j];
        for (int c = 0; c < HID; ++c) z = fmaf(f3[node][c], p1_W[c * 32 + j], z);
        z = fmaxf(z, 0.f);
        po = fmaf(z, p2_W[j], po);
    }
#pragma unroll
    for (int msk = 4; msk >= 1; msk >>= 1) po += __shfl_xor(po, msk);
    int gn = base + node;
    if (r == 0 && gn < N) outp[gn] = po + p2_b[0];
}

// ---------------- launch ----------------

extern "C" void kernel_launch(void* const* d_in, const int* in_sizes, int n_in,
                              void* d_out, int out_size, void* d_ws, size_t ws_size,
                              hipStream_t stream) {
    const float* x      = (const float*)d_in[0];
    const int*   ei     = (const int*)  d_in[1];
    const float* bn1_g  = (const float*)d_in[2];
    const float* bn1_b  = (const float*)d_in[3];
    const float* bn1_m  = (const float*)d_in[4];
    const float* bn1_v  = (const float*)d_in[5];
    const float* W1     = (const float*)d_in[6];
    const float* a1_src = (const float*)d_in[7];
    const float* a1_dst = (const float*)d_in[8];
    const float* b1     = (const float*)d_in[9];
    const float* bn2_g  = (const float*)d_in[10];
    const float* bn2_b  = (const float*)d_in[11];
    const float* bn2_m  = (const float*)d_in[12];
    const float* bn2_v  = (const float*)d_in[13];
    const float* W2     = (const float*)d_in[14];
    const float* a2_src = (const float*)d_in[15];
    const float* a2_dst = (const float*)d_in[16];
    const float* b2     = (const float*)d_in[17];
    const float* bn3_g  = (const float*)d_in[18];
    const float* bn3_b  = (const float*)d_in[19];
    const float* bn3_m  = (const float*)d_in[20];
    const float* bn3_v  = (const float*)d_in[21];
    const float* skip_W = (const float*)d_in[22];
    const float* skip_b = (const float*)d_in[23];
    const float* p1_W   = (const float*)d_in[24];
    const float* p1_b   = (const float*)d_in[25];
    const float* p2_W   = (const float*)d_in[26];
    const float* p2_b   = (const float*)d_in[27];

    int N = in_sizes[0] / 64;
    int E = in_sizes[1] / 2;
    int EE = E + N;

    uintptr_t w = (uintptr_t)d_ws;
    auto carve = [&](size_t bytes) -> void* {
        uintptr_t p = w;
        w += (bytes + 255) & ~(size_t)255;
        return (void*)p;
    };
    int*   deg  = (int*)carve((size_t)N * 4);
    int*   cur  = (int*)carve((size_t)N * 4);
    int*   offs = (int*)carve(((size_t)N + 1) * 4);
    int*   csr  = (int*)carve((size_t)EE * 4);
    float* ssrc = (float*)carve((size_t)N * HEADS * 4);
    float* sdst = (float*)carve((size_t)N * HEADS * 4);
    unsigned short* wf1 = (unsigned short*)carve((size_t)2 * 16 * 64 * 8 * 2);
    unsigned short* wf2 = (unsigned short*)carve((size_t)8 * 16 * 64 * 8 * 2);
    float* c1   = (float*)carve((size_t)HID * 4);
    float* c2   = (float*)carve((size_t)HID * 4);
    unsigned short* hbf = (unsigned short*)carve((size_t)N * HID * 2);
    float* tbuf = (float*)carve((size_t)N * HID * 4);

    hipMemsetAsync(deg, 0, (size_t)N * 4, stream);
    hipMemsetAsync(cur, 0, (size_t)N * 4, stream);

    // W fragment pregen + bias folds
    wfrag_kernel<<<2 * 16, 64, 0, stream>>>(W1, bn1_g, bn1_v, wf1);
    wfrag_kernel<<<8 * 16, 64, 0, stream>>>(W2, bn2_g, bn2_v, wf2);
    fold_c_kernel<<<1, 256, 0, stream>>>(W1, bn1_g, bn1_b, bn1_m, bn1_v, c1, 64);
    fold_c_kernel<<<1, 256, 0, stream>>>(W2, bn2_g, bn2_b, bn2_m, bn2_v, c2, HID);

    // CSR
    int eblk = (EE + 255) / 256;
    degree_kernel<<<eblk, 256, 0, stream>>>(ei, deg, E, EE);
    scan_kernel<<<1, 1024, 0, stream>>>(deg, offs, N);
    scatter_kernel<<<eblk, 256, 0, stream>>>(ei, offs, cur, csr, E, EE);

    int gblk = (N + 63) / 64;
    // layer 1
    gemm_mfma<64><<<gblk, 256, 0, stream>>>(x, wf1, c1, a1_src, a1_dst,
                                            hbf, ssrc, sdst, N);
    agg_kernel<<<N, 256, 0, stream>>>((const __hip_bfloat16*)hbf, ssrc, sdst,
                                      offs, csr, b1, tbuf, N);

    // layer 2
    gemm_mfma<HID><<<gblk, 256, 0, stream>>>(tbuf, wf2, c2, a2_src, a2_dst,
                                             hbf, ssrc, sdst, N);
    agg_kernel<<<N, 256, 0, stream>>>((const __hip_bfloat16*)hbf, ssrc, sdst,
                                      offs, csr, b2, tbuf, N);

    // head
    int fblk = (N + 31) / 32;
    final_kernel<<<fblk, 256, 0, stream>>>(
        tbuf, x, bn3_g, bn3_b, bn3_m, bn3_v, skip_W, skip_b,
        p1_W, p1_b, p2_W, p2_b, (float*)d_out, N);
}

// Round 5
// 570.811 us; speedup vs baseline: 1.7898x; 1.1449x over previous
//
#include <hip/hip_runtime.h>
#include <hip/hip_bf16.h>
#include <math.h>
#include <stdint.h>

#define HID 256
#define HEADS 8
#define BN_EPS 1e-5f
#define NEG 0.2f
#define CAP 192
#define SCSTR 196

typedef short sv8  __attribute__((ext_vector_type(8)));
typedef float f32x4 __attribute__((ext_vector_type(4)));

__device__ __forceinline__ float lrelu(float x) { return x > 0.f ? x : NEG * x; }
__device__ __forceinline__ float eluf(float x)  { return x > 0.f ? x : expm1f(x); }

__device__ __forceinline__ unsigned short f2bf(float f) {
    unsigned int u = __float_as_uint(f);
    u = (u + 0x7fffu + ((u >> 16) & 1u)) >> 16;   // RNE
    return (unsigned short)u;
}
__device__ __forceinline__ unsigned int pk2(float lo, float hi) {
    return (unsigned int)f2bf(lo) | ((unsigned int)f2bf(hi) << 16);
}

// ---------------- CSR build ----------------

__global__ __launch_bounds__(256) void degree_kernel(const int* __restrict__ ei,
                                                     int* __restrict__ deg,
                                                     int E, int EE) {
    int e = blockIdx.x * 256 + threadIdx.x;
    if (e >= EE) return;
    int d = (e < E) ? ei[E + e] : (e - E);
    atomicAdd(&deg[d], 1);
}

__global__ __launch_bounds__(1024) void scan_kernel(const int* __restrict__ deg,
                                                    int* __restrict__ offs, int N) {
    __shared__ int part[1024];
    int t = threadIdx.x;
    int chunk = (N + 1023) >> 10;
    int c0 = t * chunk;
    int c1 = min(c0 + chunk, N);
    int s = 0;
    for (int j = c0; j < c1; ++j) s += deg[j];
    part[t] = s;
    __syncthreads();
    for (int d = 1; d < 1024; d <<= 1) {
        int vv = (t >= d) ? part[t - d] : 0;
        __syncthreads();
        part[t] += vv;
        __syncthreads();
    }
    int run = part[t] - s;
    for (int j = c0; j < c1; ++j) { offs[j] = run; run += deg[j]; }
    if (t == 1023) offs[N] = part[1023];
}

__global__ __launch_bounds__(256) void scatter_kernel(const int* __restrict__ ei,
                                                      const int* __restrict__ offs,
                                                      int* __restrict__ cur,
                                                      int* __restrict__ csr_src,
                                                      int E, int EE) {
    int e = blockIdx.x * 256 + threadIdx.x;
    if (e >= EE) return;
    int s = (e < E) ? ei[e] : (e - E);
    int d = (e < E) ? ei[E + e] : (e - E);
    int pos = offs[d] + atomicAdd(&cur[d], 1);
    csr_src[pos] = s;
}

// ---------------- W' fragment pregen (layer GEMMs) ----------------
// tile = ktile*16 + coltile; lane l holds W'[k0+8*(l>>4)+j][c0+(l&15)]
__global__ __launch_bounds__(64) void wfrag_kernel(const float* __restrict__ W,
                                                   const float* __restrict__ g,
                                                   const float* __restrict__ v,
                                                   unsigned short* __restrict__ frag) {
    int tile = blockIdx.x;
    int ct = tile & 15, kt = tile >> 4;
    int l = threadIdx.x;
    int c = ct * 16 + (l & 15);
    int k0 = kt * 32 + (l >> 4) * 8;
    float val[8];
#pragma unroll
    for (int j = 0; j < 8; ++j) {
        float s = g[k0 + j] * rsqrtf(v[k0 + j] + BN_EPS);
        val[j] = W[(size_t)(k0 + j) * HID + c] * s;
    }
    uint4 o;
    o.x = pk2(val[0], val[1]);
    o.y = pk2(val[2], val[3]);
    o.z = pk2(val[4], val[5]);
    o.w = pk2(val[6], val[7]);
    *(uint4*)&frag[((size_t)tile * 64 + l) * 8] = o;
}

__global__ __launch_bounds__(256) void fold_c_kernel(const float* __restrict__ W,
                                                     const float* __restrict__ g,
                                                     const float* __restrict__ b,
                                                     const float* __restrict__ m,
                                                     const float* __restrict__ v,
                                                     float* __restrict__ cvec, int K) {
    int j = threadIdx.x;
    float acc = 0.f;
    for (int k = 0; k < K; ++k) {
        float s = g[k] * rsqrtf(v[k] + BN_EPS);
        acc = fmaf(b[k] - m[k] * s, W[(size_t)k * HID + j], acc);
    }
    cvec[j] = acc;
}

// ---------------- head folds ----------------
// S' = skip_W @ p1_W   [64,32]
__global__ __launch_bounds__(32) void sfold_kernel(const float* __restrict__ skip_W,
                                                   const float* __restrict__ p1_W,
                                                   float* __restrict__ Sp) {
    int cx = blockIdx.x, j = threadIdx.x;
    float acc = 0.f;
    for (int c = 0; c < HID; ++c)
        acc = fmaf(skip_W[(size_t)cx * HID + c], p1_W[c * 32 + j], acc);
    Sp[cx * 32 + j] = acc;
}

// c' = (b3 - m3*s3 + skip_b) @ p1_W + p1_b   [32]
__global__ __launch_bounds__(32) void cfold_kernel(const float* __restrict__ g3,
                                                   const float* __restrict__ b3,
                                                   const float* __restrict__ m3,
                                                   const float* __restrict__ v3,
                                                   const float* __restrict__ skip_b,
                                                   const float* __restrict__ p1_W,
                                                   const float* __restrict__ p1_b,
                                                   float* __restrict__ cp) {
    int j = threadIdx.x;
    float acc = p1_b[j];
    for (int c = 0; c < HID; ++c) {
        float s3 = g3[c] * rsqrtf(v3[c] + BN_EPS);
        acc = fmaf(b3[c] - m3[c] * s3 + skip_b[c], p1_W[c * 32 + j], acc);
    }
    cp[j] = acc;
}

// head A-fragments: M[c][j], c in 0..319: c<256 -> s3[c]*p1_W[c][j]; else S'[c-256][j]
// tile = kt*2 + mt (kt 0..9, mt 0..1); lane l: j = mt*16+(l&15), k = kt*32+(l>>4)*8+jj
__global__ __launch_bounds__(64) void hfrag_kernel(const float* __restrict__ p1_W,
                                                   const float* __restrict__ g3,
                                                   const float* __restrict__ v3,
                                                   const float* __restrict__ Sp,
                                                   unsigned short* __restrict__ frag) {
    int tile = blockIdx.x;
    int mt = tile & 1, kt = tile >> 1;
    int l = threadIdx.x;
    int j = mt * 16 + (l & 15);
    int k0 = kt * 32 + (l >> 4) * 8;
    float val[8];
#pragma unroll
    for (int jj = 0; jj < 8; ++jj) {
        int c = k0 + jj;
        if (c < HID) {
            float s3 = g3[c] * rsqrtf(v3[c] + BN_EPS);
            val[jj] = s3 * p1_W[c * 32 + j];
        } else {
            val[jj] = Sp[(c - HID) * 32 + j];
        }
    }
    uint4 o;
    o.x = pk2(val[0], val[1]);
    o.y = pk2(val[2], val[3]);
    o.z = pk2(val[4], val[5]);
    o.w = pk2(val[6], val[7]);
    *(uint4*)&frag[((size_t)tile * 64 + l) * 8] = o;
}

// ---------------- MFMA GEMM (swapped): D[wcol][node] = W'^T-op x X-op ----------------
template <int K>
__global__ __launch_bounds__(256) void gemm_mfma(
    const float* __restrict__ in, const unsigned short* __restrict__ wfrag,
    const float* __restrict__ cvec,
    const float* __restrict__ a_src, const float* __restrict__ a_dst,
    unsigned short* __restrict__ h, float* __restrict__ s_src,
    float* __restrict__ s_dst, int N) {
    constexpr int KT = K / 32;
    constexpr int OPR = K / 8;
    __shared__ unsigned short xfrag[KT * 4 * 64 * 8];
    int tid = threadIdx.x;
    int w = tid >> 6, l = tid & 63;
    int gg = l >> 4, li = l & 15;
    int base = blockIdx.x * 64;

    for (int id = tid; id < 64 * OPR; id += 256) {
        int r = id / OPR, o = id % OPR;
        int node = min(base + r, N - 1);
        const float* p = &in[(size_t)node * K + o * 8];
        float4 f0 = *(const float4*)p;
        float4 f1 = *(const float4*)(p + 4);
        uint4 pkv;
        pkv.x = pk2(f0.x, f0.y);
        pkv.y = pk2(f0.z, f0.w);
        pkv.z = pk2(f1.x, f1.y);
        pkv.w = pk2(f1.z, f1.w);
        int kt = o >> 2, og = o & 3, nt = r >> 4;
        *(uint4*)&xfrag[(((kt * 4 + nt) * 64) + (r & 15) + 16 * og) * 8] = pkv;
    }
    __syncthreads();

    f32x4 acc[4][4];
#pragma unroll
    for (int mm = 0; mm < 4; ++mm) {
        float4 cv = *(const float4*)&cvec[64 * w + 16 * mm + 4 * gg];
#pragma unroll
        for (int nn = 0; nn < 4; ++nn) {
            acc[mm][nn][0] = cv.x; acc[mm][nn][1] = cv.y;
            acc[mm][nn][2] = cv.z; acc[mm][nn][3] = cv.w;
        }
    }

    for (int ks = 0; ks < KT; ++ks) {
        sv8 a[4], b[4];
#pragma unroll
        for (int mm = 0; mm < 4; ++mm)
            a[mm] = *(const sv8*)&wfrag[((size_t)(ks * 16 + w * 4 + mm) * 64 + l) * 8];
#pragma unroll
        for (int nn = 0; nn < 4; ++nn)
            b[nn] = *(const sv8*)&xfrag[((ks * 4 + nn) * 64 + l) * 8];
#pragma unroll
        for (int mm = 0; mm < 4; ++mm)
#pragma unroll
            for (int nn = 0; nn < 4; ++nn)
                acc[mm][nn] = __builtin_amdgcn_mfma_f32_16x16x32_bf16(
                    a[mm], b[nn], acc[mm][nn], 0, 0, 0);
    }

    float svp[4][2], sdp[4][2];
#pragma unroll
    for (int nn = 0; nn < 4; ++nn) { svp[nn][0]=0.f; svp[nn][1]=0.f; sdp[nn][0]=0.f; sdp[nn][1]=0.f; }

#pragma unroll
    for (int mm = 0; mm < 4; ++mm) {
        int cb = 64 * w + 16 * mm + 4 * gg;
        float4 as4 = *(const float4*)&a_src[cb];
        float4 ad4 = *(const float4*)&a_dst[cb];
        int hp = mm >> 1;
#pragma unroll
        for (int nn = 0; nn < 4; ++nn) {
            f32x4 A = acc[mm][nn];
            svp[nn][hp] += A[0]*as4.x + A[1]*as4.y + A[2]*as4.z + A[3]*as4.w;
            sdp[nn][hp] += A[0]*ad4.x + A[1]*ad4.y + A[2]*ad4.z + A[3]*ad4.w;
            int node = base + 16 * nn + li;
            if (node < N) {
                ushort4 pkv;
                pkv.x = f2bf(A[0]); pkv.y = f2bf(A[1]);
                pkv.z = f2bf(A[2]); pkv.w = f2bf(A[3]);
                *(ushort4*)&h[(size_t)node * HID + cb] = pkv;
            }
        }
    }
#pragma unroll
    for (int nn = 0; nn < 4; ++nn)
#pragma unroll
        for (int hp = 0; hp < 2; ++hp) {
            svp[nn][hp] += __shfl_xor(svp[nn][hp], 16);
            svp[nn][hp] += __shfl_xor(svp[nn][hp], 32);
            sdp[nn][hp] += __shfl_xor(sdp[nn][hp], 16);
            sdp[nn][hp] += __shfl_xor(sdp[nn][hp], 32);
        }
    if (gg == 0) {
#pragma unroll
        for (int nn = 0; nn < 4; ++nn) {
            int node = base + 16 * nn + li;
            if (node < N) {
#pragma unroll
                for (int hp = 0; hp < 2; ++hp) {
                    s_src[node * HEADS + 2 * w + hp] = svp[nn][hp];
                    s_dst[node * HEADS + 2 * w + hp] = sdp[nn][hp];
                }
            }
        }
    }
}

// ---------------- per-dst segment softmax + aggregation + bias + ELU ----------------
__global__ __launch_bounds__(256) void agg_kernel(
    const __hip_bfloat16* __restrict__ h, const float* __restrict__ s_src,
    const float* __restrict__ s_dst, const int* __restrict__ offs,
    const int* __restrict__ csr_src, const float* __restrict__ bias,
    float* __restrict__ outp, int N) {
    int vtx = blockIdx.x;
    int beg = offs[vtx], end = offs[vtx + 1];
    int deg = end - beg;
    __shared__ float sc_lds[HEADS * SCSTR];
    __shared__ int   u_lds[CAP];
    __shared__ float mxs[HEADS], invs[HEADS];
    int tid = threadIdx.x;
    int head = tid >> 5, el = tid & 31;
    float sdv = s_dst[vtx * HEADS + head];

    float mval = -3.0e38f, sval = 0.f;
    for (int e = el; e < deg; e += 32) {
        int u = csr_src[beg + e];
        if (head == 0 && e < CAP) u_lds[e] = u;
        float sc = lrelu(s_src[u * HEADS + head] + sdv);
        if (e < CAP) sc_lds[head * SCSTR + e] = sc;
        float nm = fmaxf(mval, sc);
        sval = sval * __expf(mval - nm) + __expf(sc - nm);
        mval = nm;
    }
#pragma unroll
    for (int msk = 16; msk >= 1; msk >>= 1) {
        float om = __shfl_xor(mval, msk);
        float os = __shfl_xor(sval, msk);
        float nm = fmaxf(mval, om);
        sval = sval * __expf(mval - nm) + os * __expf(om - nm);
        mval = nm;
    }
    if (el == 0) { mxs[head] = mval; invs[head] = 1.f / sval; }
    __syncthreads();

    int dc = min(deg, CAP);
    for (int idx = tid; idx < dc * HEADS; idx += 256) {
        int e = idx >> 3, hh = idx & 7;
        float scv = sc_lds[hh * SCSTR + e];
        sc_lds[hh * SCSTR + e] = __expf(scv - mxs[hh]) * invs[hh];
    }
    __syncthreads();

    float acc = 0.f;
#pragma unroll 4
    for (int e = 0; e < dc; ++e) {
        int u = u_lds[e];
        float al = sc_lds[head * SCSTR + e];
        float hv = __bfloat162float(h[(size_t)u * HID + tid]);
        acc = fmaf(al, hv, acc);
    }
    if (deg > CAP) {
        float mh = mxs[head], inv = invs[head];
        for (int e = CAP; e < deg; ++e) {
            int u = csr_src[beg + e];
            float sc = lrelu(s_src[u * HEADS + head] + sdv);
            float al = __expf(sc - mh) * inv;
            acc = fmaf(al, __bfloat162float(h[(size_t)u * HID + tid]), acc);
        }
    }
    outp[(size_t)vtx * HID + tid] = eluf(acc + bias[tid]);
}

// ---------------- head: q = [t|x] @ hfrag + c'; out = relu(q) @ p2_W + p2_b ----------
__global__ __launch_bounds__(256) void final_mfma(
    const float* __restrict__ t_in, const float* __restrict__ x,
    const unsigned short* __restrict__ hf, const float* __restrict__ cp,
    const float* __restrict__ p2_W, const float* __restrict__ p2_b,
    float* __restrict__ outp, int N) {
    constexpr int KT = 10;           // 8 tiles from t (K=256) + 2 from x (K=64)
    __shared__ unsigned short xfrag[KT * 4 * 64 * 8];
    int tid = threadIdx.x;
    int w = tid >> 6, l = tid & 63;
    int gg = l >> 4, li = l & 15;
    int base = blockIdx.x * 64;

    for (int id = tid; id < 64 * 40; id += 256) {
        int r = id / 40, o = id % 40;
        int node = min(base + r, N - 1);
        const float* p = (o < 32) ? &t_in[(size_t)node * HID + o * 8]
                                  : &x[(size_t)node * 64 + (o - 32) * 8];
        float4 f0 = *(const float4*)p;
        float4 f1 = *(const float4*)(p + 4);
        uint4 pkv;
        pkv.x = pk2(f0.x, f0.y);
        pkv.y = pk2(f0.z, f0.w);
        pkv.z = pk2(f1.x, f1.y);
        pkv.w = pk2(f1.z, f1.w);
        int kt = o >> 2, og = o & 3, nt = r >> 4;
        *(uint4*)&xfrag[(((kt * 4 + nt) * 64) + (r & 15) + 16 * og) * 8] = pkv;
    }
    __syncthreads();

    // wave w handles node sub-tile nn = w
    f32x4 acc[2];
#pragma unroll
    for (int mt = 0; mt < 2; ++mt) {
        float4 cv = *(const float4*)&cp[mt * 16 + 4 * gg];
        acc[mt][0] = cv.x; acc[mt][1] = cv.y; acc[mt][2] = cv.z; acc[mt][3] = cv.w;
    }

    for (int kt = 0; kt < KT; ++kt) {
        sv8 b = *(const sv8*)&xfrag[((kt * 4 + w) * 64 + l) * 8];
#pragma unroll
        for (int mt = 0; mt < 2; ++mt) {
            sv8 a = *(const sv8*)&hf[((size_t)(kt * 2 + mt) * 64 + l) * 8];
            acc[mt] = __builtin_amdgcn_mfma_f32_16x16x32_bf16(a, b, acc[mt], 0, 0, 0);
        }
    }

    // relu + dot p2_W over lane's 8 j's, then reduce across g-groups
    float po = 0.f;
#pragma unroll
    for (int mt = 0; mt < 2; ++mt) {
        float4 p2v = *(const float4*)&p2_W[mt * 16 + 4 * gg];
        po += fmaxf(acc[mt][0], 0.f) * p2v.x;
        po += fmaxf(acc[mt][1], 0.f) * p2v.y;
        po += fmaxf(acc[mt][2], 0.f) * p2v.z;
        po += fmaxf(acc[mt][3], 0.f) * p2v.w;
    }
    po += __shfl_xor(po, 16);
    po += __shfl_xor(po, 32);
    int node = base + 16 * w + li;
    if (gg == 0 && node < N) outp[node] = po + p2_b[0];
}

// ---------------- launch ----------------

extern "C" void kernel_launch(void* const* d_in, const int* in_sizes, int n_in,
                              void* d_out, int out_size, void* d_ws, size_t ws_size,
                              hipStream_t stream) {
    const float* x      = (const float*)d_in[0];
    const int*   ei     = (const int*)  d_in[1];
    const float* bn1_g  = (const float*)d_in[2];
    const float* bn1_b  = (const float*)d_in[3];
    const float* bn1_m  = (const float*)d_in[4];
    const float* bn1_v  = (const float*)d_in[5];
    const float* W1     = (const float*)d_in[6];
    const float* a1_src = (const float*)d_in[7];
    const float* a1_dst = (const float*)d_in[8];
    const float* b1     = (const float*)d_in[9];
    const float* bn2_g  = (const float*)d_in[10];
    const float* bn2_b  = (const float*)d_in[11];
    const float* bn2_m  = (const float*)d_in[12];
    const float* bn2_v  = (const float*)d_in[13];
    const float* W2     = (const float*)d_in[14];
    const float* a2_src = (const float*)d_in[15];
    const float* a2_dst = (const float*)d_in[16];
    const float* b2     = (const float*)d_in[17];
    const float* bn3_g  = (const float*)d_in[18];
    const float* bn3_b  = (const float*)d_in[19];
    const float* bn3_m  = (const float*)d_in[20];
    const float* bn3_v  = (const float*)d_in[21];
    const float* skip_W = (const float*)d_in[22];
    const float* skip_b = (const float*)d_in[23];
    const float* p1_W   = (const float*)d_in[24];
    const float* p1_b   = (const float*)d_in[25];
    const float* p2_W   = (const float*)d_in[26];
    const float* p2_b   = (const float*)d_in[27];

    int N = in_sizes[0] / 64;
    int E = in_sizes[1] / 2;
    int EE = E + N;

    uintptr_t w = (uintptr_t)d_ws;
    auto carve = [&](size_t bytes) -> void* {
        uintptr_t p = w;
        w += (bytes + 255) & ~(size_t)255;
        return (void*)p;
    };
    int*   deg  = (int*)carve((size_t)N * 4);
    int*   cur  = (int*)carve((size_t)N * 4);
    int*   offs = (int*)carve(((size_t)N + 1) * 4);
    int*   csr  = (int*)carve((size_t)EE * 4);
    float* ssrc = (float*)carve((size_t)N * HEADS * 4);
    float* sdst = (float*)carve((size_t)N * HEADS * 4);
    unsigned short* wf1 = (unsigned short*)carve((size_t)2 * 16 * 64 * 8 * 2);
    unsigned short* wf2 = (unsigned short*)carve((size_t)8 * 16 * 64 * 8 * 2);
    unsigned short* hf  = (unsigned short*)carve((size_t)20 * 64 * 8 * 2);
    float* c1   = (float*)carve((size_t)HID * 4);
    float* c2   = (float*)carve((size_t)HID * 4);
    float* Sp   = (float*)carve((size_t)64 * 32 * 4);
    float* cp   = (float*)carve((size_t)32 * 4);
    unsigned short* hbf = (unsigned short*)carve((size_t)N * HID * 2);
    float* tbuf = (float*)carve((size_t)N * HID * 4);

    hipMemsetAsync(deg, 0, (size_t)N * 4, stream);
    hipMemsetAsync(cur, 0, (size_t)N * 4, stream);

    // fragment pregen + folds
    wfrag_kernel<<<2 * 16, 64, 0, stream>>>(W1, bn1_g, bn1_v, wf1);
    wfrag_kernel<<<8 * 16, 64, 0, stream>>>(W2, bn2_g, bn2_v, wf2);
    fold_c_kernel<<<1, 256, 0, stream>>>(W1, bn1_g, bn1_b, bn1_m, bn1_v, c1, 64);
    fold_c_kernel<<<1, 256, 0, stream>>>(W2, bn2_g, bn2_b, bn2_m, bn2_v, c2, HID);
    sfold_kernel<<<64, 32, 0, stream>>>(skip_W, p1_W, Sp);
    cfold_kernel<<<1, 32, 0, stream>>>(bn3_g, bn3_b, bn3_m, bn3_v, skip_b,
                                       p1_W, p1_b, cp);
    hfrag_kernel<<<20, 64, 0, stream>>>(p1_W, bn3_g, bn3_v, Sp, hf);

    // CSR
    int eblk = (EE + 255) / 256;
    degree_kernel<<<eblk, 256, 0, stream>>>(ei, deg, E, EE);
    scan_kernel<<<1, 1024, 0, stream>>>(deg, offs, N);
    scatter_kernel<<<eblk, 256, 0, stream>>>(ei, offs, cur, csr, E, EE);

    int gblk = (N + 63) / 64;
    // layer 1
    gemm_mfma<64><<<gblk, 256, 0, stream>>>(x, wf1, c1, a1_src, a1_dst,
                                            hbf, ssrc, sdst, N);
    agg_kernel<<<N, 256, 0, stream>>>((const __hip_bfloat16*)hbf, ssrc, sdst,
                                      offs, csr, b1, tbuf, N);

    // layer 2
    gemm_mfma<HID><<<gblk, 256, 0, stream>>>(tbuf, wf2, c2, a2_src, a2_dst,
                                             hbf, ssrc, sdst, N);
    agg_kernel<<<N, 256, 0, stream>>>((const __hip_bfloat16*)hbf, ssrc, sdst,
                                      offs, csr, b2, tbuf, N);

    // head (fully folded)
    final_mfma<<<gblk, 256, 0, stream>>>(tbuf, x, hf, cp, p2_W, p2_b,
                                         (float*)d_out, N);
}

// Round 6
// 552.161 us; speedup vs baseline: 1.8503x; 1.0338x over previous
//
#include <hip/hip_runtime.h>
#include <hip/hip_bf16.h>
#include <math.h>
#include <stdint.h>

#define HID 256
#define HEADS 8
#define BN_EPS 1e-5f
#define NEG 0.2f
#define CAP 192
#define SCSTR 196

typedef short sv8  __attribute__((ext_vector_type(8)));
typedef float f32x4 __attribute__((ext_vector_type(4)));

__device__ __forceinline__ float lrelu(float x) { return x > 0.f ? x : NEG * x; }
__device__ __forceinline__ float eluf(float x)  { return x > 0.f ? x : expm1f(x); }

__device__ __forceinline__ unsigned short f2bf(float f) {
    unsigned int u = __float_as_uint(f);
    u = (u + 0x7fffu + ((u >> 16) & 1u)) >> 16;   // RNE
    return (unsigned short)u;
}
__device__ __forceinline__ unsigned int pk2(float lo, float hi) {
    return (unsigned int)f2bf(lo) | ((unsigned int)f2bf(hi) << 16);
}

// ---------------- CSR build ----------------

__global__ __launch_bounds__(256) void degree_kernel(const int* __restrict__ ei,
                                                     int* __restrict__ deg,
                                                     int E, int EE) {
    int e = blockIdx.x * 256 + threadIdx.x;
    if (e >= EE) return;
    int d = (e < E) ? ei[E + e] : (e - E);
    atomicAdd(&deg[d], 1);
}

__global__ __launch_bounds__(1024) void scan_kernel(const int* __restrict__ deg,
                                                    int* __restrict__ offs, int N) {
    __shared__ int part[1024];
    int t = threadIdx.x;
    int chunk = (N + 1023) >> 10;
    int c0 = t * chunk;
    int c1 = min(c0 + chunk, N);
    int s = 0;
    for (int j = c0; j < c1; ++j) s += deg[j];
    part[t] = s;
    __syncthreads();
    for (int d = 1; d < 1024; d <<= 1) {
        int vv = (t >= d) ? part[t - d] : 0;
        __syncthreads();
        part[t] += vv;
        __syncthreads();
    }
    int run = part[t] - s;
    for (int j = c0; j < c1; ++j) { offs[j] = run; run += deg[j]; }
    if (t == 1023) offs[N] = part[1023];
}

__global__ __launch_bounds__(256) void scatter_kernel(const int* __restrict__ ei,
                                                      const int* __restrict__ offs,
                                                      int* __restrict__ cur,
                                                      int* __restrict__ csr_src,
                                                      int E, int EE) {
    int e = blockIdx.x * 256 + threadIdx.x;
    if (e >= EE) return;
    int s = (e < E) ? ei[e] : (e - E);
    int d = (e < E) ? ei[E + e] : (e - E);
    int pos = offs[d] + atomicAdd(&cur[d], 1);
    csr_src[pos] = s;
}

// ---------------- W' fragment pregen (layer GEMMs) ----------------
__global__ __launch_bounds__(64) void wfrag_kernel(const float* __restrict__ W,
                                                   const float* __restrict__ g,
                                                   const float* __restrict__ v,
                                                   unsigned short* __restrict__ frag) {
    int tile = blockIdx.x;
    int ct = tile & 15, kt = tile >> 4;
    int l = threadIdx.x;
    int c = ct * 16 + (l & 15);
    int k0 = kt * 32 + (l >> 4) * 8;
    float val[8];
#pragma unroll
    for (int j = 0; j < 8; ++j) {
        float s = g[k0 + j] * rsqrtf(v[k0 + j] + BN_EPS);
        val[j] = W[(size_t)(k0 + j) * HID + c] * s;
    }
    uint4 o;
    o.x = pk2(val[0], val[1]);
    o.y = pk2(val[2], val[3]);
    o.z = pk2(val[4], val[5]);
    o.w = pk2(val[6], val[7]);
    *(uint4*)&frag[((size_t)tile * 64 + l) * 8] = o;
}

__global__ __launch_bounds__(256) void fold_c_kernel(const float* __restrict__ W,
                                                     const float* __restrict__ g,
                                                     const float* __restrict__ b,
                                                     const float* __restrict__ m,
                                                     const float* __restrict__ v,
                                                     float* __restrict__ cvec, int K) {
    int j = threadIdx.x;
    float acc = 0.f;
    for (int k = 0; k < K; ++k) {
        float s = g[k] * rsqrtf(v[k] + BN_EPS);
        acc = fmaf(b[k] - m[k] * s, W[(size_t)k * HID + j], acc);
    }
    cvec[j] = acc;
}

// ---------------- head folds ----------------
__global__ __launch_bounds__(32) void sfold_kernel(const float* __restrict__ skip_W,
                                                   const float* __restrict__ p1_W,
                                                   float* __restrict__ Sp) {
    int cx = blockIdx.x, j = threadIdx.x;
    float acc = 0.f;
    for (int c = 0; c < HID; ++c)
        acc = fmaf(skip_W[(size_t)cx * HID + c], p1_W[c * 32 + j], acc);
    Sp[cx * 32 + j] = acc;
}

__global__ __launch_bounds__(32) void cfold_kernel(const float* __restrict__ g3,
                                                   const float* __restrict__ b3,
                                                   const float* __restrict__ m3,
                                                   const float* __restrict__ v3,
                                                   const float* __restrict__ skip_b,
                                                   const float* __restrict__ p1_W,
                                                   const float* __restrict__ p1_b,
                                                   float* __restrict__ cp) {
    int j = threadIdx.x;
    float acc = p1_b[j];
    for (int c = 0; c < HID; ++c) {
        float s3 = g3[c] * rsqrtf(v3[c] + BN_EPS);
        acc = fmaf(b3[c] - m3[c] * s3 + skip_b[c], p1_W[c * 32 + j], acc);
    }
    cp[j] = acc;
}

__global__ __launch_bounds__(64) void hfrag_kernel(const float* __restrict__ p1_W,
                                                   const float* __restrict__ g3,
                                                   const float* __restrict__ v3,
                                                   const float* __restrict__ Sp,
                                                   unsigned short* __restrict__ frag) {
    int tile = blockIdx.x;
    int mt = tile & 1, kt = tile >> 1;
    int l = threadIdx.x;
    int j = mt * 16 + (l & 15);
    int k0 = kt * 32 + (l >> 4) * 8;
    float val[8];
#pragma unroll
    for (int jj = 0; jj < 8; ++jj) {
        int c = k0 + jj;
        if (c < HID) {
            float s3 = g3[c] * rsqrtf(v3[c] + BN_EPS);
            val[jj] = s3 * p1_W[c * 32 + j];
        } else {
            val[jj] = Sp[(c - HID) * 32 + j];
        }
    }
    uint4 o;
    o.x = pk2(val[0], val[1]);
    o.y = pk2(val[2], val[3]);
    o.z = pk2(val[4], val[5]);
    o.w = pk2(val[6], val[7]);
    *(uint4*)&frag[((size_t)tile * 64 + l) * 8] = o;
}

// ---------------- MFMA GEMM (swapped): D[wcol][node] = W'^T-op x X-op ----------------
template <int K>
__global__ __launch_bounds__(256) void gemm_mfma(
    const float* __restrict__ in, const unsigned short* __restrict__ wfrag,
    const float* __restrict__ cvec,
    const float* __restrict__ a_src, const float* __restrict__ a_dst,
    unsigned short* __restrict__ h, float* __restrict__ s_src,
    float* __restrict__ s_dst, int N) {
    constexpr int KT = K / 32;
    constexpr int OPR = K / 8;
    __shared__ unsigned short xfrag[KT * 4 * 64 * 8];
    int tid = threadIdx.x;
    int w = tid >> 6, l = tid & 63;
    int gg = l >> 4, li = l & 15;
    int base = blockIdx.x * 64;

    for (int id = tid; id < 64 * OPR; id += 256) {
        int r = id / OPR, o = id % OPR;
        int node = min(base + r, N - 1);
        const float* p = &in[(size_t)node * K + o * 8];
        float4 f0 = *(const float4*)p;
        float4 f1 = *(const float4*)(p + 4);
        uint4 pkv;
        pkv.x = pk2(f0.x, f0.y);
        pkv.y = pk2(f0.z, f0.w);
        pkv.z = pk2(f1.x, f1.y);
        pkv.w = pk2(f1.z, f1.w);
        int kt = o >> 2, og = o & 3, nt = r >> 4;
        *(uint4*)&xfrag[(((kt * 4 + nt) * 64) + (r & 15) + 16 * og) * 8] = pkv;
    }
    __syncthreads();

    f32x4 acc[4][4];
#pragma unroll
    for (int mm = 0; mm < 4; ++mm) {
        float4 cv = *(const float4*)&cvec[64 * w + 16 * mm + 4 * gg];
#pragma unroll
        for (int nn = 0; nn < 4; ++nn) {
            acc[mm][nn][0] = cv.x; acc[mm][nn][1] = cv.y;
            acc[mm][nn][2] = cv.z; acc[mm][nn][3] = cv.w;
        }
    }

    for (int ks = 0; ks < KT; ++ks) {
        sv8 a[4], b[4];
#pragma unroll
        for (int mm = 0; mm < 4; ++mm)
            a[mm] = *(const sv8*)&wfrag[((size_t)(ks * 16 + w * 4 + mm) * 64 + l) * 8];
#pragma unroll
        for (int nn = 0; nn < 4; ++nn)
            b[nn] = *(const sv8*)&xfrag[((ks * 4 + nn) * 64 + l) * 8];
#pragma unroll
        for (int mm = 0; mm < 4; ++mm)
#pragma unroll
            for (int nn = 0; nn < 4; ++nn)
                acc[mm][nn] = __builtin_amdgcn_mfma_f32_16x16x32_bf16(
                    a[mm], b[nn], acc[mm][nn], 0, 0, 0);
    }

    float svp[4][2], sdp[4][2];
#pragma unroll
    for (int nn = 0; nn < 4; ++nn) { svp[nn][0]=0.f; svp[nn][1]=0.f; sdp[nn][0]=0.f; sdp[nn][1]=0.f; }

#pragma unroll
    for (int mm = 0; mm < 4; ++mm) {
        int cb = 64 * w + 16 * mm + 4 * gg;
        float4 as4 = *(const float4*)&a_src[cb];
        float4 ad4 = *(const float4*)&a_dst[cb];
        int hp = mm >> 1;
#pragma unroll
        for (int nn = 0; nn < 4; ++nn) {
            f32x4 A = acc[mm][nn];
            svp[nn][hp] += A[0]*as4.x + A[1]*as4.y + A[2]*as4.z + A[3]*as4.w;
            sdp[nn][hp] += A[0]*ad4.x + A[1]*ad4.y + A[2]*ad4.z + A[3]*ad4.w;
            int node = base + 16 * nn + li;
            if (node < N) {
                ushort4 pkv;
                pkv.x = f2bf(A[0]); pkv.y = f2bf(A[1]);
                pkv.z = f2bf(A[2]); pkv.w = f2bf(A[3]);
                *(ushort4*)&h[(size_t)node * HID + cb] = pkv;
            }
        }
    }
#pragma unroll
    for (int nn = 0; nn < 4; ++nn)
#pragma unroll
        for (int hp = 0; hp < 2; ++hp) {
            svp[nn][hp] += __shfl_xor(svp[nn][hp], 16);
            svp[nn][hp] += __shfl_xor(svp[nn][hp], 32);
            sdp[nn][hp] += __shfl_xor(sdp[nn][hp], 16);
            sdp[nn][hp] += __shfl_xor(sdp[nn][hp], 32);
        }
    if (gg == 0) {
#pragma unroll
        for (int nn = 0; nn < 4; ++nn) {
            int node = base + 16 * nn + li;
            if (node < N) {
#pragma unroll
                for (int hp = 0; hp < 2; ++hp) {
                    s_src[node * HEADS + 2 * w + hp] = svp[nn][hp];
                    s_dst[node * HEADS + 2 * w + hp] = sdp[nn][hp];
                }
            }
        }
    }
}

// ---------------- per-dst segment softmax + aggregation + bias + ELU ----------------
// pass A: head = tid>>5, 32 edge-lanes. pass B: waves split edges; lane owns 4 cols.
__global__ __launch_bounds__(256) void agg_kernel(
    const unsigned short* __restrict__ h, const float* __restrict__ s_src,
    const float* __restrict__ s_dst, const int* __restrict__ offs,
    const int* __restrict__ csr_src, const float* __restrict__ bias,
    float* __restrict__ outp, int N) {
    int vtx = blockIdx.x;
    int beg = offs[vtx], end = offs[vtx + 1];
    int deg = end - beg;
    __shared__ float sc_lds[HEADS * SCSTR];
    __shared__ int   u_lds[CAP];
    __shared__ float red[3][HID];
    __shared__ float mxs[HEADS], invs[HEADS], sdvs[HEADS];
    int tid = threadIdx.x;
    int w = tid >> 6, l = tid & 63;
    int head = tid >> 5, el = tid & 31;
    if (tid < HEADS) sdvs[tid] = s_dst[vtx * HEADS + tid];
    float sdv = s_dst[vtx * HEADS + head];

    // pass A: online max/sum per head; cache u + raw scores
    float mval = -3.0e38f, sval = 0.f;
    for (int e = el; e < deg; e += 32) {
        int u = csr_src[beg + e];
        if (head == 0 && e < CAP) u_lds[e] = u;
        float sc = lrelu(s_src[u * HEADS + head] + sdv);
        if (e < CAP) sc_lds[head * SCSTR + e] = sc;
        float nm = fmaxf(mval, sc);
        sval = sval * __expf(mval - nm) + __expf(sc - nm);
        mval = nm;
    }
#pragma unroll
    for (int msk = 16; msk >= 1; msk >>= 1) {
        float om = __shfl_xor(mval, msk);
        float os = __shfl_xor(sval, msk);
        float nm = fmaxf(mval, om);
        sval = sval * __expf(mval - nm) + os * __expf(om - nm);
        mval = nm;
    }
    if (el == 0) { mxs[head] = mval; invs[head] = 1.f / sval; }
    __syncthreads();

    // normalize scores -> alphas
    int dc = min(deg, CAP);
    for (int idx = tid; idx < dc * HEADS; idx += 256) {
        int e = idx >> 3, hh = idx & 7;
        float scv = sc_lds[hh * SCSTR + e];
        sc_lds[hh * SCSTR + e] = __expf(scv - mxs[hh]) * invs[hh];
    }
    __syncthreads();

    // pass B: wave w takes edges e = w, w+4, ...; lane owns cols 4l..4l+3
    int hd = l >> 3;
    float4 acc = {0.f, 0.f, 0.f, 0.f};
    for (int e = w; e < dc; e += 4) {
        int u = u_lds[e];
        float al = sc_lds[hd * SCSTR + e];
        uint2 hv = *(const uint2*)&h[(size_t)u * HID + 4 * l];
        float f0 = __uint_as_float(hv.x << 16);
        float f1 = __uint_as_float(hv.x & 0xffff0000u);
        float f2 = __uint_as_float(hv.y << 16);
        float f3 = __uint_as_float(hv.y & 0xffff0000u);
        acc.x = fmaf(al, f0, acc.x);
        acc.y = fmaf(al, f1, acc.y);
        acc.z = fmaf(al, f2, acc.z);
        acc.w = fmaf(al, f3, acc.w);
    }
    if (deg > CAP) {   // fallback (never for this graph)
        float mh = mxs[hd], inv = invs[hd], sdh = sdvs[hd];
        for (int e = CAP + w; e < deg; e += 4) {
            int u = csr_src[beg + e];
            float sc = lrelu(s_src[u * HEADS + hd] + sdh);
            float al = __expf(sc - mh) * inv;
            uint2 hv = *(const uint2*)&h[(size_t)u * HID + 4 * l];
            acc.x = fmaf(al, __uint_as_float(hv.x << 16), acc.x);
            acc.y = fmaf(al, __uint_as_float(hv.x & 0xffff0000u), acc.y);
            acc.z = fmaf(al, __uint_as_float(hv.y << 16), acc.z);
            acc.w = fmaf(al, __uint_as_float(hv.y & 0xffff0000u), acc.w);
        }
    }
    if (w > 0) *(float4*)&red[w - 1][4 * l] = acc;
    __syncthreads();
    if (w == 0) {
        float4 r0 = *(const float4*)&red[0][4 * l];
        float4 r1 = *(const float4*)&red[1][4 * l];
        float4 r2 = *(const float4*)&red[2][4 * l];
        float4 bb = *(const float4*)&bias[4 * l];
        float4 o;
        o.x = eluf(acc.x + r0.x + r1.x + r2.x + bb.x);
        o.y = eluf(acc.y + r0.y + r1.y + r2.y + bb.y);
        o.z = eluf(acc.z + r0.z + r1.z + r2.z + bb.z);
        o.w = eluf(acc.w + r0.w + r1.w + r2.w + bb.w);
        *(float4*)&outp[(size_t)vtx * HID + 4 * l] = o;
    }
}

// ---------------- head: q = [t|x] @ hfrag + c'; out = relu(q) @ p2_W + p2_b ----------
__global__ __launch_bounds__(256) void final_mfma(
    const float* __restrict__ t_in, const float* __restrict__ x,
    const unsigned short* __restrict__ hf, const float* __restrict__ cp,
    const float* __restrict__ p2_W, const float* __restrict__ p2_b,
    float* __restrict__ outp, int N) {
    constexpr int KT = 10;
    __shared__ unsigned short xfrag[KT * 4 * 64 * 8];
    int tid = threadIdx.x;
    int w = tid >> 6, l = tid & 63;
    int gg = l >> 4, li = l & 15;
    int base = blockIdx.x * 64;

    for (int id = tid; id < 64 * 40; id += 256) {
        int r = id / 40, o = id % 40;
        int node = min(base + r, N - 1);
        const float* p = (o < 32) ? &t_in[(size_t)node * HID + o * 8]
                                  : &x[(size_t)node * 64 + (o - 32) * 8];
        float4 f0 = *(const float4*)p;
        float4 f1 = *(const float4*)(p + 4);
        uint4 pkv;
        pkv.x = pk2(f0.x, f0.y);
        pkv.y = pk2(f0.z, f0.w);
        pkv.z = pk2(f1.x, f1.y);
        pkv.w = pk2(f1.z, f1.w);
        int kt = o >> 2, og = o & 3, nt = r >> 4;
        *(uint4*)&xfrag[(((kt * 4 + nt) * 64) + (r & 15) + 16 * og) * 8] = pkv;
    }
    __syncthreads();

    f32x4 acc[2];
#pragma unroll
    for (int mt = 0; mt < 2; ++mt) {
        float4 cv = *(const float4*)&cp[mt * 16 + 4 * gg];
        acc[mt][0] = cv.x; acc[mt][1] = cv.y; acc[mt][2] = cv.z; acc[mt][3] = cv.w;
    }

    for (int kt = 0; kt < KT; ++kt) {
        sv8 b = *(const sv8*)&xfrag[((kt * 4 + w) * 64 + l) * 8];
#pragma unroll
        for (int mt = 0; mt < 2; ++mt) {
            sv8 a = *(const sv8*)&hf[((size_t)(kt * 2 + mt) * 64 + l) * 8];
            acc[mt] = __builtin_amdgcn_mfma_f32_16x16x32_bf16(a, b, acc[mt], 0, 0, 0);
        }
    }

    float po = 0.f;
#pragma unroll
    for (int mt = 0; mt < 2; ++mt) {
        float4 p2v = *(const float4*)&p2_W[mt * 16 + 4 * gg];
        po += fmaxf(acc[mt][0], 0.f) * p2v.x;
        po += fmaxf(acc[mt][1], 0.f) * p2v.y;
        po += fmaxf(acc[mt][2], 0.f) * p2v.z;
        po += fmaxf(acc[mt][3], 0.f) * p2v.w;
    }
    po += __shfl_xor(po, 16);
    po += __shfl_xor(po, 32);
    int node = base + 16 * w + li;
    if (gg == 0 && node < N) outp[node] = po + p2_b[0];
}

// ---------------- launch ----------------

extern "C" void kernel_launch(void* const* d_in, const int* in_sizes, int n_in,
                              void* d_out, int out_size, void* d_ws, size_t ws_size,
                              hipStream_t stream) {
    const float* x      = (const float*)d_in[0];
    const int*   ei     = (const int*)  d_in[1];
    const float* bn1_g  = (const float*)d_in[2];
    const float* bn1_b  = (const float*)d_in[3];
    const float* bn1_m  = (const float*)d_in[4];
    const float* bn1_v  = (const float*)d_in[5];
    const float* W1     = (const float*)d_in[6];
    const float* a1_src = (const float*)d_in[7];
    const float* a1_dst = (const float*)d_in[8];
    const float* b1     = (const float*)d_in[9];
    const float* bn2_g  = (const float*)d_in[10];
    const float* bn2_b  = (const float*)d_in[11];
    const float* bn2_m  = (const float*)d_in[12];
    const float* bn2_v  = (const float*)d_in[13];
    const float* W2     = (const float*)d_in[14];
    const float* a2_src = (const float*)d_in[15];
    const float* a2_dst = (const float*)d_in[16];
    const float* b2     = (const float*)d_in[17];
    const float* bn3_g  = (const float*)d_in[18];
    const float* bn3_b  = (const float*)d_in[19];
    const float* bn3_m  = (const float*)d_in[20];
    const float* bn3_v  = (const float*)d_in[21];
    const float* skip_W = (const float*)d_in[22];
    const float* skip_b = (const float*)d_in[23];
    const float* p1_W   = (const float*)d_in[24];
    const float* p1_b   = (const float*)d_in[25];
    const float* p2_W   = (const float*)d_in[26];
    const float* p2_b   = (const float*)d_in[27];

    int N = in_sizes[0] / 64;
    int E = in_sizes[1] / 2;
    int EE = E + N;

    uintptr_t w = (uintptr_t)d_ws;
    auto carve = [&](size_t bytes) -> void* {
        uintptr_t p = w;
        w += (bytes + 255) & ~(size_t)255;
        return (void*)p;
    };
    int*   deg  = (int*)carve((size_t)N * 4);
    int*   cur  = (int*)carve((size_t)N * 4);
    int*   offs = (int*)carve(((size_t)N + 1) * 4);
    int*   csr  = (int*)carve((size_t)EE * 4);
    float* ssrc = (float*)carve((size_t)N * HEADS * 4);
    float* sdst = (float*)carve((size_t)N * HEADS * 4);
    unsigned short* wf1 = (unsigned short*)carve((size_t)2 * 16 * 64 * 8 * 2);
    unsigned short* wf2 = (unsigned short*)carve((size_t)8 * 16 * 64 * 8 * 2);
    unsigned short* hf  = (unsigned short*)carve((size_t)20 * 64 * 8 * 2);
    float* c1   = (float*)carve((size_t)HID * 4);
    float* c2   = (float*)carve((size_t)HID * 4);
    float* Sp   = (float*)carve((size_t)64 * 32 * 4);
    float* cp   = (float*)carve((size_t)32 * 4);
    unsigned short* hbf = (unsigned short*)carve((size_t)N * HID * 2);
    float* tbuf = (float*)carve((size_t)N * HID * 4);

    hipMemsetAsync(deg, 0, (size_t)N * 4, stream);
    hipMemsetAsync(cur, 0, (size_t)N * 4, stream);

    // fragment pregen + folds
    wfrag_kernel<<<2 * 16, 64, 0, stream>>>(W1, bn1_g, bn1_v, wf1);
    wfrag_kernel<<<8 * 16, 64, 0, stream>>>(W2, bn2_g, bn2_v, wf2);
    fold_c_kernel<<<1, 256, 0, stream>>>(W1, bn1_g, bn1_b, bn1_m, bn1_v, c1, 64);
    fold_c_kernel<<<1, 256, 0, stream>>>(W2, bn2_g, bn2_b, bn2_m, bn2_v, c2, HID);
    sfold_kernel<<<64, 32, 0, stream>>>(skip_W, p1_W, Sp);
    cfold_kernel<<<1, 32, 0, stream>>>(bn3_g, bn3_b, bn3_m, bn3_v, skip_b,
                                       p1_W, p1_b, cp);
    hfrag_kernel<<<20, 64, 0, stream>>>(p1_W, bn3_g, bn3_v, Sp, hf);

    // CSR
    int eblk = (EE + 255) / 256;
    degree_kernel<<<eblk, 256, 0, stream>>>(ei, deg, E, EE);
    scan_kernel<<<1, 1024, 0, stream>>>(deg, offs, N);
    scatter_kernel<<<eblk, 256, 0, stream>>>(ei, offs, cur, csr, E, EE);

    int gblk = (N + 63) / 64;
    // layer 1
    gemm_mfma<64><<<gblk, 256, 0, stream>>>(x, wf1, c1, a1_src, a1_dst,
                                            hbf, ssrc, sdst, N);
    agg_kernel<<<N, 256, 0, stream>>>(hbf, ssrc, sdst, offs, csr, b1, tbuf, N);

    // layer 2
    gemm_mfma<HID><<<gblk, 256, 0, stream>>>(tbuf, wf2, c2, a2_src, a2_dst,
                                             hbf, ssrc, sdst, N);
    agg_kernel<<<N, 256, 0, stream>>>(hbf, ssrc, sdst, offs, csr, b2, tbuf, N);

    // head (fully folded)
    final_mfma<<<gblk, 256, 0, stream>>>(tbuf, x, hf, cp, p2_W, p2_b,
                                         (float*)d_out, N);
}

// Round 7
// 543.617 us; speedup vs baseline: 1.8794x; 1.0157x over previous
//
#include <hip/hip_runtime.h>
#include <hip/hip_bf16.h>
#include <math.h>
#include <stdint.h>

#define HID 256
#define HEADS 8
#define BN_EPS 1e-5f
#define NEG 0.2f
#define CAP 192
#define SCSTR 196

typedef short sv8  __attribute__((ext_vector_type(8)));
typedef float f32x4 __attribute__((ext_vector_type(4)));

__device__ __forceinline__ float lrelu(float x) { return x > 0.f ? x : NEG * x; }
__device__ __forceinline__ float eluf(float x)  { return x > 0.f ? x : expm1f(x); }

__device__ __forceinline__ unsigned short f2bf(float f) {
    unsigned int u = __float_as_uint(f);
    u = (u + 0x7fffu + ((u >> 16) & 1u)) >> 16;   // RNE
    return (unsigned short)u;
}
__device__ __forceinline__ unsigned int pk2(float lo, float hi) {
    return (unsigned int)f2bf(lo) | ((unsigned int)f2bf(hi) << 16);
}

// ---------------- CSR build ----------------

__global__ __launch_bounds__(256) void degree_kernel(const int* __restrict__ ei,
                                                     int* __restrict__ deg,
                                                     int E, int EE) {
    int e = blockIdx.x * 256 + threadIdx.x;
    if (e >= EE) return;
    int d = (e < E) ? ei[E + e] : (e - E);
    atomicAdd(&deg[d], 1);
}

__global__ __launch_bounds__(1024) void scan_kernel(const int* __restrict__ deg,
                                                    int* __restrict__ offs, int N) {
    __shared__ int part[1024];
    int t = threadIdx.x;
    int chunk = (N + 1023) >> 10;
    int c0 = t * chunk;
    int c1 = min(c0 + chunk, N);
    int s = 0;
    for (int j = c0; j < c1; ++j) s += deg[j];
    part[t] = s;
    __syncthreads();
    for (int d = 1; d < 1024; d <<= 1) {
        int vv = (t >= d) ? part[t - d] : 0;
        __syncthreads();
        part[t] += vv;
        __syncthreads();
    }
    int run = part[t] - s;
    for (int j = c0; j < c1; ++j) { offs[j] = run; run += deg[j]; }
    if (t == 1023) offs[N] = part[1023];
}

__global__ __launch_bounds__(256) void scatter_kernel(const int* __restrict__ ei,
                                                      const int* __restrict__ offs,
                                                      int* __restrict__ cur,
                                                      int* __restrict__ csr_src,
                                                      int E, int EE) {
    int e = blockIdx.x * 256 + threadIdx.x;
    if (e >= EE) return;
    int s = (e < E) ? ei[e] : (e - E);
    int d = (e < E) ? ei[E + e] : (e - E);
    int pos = offs[d] + atomicAdd(&cur[d], 1);
    csr_src[pos] = s;
}

// ---------------- W' fragment pregen (layer GEMMs) ----------------
__global__ __launch_bounds__(64) void wfrag_kernel(const float* __restrict__ W,
                                                   const float* __restrict__ g,
                                                   const float* __restrict__ v,
                                                   unsigned short* __restrict__ frag) {
    int tile = blockIdx.x;
    int ct = tile & 15, kt = tile >> 4;
    int l = threadIdx.x;
    int c = ct * 16 + (l & 15);
    int k0 = kt * 32 + (l >> 4) * 8;
    float val[8];
#pragma unroll
    for (int j = 0; j < 8; ++j) {
        float s = g[k0 + j] * rsqrtf(v[k0 + j] + BN_EPS);
        val[j] = W[(size_t)(k0 + j) * HID + c] * s;
    }
    uint4 o;
    o.x = pk2(val[0], val[1]);
    o.y = pk2(val[2], val[3]);
    o.z = pk2(val[4], val[5]);
    o.w = pk2(val[6], val[7]);
    *(uint4*)&frag[((size_t)tile * 64 + l) * 8] = o;
}

__global__ __launch_bounds__(256) void fold_c_kernel(const float* __restrict__ W,
                                                     const float* __restrict__ g,
                                                     const float* __restrict__ b,
                                                     const float* __restrict__ m,
                                                     const float* __restrict__ v,
                                                     float* __restrict__ cvec, int K) {
    int j = threadIdx.x;
    float acc = 0.f;
    for (int k = 0; k < K; ++k) {
        float s = g[k] * rsqrtf(v[k] + BN_EPS);
        acc = fmaf(b[k] - m[k] * s, W[(size_t)k * HID + j], acc);
    }
    cvec[j] = acc;
}

// ---------------- head folds ----------------
__global__ __launch_bounds__(32) void sfold_kernel(const float* __restrict__ skip_W,
                                                   const float* __restrict__ p1_W,
                                                   float* __restrict__ Sp) {
    int cx = blockIdx.x, j = threadIdx.x;
    float acc = 0.f;
    for (int c = 0; c < HID; ++c)
        acc = fmaf(skip_W[(size_t)cx * HID + c], p1_W[c * 32 + j], acc);
    Sp[cx * 32 + j] = acc;
}

__global__ __launch_bounds__(32) void cfold_kernel(const float* __restrict__ g3,
                                                   const float* __restrict__ b3,
                                                   const float* __restrict__ m3,
                                                   const float* __restrict__ v3,
                                                   const float* __restrict__ skip_b,
                                                   const float* __restrict__ p1_W,
                                                   const float* __restrict__ p1_b,
                                                   float* __restrict__ cp) {
    int j = threadIdx.x;
    float acc = p1_b[j];
    for (int c = 0; c < HID; ++c) {
        float s3 = g3[c] * rsqrtf(v3[c] + BN_EPS);
        acc = fmaf(b3[c] - m3[c] * s3 + skip_b[c], p1_W[c * 32 + j], acc);
    }
    cp[j] = acc;
}

__global__ __launch_bounds__(64) void hfrag_kernel(const float* __restrict__ p1_W,
                                                   const float* __restrict__ g3,
                                                   const float* __restrict__ v3,
                                                   const float* __restrict__ Sp,
                                                   unsigned short* __restrict__ frag) {
    int tile = blockIdx.x;
    int mt = tile & 1, kt = tile >> 1;
    int l = threadIdx.x;
    int j = mt * 16 + (l & 15);
    int k0 = kt * 32 + (l >> 4) * 8;
    float val[8];
#pragma unroll
    for (int jj = 0; jj < 8; ++jj) {
        int c = k0 + jj;
        if (c < HID) {
            float s3 = g3[c] * rsqrtf(v3[c] + BN_EPS);
            val[jj] = s3 * p1_W[c * 32 + j];
        } else {
            val[jj] = Sp[(c - HID) * 32 + j];
        }
    }
    uint4 o;
    o.x = pk2(val[0], val[1]);
    o.y = pk2(val[2], val[3]);
    o.z = pk2(val[4], val[5]);
    o.w = pk2(val[6], val[7]);
    *(uint4*)&frag[((size_t)tile * 64 + l) * 8] = o;
}

// ---------------- MFMA GEMM (swapped): D[wcol][node] = W'^T-op x X-op ----------------
template <int K>
__global__ __launch_bounds__(256) void gemm_mfma(
    const float* __restrict__ in, const unsigned short* __restrict__ wfrag,
    const float* __restrict__ cvec,
    const float* __restrict__ a_src, const float* __restrict__ a_dst,
    unsigned short* __restrict__ h, float* __restrict__ s_src,
    float* __restrict__ s_dst, int N) {
    constexpr int KT = K / 32;
    constexpr int OPR = K / 8;
    __shared__ unsigned short xfrag[KT * 4 * 64 * 8];
    int tid = threadIdx.x;
    int w = tid >> 6, l = tid & 63;
    int gg = l >> 4, li = l & 15;
    int base = blockIdx.x * 64;

    for (int id = tid; id < 64 * OPR; id += 256) {
        int r = id / OPR, o = id % OPR;
        int node = min(base + r, N - 1);
        const float* p = &in[(size_t)node * K + o * 8];
        float4 f0 = *(const float4*)p;
        float4 f1 = *(const float4*)(p + 4);
        uint4 pkv;
        pkv.x = pk2(f0.x, f0.y);
        pkv.y = pk2(f0.z, f0.w);
        pkv.z = pk2(f1.x, f1.y);
        pkv.w = pk2(f1.z, f1.w);
        int kt = o >> 2, og = o & 3, nt = r >> 4;
        *(uint4*)&xfrag[(((kt * 4 + nt) * 64) + (r & 15) + 16 * og) * 8] = pkv;
    }
    __syncthreads();

    f32x4 acc[4][4];
#pragma unroll
    for (int mm = 0; mm < 4; ++mm) {
        float4 cv = *(const float4*)&cvec[64 * w + 16 * mm + 4 * gg];
#pragma unroll
        for (int nn = 0; nn < 4; ++nn) {
            acc[mm][nn][0] = cv.x; acc[mm][nn][1] = cv.y;
            acc[mm][nn][2] = cv.z; acc[mm][nn][3] = cv.w;
        }
    }

    for (int ks = 0; ks < KT; ++ks) {
        sv8 a[4], b[4];
#pragma unroll
        for (int mm = 0; mm < 4; ++mm)
            a[mm] = *(const sv8*)&wfrag[((size_t)(ks * 16 + w * 4 + mm) * 64 + l) * 8];
#pragma unroll
        for (int nn = 0; nn < 4; ++nn)
            b[nn] = *(const sv8*)&xfrag[((ks * 4 + nn) * 64 + l) * 8];
#pragma unroll
        for (int mm = 0; mm < 4; ++mm)
#pragma unroll
            for (int nn = 0; nn < 4; ++nn)
                acc[mm][nn] = __builtin_amdgcn_mfma_f32_16x16x32_bf16(
                    a[mm], b[nn], acc[mm][nn], 0, 0, 0);
    }

    float svp[4][2], sdp[4][2];
#pragma unroll
    for (int nn = 0; nn < 4; ++nn) { svp[nn][0]=0.f; svp[nn][1]=0.f; sdp[nn][0]=0.f; sdp[nn][1]=0.f; }

#pragma unroll
    for (int mm = 0; mm < 4; ++mm) {
        int cb = 64 * w + 16 * mm + 4 * gg;
        float4 as4 = *(const float4*)&a_src[cb];
        float4 ad4 = *(const float4*)&a_dst[cb];
        int hp = mm >> 1;
#pragma unroll
        for (int nn = 0; nn < 4; ++nn) {
            f32x4 A = acc[mm][nn];
            svp[nn][hp] += A[0]*as4.x + A[1]*as4.y + A[2]*as4.z + A[3]*as4.w;
            sdp[nn][hp] += A[0]*ad4.x + A[1]*ad4.y + A[2]*ad4.z + A[3]*ad4.w;
            int node = base + 16 * nn + li;
            if (node < N) {
                ushort4 pkv;
                pkv.x = f2bf(A[0]); pkv.y = f2bf(A[1]);
                pkv.z = f2bf(A[2]); pkv.w = f2bf(A[3]);
                *(ushort4*)&h[(size_t)node * HID + cb] = pkv;
            }
        }
    }
#pragma unroll
    for (int nn = 0; nn < 4; ++nn)
#pragma unroll
        for (int hp = 0; hp < 2; ++hp) {
            svp[nn][hp] += __shfl_xor(svp[nn][hp], 16);
            svp[nn][hp] += __shfl_xor(svp[nn][hp], 32);
            sdp[nn][hp] += __shfl_xor(sdp[nn][hp], 16);
            sdp[nn][hp] += __shfl_xor(sdp[nn][hp], 32);
        }
    if (gg == 0) {
#pragma unroll
        for (int nn = 0; nn < 4; ++nn) {
            int node = base + 16 * nn + li;
            if (node < N) {
#pragma unroll
                for (int hp = 0; hp < 2; ++hp) {
                    s_src[node * HEADS + 2 * w + hp] = svp[nn][hp];
                    s_dst[node * HEADS + 2 * w + hp] = sdp[nn][hp];
                }
            }
        }
    }
}

// ---------------- per-dst segment softmax + aggregation + bias + ELU ----------------
// pass A: two-pass softmax (max-butterfly, then ONE exp per edge-head, sum-butterfly).
// pass B: waves split edges, lane owns 4 cols, deferred 1/sum normalization.
__global__ __launch_bounds__(256) void agg_kernel(
    const unsigned short* __restrict__ h, const float* __restrict__ s_src,
    const float* __restrict__ s_dst, const int* __restrict__ offs,
    const int* __restrict__ csr_src, const float* __restrict__ bias,
    float* __restrict__ outp, int N) {
    int vtx = blockIdx.x;
    int beg = offs[vtx], end = offs[vtx + 1];
    int deg = end - beg;
    __shared__ float sc_lds[HEADS * SCSTR];   // raw scores, then exp(sc-mx)
    __shared__ int   u_lds[CAP];
    __shared__ float red[3][HID];
    __shared__ float mxs[HEADS], invs[HEADS], sdvs[HEADS];
    int tid = threadIdx.x;
    int w = tid >> 6, l = tid & 63;
    int head = tid >> 5, el = tid & 31;
    if (tid < HEADS) sdvs[tid] = s_dst[vtx * HEADS + tid];
    float sdv = s_dst[vtx * HEADS + head];

    // max pass (no exp)
    float mval = -3.0e38f;
    for (int e = el; e < deg; e += 32) {
        int u = csr_src[beg + e];
        if (head == 0 && e < CAP) u_lds[e] = u;
        float sc = lrelu(s_src[u * HEADS + head] + sdv);
        if (e < CAP) sc_lds[head * SCSTR + e] = sc;
        mval = fmaxf(mval, sc);
    }
#pragma unroll
    for (int msk = 16; msk >= 1; msk >>= 1)
        mval = fmaxf(mval, __shfl_xor(mval, msk));

    // exp+sum pass: exactly one exp per (edge, head)
    float sval = 0.f;
    for (int e = el; e < deg; e += 32) {
        float sc;
        if (e < CAP) {
            sc = sc_lds[head * SCSTR + e];          // own write, no barrier needed
        } else {
            int u = csr_src[beg + e];
            sc = lrelu(s_src[u * HEADS + head] + sdv);
        }
        float p = __expf(sc - mval);
        if (e < CAP) sc_lds[head * SCSTR + e] = p;  // unnormalized alpha
        sval += p;
    }
#pragma unroll
    for (int msk = 16; msk >= 1; msk >>= 1)
        sval += __shfl_xor(sval, msk);
    if (el == 0) { mxs[head] = mval; invs[head] = 1.f / sval; }
    __syncthreads();

    // pass B: wave w takes edges e = w, w+4, ...; lane owns cols 4l..4l+3
    int hd = l >> 3;
    int dc = min(deg, CAP);
    float4 acc = {0.f, 0.f, 0.f, 0.f};
    for (int e = w; e < dc; e += 4) {
        int u = u_lds[e];
        float al = sc_lds[hd * SCSTR + e];
        uint2 hv = *(const uint2*)&h[(size_t)u * HID + 4 * l];
        acc.x = fmaf(al, __uint_as_float(hv.x << 16), acc.x);
        acc.y = fmaf(al, __uint_as_float(hv.x & 0xffff0000u), acc.y);
        acc.z = fmaf(al, __uint_as_float(hv.y << 16), acc.z);
        acc.w = fmaf(al, __uint_as_float(hv.y & 0xffff0000u), acc.w);
    }
    if (deg > CAP) {   // fallback (never for this graph)
        float mh = mxs[hd], sdh = sdvs[hd];
        for (int e = CAP + w; e < deg; e += 4) {
            int u = csr_src[beg + e];
            float sc = lrelu(s_src[u * HEADS + hd] + sdh);
            float al = __expf(sc - mh);
            uint2 hv = *(const uint2*)&h[(size_t)u * HID + 4 * l];
            acc.x = fmaf(al, __uint_as_float(hv.x << 16), acc.x);
            acc.y = fmaf(al, __uint_as_float(hv.x & 0xffff0000u), acc.y);
            acc.z = fmaf(al, __uint_as_float(hv.y << 16), acc.z);
            acc.w = fmaf(al, __uint_as_float(hv.y & 0xffff0000u), acc.w);
        }
    }
    if (w > 0) *(float4*)&red[w - 1][4 * l] = acc;
    __syncthreads();
    if (w == 0) {
        float4 r0 = *(const float4*)&red[0][4 * l];
        float4 r1 = *(const float4*)&red[1][4 * l];
        float4 r2 = *(const float4*)&red[2][4 * l];
        float4 bb = *(const float4*)&bias[4 * l];
        float inv = invs[hd];
        float4 o;
        o.x = eluf((acc.x + r0.x + r1.x + r2.x) * inv + bb.x);
        o.y = eluf((acc.y + r0.y + r1.y + r2.y) * inv + bb.y);
        o.z = eluf((acc.z + r0.z + r1.z + r2.z) * inv + bb.z);
        o.w = eluf((acc.w + r0.w + r1.w + r2.w) * inv + bb.w);
        *(float4*)&outp[(size_t)vtx * HID + 4 * l] = o;
    }
}

// ---------------- head: q = [t|x] @ hfrag + c'; out = relu(q) @ p2_W + p2_b ----------
__global__ __launch_bounds__(256) void final_mfma(
    const float* __restrict__ t_in, const float* __restrict__ x,
    const unsigned short* __restrict__ hf, const float* __restrict__ cp,
    const float* __restrict__ p2_W, const float* __restrict__ p2_b,
    float* __restrict__ outp, int N) {
    constexpr int KT = 10;
    __shared__ unsigned short xfrag[KT * 4 * 64 * 8];
    int tid = threadIdx.x;
    int w = tid >> 6, l = tid & 63;
    int gg = l >> 4, li = l & 15;
    int base = blockIdx.x * 64;

    for (int id = tid; id < 64 * 40; id += 256) {
        int r = id / 40, o = id % 40;
        int node = min(base + r, N - 1);
        const float* p = (o < 32) ? &t_in[(size_t)node * HID + o * 8]
                                  : &x[(size_t)node * 64 + (o - 32) * 8];
        float4 f0 = *(const float4*)p;
        float4 f1 = *(const float4*)(p + 4);
        uint4 pkv;
        pkv.x = pk2(f0.x, f0.y);
        pkv.y = pk2(f0.z, f0.w);
        pkv.z = pk2(f1.x, f1.y);
        pkv.w = pk2(f1.z, f1.w);
        int kt = o >> 2, og = o & 3, nt = r >> 4;
        *(uint4*)&xfrag[(((kt * 4 + nt) * 64) + (r & 15) + 16 * og) * 8] = pkv;
    }
    __syncthreads();

    f32x4 acc[2];
#pragma unroll
    for (int mt = 0; mt < 2; ++mt) {
        float4 cv = *(const float4*)&cp[mt * 16 + 4 * gg];
        acc[mt][0] = cv.x; acc[mt][1] = cv.y; acc[mt][2] = cv.z; acc[mt][3] = cv.w;
    }

    for (int kt = 0; kt < KT; ++kt) {
        sv8 b = *(const sv8*)&xfrag[((kt * 4 + w) * 64 + l) * 8];
#pragma unroll
        for (int mt = 0; mt < 2; ++mt) {
            sv8 a = *(const sv8*)&hf[((size_t)(kt * 2 + mt) * 64 + l) * 8];
            acc[mt] = __builtin_amdgcn_mfma_f32_16x16x32_bf16(a, b, acc[mt], 0, 0, 0);
        }
    }

    float po = 0.f;
#pragma unroll
    for (int mt = 0; mt < 2; ++mt) {
        float4 p2v = *(const float4*)&p2_W[mt * 16 + 4 * gg];
        po += fmaxf(acc[mt][0], 0.f) * p2v.x;
        po += fmaxf(acc[mt][1], 0.f) * p2v.y;
        po += fmaxf(acc[mt][2], 0.f) * p2v.z;
        po += fmaxf(acc[mt][3], 0.f) * p2v.w;
    }
    po += __shfl_xor(po, 16);
    po += __shfl_xor(po, 32);
    int node = base + 16 * w + li;
    if (gg == 0 && node < N) outp[node] = po + p2_b[0];
}

// ---------------- launch ----------------

extern "C" void kernel_launch(void* const* d_in, const int* in_sizes, int n_in,
                              void* d_out, int out_size, void* d_ws, size_t ws_size,
                              hipStream_t stream) {
    const float* x      = (const float*)d_in[0];
    const int*   ei     = (const int*)  d_in[1];
    const float* bn1_g  = (const float*)d_in[2];
    const float* bn1_b  = (const float*)d_in[3];
    const float* bn1_m  = (const float*)d_in[4];
    const float* bn1_v  = (const float*)d_in[5];
    const float* W1     = (const float*)d_in[6];
    const float* a1_src = (const float*)d_in[7];
    const float* a1_dst = (const float*)d_in[8];
    const float* b1     = (const float*)d_in[9];
    const float* bn2_g  = (const float*)d_in[10];
    const float* bn2_b  = (const float*)d_in[11];
    const float* bn2_m  = (const float*)d_in[12];
    const float* bn2_v  = (const float*)d_in[13];
    const float* W2     = (const float*)d_in[14];
    const float* a2_src = (const float*)d_in[15];
    const float* a2_dst = (const float*)d_in[16];
    const float* b2     = (const float*)d_in[17];
    const float* bn3_g  = (const float*)d_in[18];
    const float* bn3_b  = (const float*)d_in[19];
    const float* bn3_m  = (const float*)d_in[20];
    const float* bn3_v  = (const float*)d_in[21];
    const float* skip_W = (const float*)d_in[22];
    const float* skip_b = (const float*)d_in[23];
    const float* p1_W   = (const float*)d_in[24];
    const float* p1_b   = (const float*)d_in[25];
    const float* p2_W   = (const float*)d_in[26];
    const float* p2_b   = (const float*)d_in[27];

    int N = in_sizes[0] / 64;
    int E = in_sizes[1] / 2;
    int EE = E + N;

    uintptr_t w = (uintptr_t)d_ws;
    auto carve = [&](size_t bytes) -> void* {
        uintptr_t p = w;
        w += (bytes + 255) & ~(size_t)255;
        return (void*)p;
    };
    int*   deg  = (int*)carve((size_t)N * 4);
    int*   cur  = (int*)carve((size_t)N * 4);
    int*   offs = (int*)carve(((size_t)N + 1) * 4);
    int*   csr  = (int*)carve((size_t)EE * 4);
    float* ssrc = (float*)carve((size_t)N * HEADS * 4);
    float* sdst = (float*)carve((size_t)N * HEADS * 4);
    unsigned short* wf1 = (unsigned short*)carve((size_t)2 * 16 * 64 * 8 * 2);
    unsigned short* wf2 = (unsigned short*)carve((size_t)8 * 16 * 64 * 8 * 2);
    unsigned short* hf  = (unsigned short*)carve((size_t)20 * 64 * 8 * 2);
    float* c1   = (float*)carve((size_t)HID * 4);
    float* c2   = (float*)carve((size_t)HID * 4);
    float* Sp   = (float*)carve((size_t)64 * 32 * 4);
    float* cp   = (float*)carve((size_t)32 * 4);
    unsigned short* hbf = (unsigned short*)carve((size_t)N * HID * 2);
    float* tbuf = (float*)carve((size_t)N * HID * 4);

    hipMemsetAsync(deg, 0, (size_t)N * 4, stream);
    hipMemsetAsync(cur, 0, (size_t)N * 4, stream);

    // fragment pregen + folds
    wfrag_kernel<<<2 * 16, 64, 0, stream>>>(W1, bn1_g, bn1_v, wf1);
    wfrag_kernel<<<8 * 16, 64, 0, stream>>>(W2, bn2_g, bn2_v, wf2);
    fold_c_kernel<<<1, 256, 0, stream>>>(W1, bn1_g, bn1_b, bn1_m, bn1_v, c1, 64);
    fold_c_kernel<<<1, 256, 0, stream>>>(W2, bn2_g, bn2_b, bn2_m, bn2_v, c2, HID);
    sfold_kernel<<<64, 32, 0, stream>>>(skip_W, p1_W, Sp);
    cfold_kernel<<<1, 32, 0, stream>>>(bn3_g, bn3_b, bn3_m, bn3_v, skip_b,
                                       p1_W, p1_b, cp);
    hfrag_kernel<<<20, 64, 0, stream>>>(p1_W, bn3_g, bn3_v, Sp, hf);

    // CSR
    int eblk = (EE + 255) / 256;
    degree_kernel<<<eblk, 256, 0, stream>>>(ei, deg, E, EE);
    scan_kernel<<<1, 1024, 0, stream>>>(deg, offs, N);
    scatter_kernel<<<eblk, 256, 0, stream>>>(ei, offs, cur, csr, E, EE);

    int gblk = (N + 63) / 64;
    // layer 1
    gemm_mfma<64><<<gblk, 256, 0, stream>>>(x, wf1, c1, a1_src, a1_dst,
                                            hbf, ssrc, sdst, N);
    agg_kernel<<<N, 256, 0, stream>>>(hbf, ssrc, sdst, offs, csr, b1, tbuf, N);

    // layer 2
    gemm_mfma<HID><<<gblk, 256, 0, stream>>>(tbuf, wf2, c2, a2_src, a2_dst,
                                             hbf, ssrc, sdst, N);
    agg_kernel<<<N, 256, 0, stream>>>(hbf, ssrc, sdst, offs, csr, b2, tbuf, N);

    // head (fully folded)
    final_mfma<<<gblk, 256, 0, stream>>>(tbuf, x, hf, cp, p2_W, p2_b,
                                         (float*)d_out, N);
}

// Round 8
// 406.422 us; speedup vs baseline: 2.5138x; 1.3376x over previous
//
#include <hip/hip_runtime.h>
#include <hip/hip_bf16.h>
#include <math.h>
#include <stdint.h>

#define HID 256
#define HEADS 8
#define BN_EPS 1e-5f
#define NEG 0.2f
#define WCAP 96    // per-wave edge cache (deg ~ Poisson(16)+1; fallback beyond)

typedef short sv8  __attribute__((ext_vector_type(8)));
typedef float f32x4 __attribute__((ext_vector_type(4)));

__device__ __forceinline__ float lrelu(float x) { return x > 0.f ? x : NEG * x; }
__device__ __forceinline__ float eluf(float x)  { return x > 0.f ? x : expm1f(x); }

__device__ __forceinline__ unsigned short f2bf(float f) {
    unsigned int u = __float_as_uint(f);
    u = (u + 0x7fffu + ((u >> 16) & 1u)) >> 16;   // RNE
    return (unsigned short)u;
}
__device__ __forceinline__ unsigned int pk2(float lo, float hi) {
    return (unsigned int)f2bf(lo) | ((unsigned int)f2bf(hi) << 16);
}

// ---------------- CSR build ----------------

__global__ __launch_bounds__(256) void degree_kernel(const int* __restrict__ ei,
                                                     int* __restrict__ deg,
                                                     int E, int EE) {
    int e = blockIdx.x * 256 + threadIdx.x;
    if (e >= EE) return;
    int d = (e < E) ? ei[E + e] : (e - E);
    atomicAdd(&deg[d], 1);
}

__global__ __launch_bounds__(1024) void scan_kernel(const int* __restrict__ deg,
                                                    int* __restrict__ offs, int N) {
    __shared__ int part[1024];
    int t = threadIdx.x;
    int chunk = (N + 1023) >> 10;
    int c0 = t * chunk;
    int c1 = min(c0 + chunk, N);
    int s = 0;
    for (int j = c0; j < c1; ++j) s += deg[j];
    part[t] = s;
    __syncthreads();
    for (int d = 1; d < 1024; d <<= 1) {
        int vv = (t >= d) ? part[t - d] : 0;
        __syncthreads();
        part[t] += vv;
        __syncthreads();
    }
    int run = part[t] - s;
    for (int j = c0; j < c1; ++j) { offs[j] = run; run += deg[j]; }
    if (t == 1023) offs[N] = part[1023];
}

__global__ __launch_bounds__(256) void scatter_kernel(const int* __restrict__ ei,
                                                      const int* __restrict__ offs,
                                                      int* __restrict__ cur,
                                                      int* __restrict__ csr_src,
                                                      int E, int EE) {
    int e = blockIdx.x * 256 + threadIdx.x;
    if (e >= EE) return;
    int s = (e < E) ? ei[e] : (e - E);
    int d = (e < E) ? ei[E + e] : (e - E);
    int pos = offs[d] + atomicAdd(&cur[d], 1);
    csr_src[pos] = s;
}

// ---------------- fused prologue: all weight prep in one launch ----------------
// fragment layout (verified R3-R6): tile per 16-col x 32-k; lane l holds
// M[k0 + 8*(l>>4) + j][c0 + (l&15)], j=0..7, packed bf16x8.

__device__ __forceinline__ void wfrag_body(const float* __restrict__ W,
                                           const float* __restrict__ g,
                                           const float* __restrict__ v,
                                           unsigned short* __restrict__ frag,
                                           int tile, int l) {
    int ct = tile & 15, kt = tile >> 4;
    int c = ct * 16 + (l & 15);
    int k0 = kt * 32 + (l >> 4) * 8;
    float val[8];
#pragma unroll
    for (int j = 0; j < 8; ++j) {
        float s = g[k0 + j] * rsqrtf(v[k0 + j] + BN_EPS);
        val[j] = W[(size_t)(k0 + j) * HID + c] * s;
    }
    uint4 o;
    o.x = pk2(val[0], val[1]);
    o.y = pk2(val[2], val[3]);
    o.z = pk2(val[4], val[5]);
    o.w = pk2(val[6], val[7]);
    *(uint4*)&frag[((size_t)tile * 64 + l) * 8] = o;
}

__global__ __launch_bounds__(256) void prep_kernel(
    const float* __restrict__ W1, const float* __restrict__ bn1_g,
    const float* __restrict__ bn1_b, const float* __restrict__ bn1_m,
    const float* __restrict__ bn1_v,
    const float* __restrict__ W2, const float* __restrict__ bn2_g,
    const float* __restrict__ bn2_b, const float* __restrict__ bn2_m,
    const float* __restrict__ bn2_v,
    const float* __restrict__ g3, const float* __restrict__ b3,
    const float* __restrict__ m3, const float* __restrict__ v3,
    const float* __restrict__ skip_W, const float* __restrict__ skip_b,
    const float* __restrict__ p1_W, const float* __restrict__ p1_b,
    unsigned short* __restrict__ wf1, unsigned short* __restrict__ wf2,
    unsigned short* __restrict__ hf, float* __restrict__ c1,
    float* __restrict__ c2, float* __restrict__ cp) {
    int b = blockIdx.x;
    int tid = threadIdx.x;
    int sub = tid >> 6, l = tid & 63;

    if (b < 8) {                       // wf1: 32 tiles (K=64)
        wfrag_body(W1, bn1_g, bn1_v, wf1, b * 4 + sub, l);
    } else if (b < 40) {               // wf2: 128 tiles (K=256)
        wfrag_body(W2, bn2_g, bn2_v, wf2, (b - 8) * 4 + sub, l);
    } else if (b < 45) {               // hf: 20 tiles, K=320 ([t|x] concat)
        int tile = (b - 40) * 4 + sub;
        int mt = tile & 1, kt = tile >> 1;
        int j = mt * 16 + (l & 15);
        int k0 = kt * 32 + (l >> 4) * 8;
        float val[8];
#pragma unroll
        for (int jj = 0; jj < 8; ++jj) {
            int c = k0 + jj;
            if (c < HID) {
                float s3 = g3[c] * rsqrtf(v3[c] + BN_EPS);
                val[jj] = s3 * p1_W[c * 32 + j];
            } else {                   // S' = skip_W @ p1_W computed inline
                float acc = 0.f;
                for (int cc = 0; cc < HID; ++cc)
                    acc = fmaf(skip_W[(size_t)(c - HID) * HID + cc],
                               p1_W[cc * 32 + j], acc);
                val[jj] = acc;
            }
        }
        uint4 o;
        o.x = pk2(val[0], val[1]);
        o.y = pk2(val[2], val[3]);
        o.z = pk2(val[4], val[5]);
        o.w = pk2(val[6], val[7]);
        *(uint4*)&hf[((size_t)tile * 64 + l) * 8] = o;
    } else if (b == 45) {              // c1 = (b1 - m1*s1) @ W1
        float acc = 0.f;
        for (int k = 0; k < 64; ++k) {
            float s = bn1_g[k] * rsqrtf(bn1_v[k] + BN_EPS);
            acc = fmaf(bn1_b[k] - bn1_m[k] * s, W1[(size_t)k * HID + tid], acc);
        }
        c1[tid] = acc;
    } else if (b == 46) {              // c2
        float acc = 0.f;
        for (int k = 0; k < HID; ++k) {
            float s = bn2_g[k] * rsqrtf(bn2_v[k] + BN_EPS);
            acc = fmaf(bn2_b[k] - bn2_m[k] * s, W2[(size_t)k * HID + tid], acc);
        }
        c2[tid] = acc;
    } else {                           // cp = (b3 - m3*s3 + skip_b) @ p1_W + p1_b
        if (tid < 32) {
            float acc = p1_b[tid];
            for (int c = 0; c < HID; ++c) {
                float s3 = g3[c] * rsqrtf(v3[c] + BN_EPS);
                acc = fmaf(b3[c] - m3[c] * s3 + skip_b[c], p1_W[c * 32 + tid], acc);
            }
            cp[tid] = acc;
        }
    }
}

// ---------------- MFMA GEMM (swapped): D[wcol][node] = W'^T-op x X-op ----------------
template <int K>
__global__ __launch_bounds__(256) void gemm_mfma(
    const float* __restrict__ in, const unsigned short* __restrict__ wfrag,
    const float* __restrict__ cvec,
    const float* __restrict__ a_src, const float* __restrict__ a_dst,
    unsigned short* __restrict__ h, float* __restrict__ s_src,
    float* __restrict__ s_dst, int N) {
    constexpr int KT = K / 32;
    constexpr int OPR = K / 8;
    __shared__ unsigned short xfrag[KT * 4 * 64 * 8];
    int tid = threadIdx.x;
    int w = tid >> 6, l = tid & 63;
    int gg = l >> 4, li = l & 15;
    int base = blockIdx.x * 64;

    for (int id = tid; id < 64 * OPR; id += 256) {
        int r = id / OPR, o = id % OPR;
        int node = min(base + r, N - 1);
        const float* p = &in[(size_t)node * K + o * 8];
        float4 f0 = *(const float4*)p;
        float4 f1 = *(const float4*)(p + 4);
        uint4 pkv;
        pkv.x = pk2(f0.x, f0.y);
        pkv.y = pk2(f0.z, f0.w);
        pkv.z = pk2(f1.x, f1.y);
        pkv.w = pk2(f1.z, f1.w);
        int kt = o >> 2, og = o & 3, nt = r >> 4;
        *(uint4*)&xfrag[(((kt * 4 + nt) * 64) + (r & 15) + 16 * og) * 8] = pkv;
    }
    __syncthreads();

    f32x4 acc[4][4];
#pragma unroll
    for (int mm = 0; mm < 4; ++mm) {
        float4 cv = *(const float4*)&cvec[64 * w + 16 * mm + 4 * gg];
#pragma unroll
        for (int nn = 0; nn < 4; ++nn) {
            acc[mm][nn][0] = cv.x; acc[mm][nn][1] = cv.y;
            acc[mm][nn][2] = cv.z; acc[mm][nn][3] = cv.w;
        }
    }

    for (int ks = 0; ks < KT; ++ks) {
        sv8 a[4], b[4];
#pragma unroll
        for (int mm = 0; mm < 4; ++mm)
            a[mm] = *(const sv8*)&wfrag[((size_t)(ks * 16 + w * 4 + mm) * 64 + l) * 8];
#pragma unroll
        for (int nn = 0; nn < 4; ++nn)
            b[nn] = *(const sv8*)&xfrag[((ks * 4 + nn) * 64 + l) * 8];
#pragma unroll
        for (int mm = 0; mm < 4; ++mm)
#pragma unroll
            for (int nn = 0; nn < 4; ++nn)
                acc[mm][nn] = __builtin_amdgcn_mfma_f32_16x16x32_bf16(
                    a[mm], b[nn], acc[mm][nn], 0, 0, 0);
    }

    float svp[4][2], sdp[4][2];
#pragma unroll
    for (int nn = 0; nn < 4; ++nn) { svp[nn][0]=0.f; svp[nn][1]=0.f; sdp[nn][0]=0.f; sdp[nn][1]=0.f; }

#pragma unroll
    for (int mm = 0; mm < 4; ++mm) {
        int cb = 64 * w + 16 * mm + 4 * gg;
        float4 as4 = *(const float4*)&a_src[cb];
        float4 ad4 = *(const float4*)&a_dst[cb];
        int hp = mm >> 1;
#pragma unroll
        for (int nn = 0; nn < 4; ++nn) {
            f32x4 A = acc[mm][nn];
            svp[nn][hp] += A[0]*as4.x + A[1]*as4.y + A[2]*as4.z + A[3]*as4.w;
            sdp[nn][hp] += A[0]*ad4.x + A[1]*ad4.y + A[2]*ad4.z + A[3]*ad4.w;
            int node = base + 16 * nn + li;
            if (node < N) {
                ushort4 pkv;
                pkv.x = f2bf(A[0]); pkv.y = f2bf(A[1]);
                pkv.z = f2bf(A[2]); pkv.w = f2bf(A[3]);
                *(ushort4*)&h[(size_t)node * HID + cb] = pkv;
            }
        }
    }
#pragma unroll
    for (int nn = 0; nn < 4; ++nn)
#pragma unroll
        for (int hp = 0; hp < 2; ++hp) {
            svp[nn][hp] += __shfl_xor(svp[nn][hp], 16);
            svp[nn][hp] += __shfl_xor(svp[nn][hp], 32);
            sdp[nn][hp] += __shfl_xor(sdp[nn][hp], 16);
            sdp[nn][hp] += __shfl_xor(sdp[nn][hp], 32);
        }
    if (gg == 0) {
#pragma unroll
        for (int nn = 0; nn < 4; ++nn) {
            int node = base + 16 * nn + li;
            if (node < N) {
#pragma unroll
                for (int hp = 0; hp < 2; ++hp) {
                    s_src[node * HEADS + 2 * w + hp] = svp[nn][hp];
                    s_dst[node * HEADS + 2 * w + hp] = sdp[nn][hp];
                }
            }
        }
    }
}

// ---------------- agg: one WAVE per dst node, zero block barriers ----------------
// pass A layout: lane = slot*8 + head  (8 heads of one edge are 8 consecutive lanes
//   -> one 32B s_src request per edge; head-reduce = 3-hop shfl_xor 8/16/32)
// pass B layout: lane owns cols 4l..4l+3 (head = l>>3); deferred 1/sum normalize.
__global__ __launch_bounds__(256) void agg_kernel(
    const unsigned short* __restrict__ h, const float* __restrict__ s_src,
    const float* __restrict__ s_dst, const int* __restrict__ offs,
    const int* __restrict__ csr_src, const float* __restrict__ bias,
    float* __restrict__ outp, int N) {
    __shared__ float al_lds[4][WCAP][8];
    __shared__ int   u_lds[4][WCAP];
    __shared__ float mi_lds[4][16];     // [0..7]=max, [8..15]=inv
    int tid = threadIdx.x;
    int w = tid >> 6, l = tid & 63;
    int vtx = blockIdx.x * 4 + w;
    if (vtx >= N) return;               // wave-uniform
    int beg = offs[vtx], end = offs[vtx + 1];
    int deg = end - beg;
    int dc = min(deg, WCAP);

    int headA = l & 7, slot = l >> 3;
    float sdv = s_dst[vtx * HEADS + headA];

    // max pass (+ cache u and raw scores)
    float m = -3.0e38f;
    for (int e = slot; e < deg; e += 8) {
        int u = csr_src[beg + e];
        float sc = lrelu(s_src[u * HEADS + headA] + sdv);
        if (e < WCAP) {
            if (headA == 0) u_lds[w][e] = u;
            al_lds[w][e][headA] = sc;
        }
        m = fmaxf(m, sc);
    }
    m = fmaxf(m, __shfl_xor(m, 8));
    m = fmaxf(m, __shfl_xor(m, 16));
    m = fmaxf(m, __shfl_xor(m, 32));

    // exp+sum pass: one exp per (edge, head); alphas left unnormalized
    float s = 0.f;
    for (int e = slot; e < dc; e += 8) {
        float p = __expf(al_lds[w][e][headA] - m);
        al_lds[w][e][headA] = p;
        s += p;
    }
    for (int e = WCAP + slot; e < deg; e += 8) {   // fallback tail
        int u = csr_src[beg + e];
        s += __expf(lrelu(s_src[u * HEADS + headA] + sdv) - m);
    }
    s += __shfl_xor(s, 8);
    s += __shfl_xor(s, 16);
    s += __shfl_xor(s, 32);
    if (slot == 0) {
        mi_lds[w][headA] = m;
        mi_lds[w][8 + headA] = 1.f / s;
    }
    __builtin_amdgcn_wave_barrier();    // order LDS writes (pass A) vs reads (pass B)

    // pass B: serial edge walk, lane owns 4 cols
    int hd = l >> 3;
    float inv = mi_lds[w][8 + hd];
    float4 acc = {0.f, 0.f, 0.f, 0.f};
#pragma unroll 4
    for (int e = 0; e < dc; ++e) {
        int u = u_lds[w][e];
        float al = al_lds[w][e][hd];
        uint2 hv = *(const uint2*)&h[(size_t)u * HID + 4 * l];
        acc.x = fmaf(al, __uint_as_float(hv.x << 16), acc.x);
        acc.y = fmaf(al, __uint_as_float(hv.x & 0xffff0000u), acc.y);
        acc.z = fmaf(al, __uint_as_float(hv.y << 16), acc.z);
        acc.w = fmaf(al, __uint_as_float(hv.y & 0xffff0000u), acc.w);
    }
    if (deg > WCAP) {                   // fallback (never for this graph)
        float mh = mi_lds[w][hd];
        float sdh = s_dst[vtx * HEADS + hd];
        for (int e = WCAP; e < deg; ++e) {
            int u = csr_src[beg + e];
            float al = __expf(lrelu(s_src[u * HEADS + hd] + sdh) - mh);
            uint2 hv = *(const uint2*)&h[(size_t)u * HID + 4 * l];
            acc.x = fmaf(al, __uint_as_float(hv.x << 16), acc.x);
            acc.y = fmaf(al, __uint_as_float(hv.x & 0xffff0000u), acc.y);
            acc.z = fmaf(al, __uint_as_float(hv.y << 16), acc.z);
            acc.w = fmaf(al, __uint_as_float(hv.y & 0xffff0000u), acc.w);
        }
    }
    float4 bb = *(const float4*)&bias[4 * l];
    float4 o;
    o.x = eluf(acc.x * inv + bb.x);
    o.y = eluf(acc.y * inv + bb.y);
    o.z = eluf(acc.z * inv + bb.z);
    o.w = eluf(acc.w * inv + bb.w);
    *(float4*)&outp[(size_t)vtx * HID + 4 * l] = o;
}

// ---------------- head: q = [t|x] @ hfrag + c'; out = relu(q) @ p2_W + p2_b ----------
__global__ __launch_bounds__(256) void final_mfma(
    const float* __restrict__ t_in, const float* __restrict__ x,
    const unsigned short* __restrict__ hf, const float* __restrict__ cp,
    const float* __restrict__ p2_W, const float* __restrict__ p2_b,
    float* __restrict__ outp, int N) {
    constexpr int KT = 10;
    __shared__ unsigned short xfrag[KT * 4 * 64 * 8];
    int tid = threadIdx.x;
    int w = tid >> 6, l = tid & 63;
    int gg = l >> 4, li = l & 15;
    int base = blockIdx.x * 64;

    for (int id = tid; id < 64 * 40; id += 256) {
        int r = id / 40, o = id % 40;
        int node = min(base + r, N - 1);
        const float* p = (o < 32) ? &t_in[(size_t)node * HID + o * 8]
                                  : &x[(size_t)node * 64 + (o - 32) * 8];
        float4 f0 = *(const float4*)p;
        float4 f1 = *(const float4*)(p + 4);
        uint4 pkv;
        pkv.x = pk2(f0.x, f0.y);
        pkv.y = pk2(f0.z, f0.w);
        pkv.z = pk2(f1.x, f1.y);
        pkv.w = pk2(f1.z, f1.w);
        int kt = o >> 2, og = o & 3, nt = r >> 4;
        *(uint4*)&xfrag[(((kt * 4 + nt) * 64) + (r & 15) + 16 * og) * 8] = pkv;
    }
    __syncthreads();

    f32x4 acc[2];
#pragma unroll
    for (int mt = 0; mt < 2; ++mt) {
        float4 cv = *(const float4*)&cp[mt * 16 + 4 * gg];
        acc[mt][0] = cv.x; acc[mt][1] = cv.y; acc[mt][2] = cv.z; acc[mt][3] = cv.w;
    }

    for (int kt = 0; kt < KT; ++kt) {
        sv8 b = *(const sv8*)&xfrag[((kt * 4 + w) * 64 + l) * 8];
#pragma unroll
        for (int mt = 0; mt < 2; ++mt) {
            sv8 a = *(const sv8*)&hf[((size_t)(kt * 2 + mt) * 64 + l) * 8];
            acc[mt] = __builtin_amdgcn_mfma_f32_16x16x32_bf16(a, b, acc[mt], 0, 0, 0);
        }
    }

    float po = 0.f;
#pragma unroll
    for (int mt = 0; mt < 2; ++mt) {
        float4 p2v = *(const float4*)&p2_W[mt * 16 + 4 * gg];
        po += fmaxf(acc[mt][0], 0.f) * p2v.x;
        po += fmaxf(acc[mt][1], 0.f) * p2v.y;
        po += fmaxf(acc[mt][2], 0.f) * p2v.z;
        po += fmaxf(acc[mt][3], 0.f) * p2v.w;
    }
    po += __shfl_xor(po, 16);
    po += __shfl_xor(po, 32);
    int node = base + 16 * w + li;
    if (gg == 0 && node < N) outp[node] = po + p2_b[0];
}

// ---------------- launch ----------------

extern "C" void kernel_launch(void* const* d_in, const int* in_sizes, int n_in,
                              void* d_out, int out_size, void* d_ws, size_t ws_size,
                              hipStream_t stream) {
    const float* x      = (const float*)d_in[0];
    const int*   ei     = (const int*)  d_in[1];
    const float* bn1_g  = (const float*)d_in[2];
    const float* bn1_b  = (const float*)d_in[3];
    const float* bn1_m  = (const float*)d_in[4];
    const float* bn1_v  = (const float*)d_in[5];
    const float* W1     = (const float*)d_in[6];
    const float* a1_src = (const float*)d_in[7];
    const float* a1_dst = (const float*)d_in[8];
    const float* b1     = (const float*)d_in[9];
    const float* bn2_g  = (const float*)d_in[10];
    const float* bn2_b  = (const float*)d_in[11];
    const float* bn2_m  = (const float*)d_in[12];
    const float* bn2_v  = (const float*)d_in[13];
    const float* W2     = (const float*)d_in[14];
    const float* a2_src = (const float*)d_in[15];
    const float* a2_dst = (const float*)d_in[16];
    const float* b2     = (const float*)d_in[17];
    const float* bn3_g  = (const float*)d_in[18];
    const float* bn3_b  = (const float*)d_in[19];
    const float* bn3_m  = (const float*)d_in[20];
    const float* bn3_v  = (const float*)d_in[21];
    const float* skip_W = (const float*)d_in[22];
    const float* skip_b = (const float*)d_in[23];
    const float* p1_W   = (const float*)d_in[24];
    const float* p1_b   = (const float*)d_in[25];
    const float* p2_W   = (const float*)d_in[26];
    const float* p2_b   = (const float*)d_in[27];

    int N = in_sizes[0] / 64;
    int E = in_sizes[1] / 2;
    int EE = E + N;

    uintptr_t w = (uintptr_t)d_ws;
    auto carve = [&](size_t bytes) -> void* {
        uintptr_t p = w;
        w += (bytes + 255) & ~(size_t)255;
        return (void*)p;
    };
    int*   deg  = (int*)carve((size_t)N * 4);
    int*   cur  = (int*)carve((size_t)N * 4);
    int*   offs = (int*)carve(((size_t)N + 1) * 4);
    int*   csr  = (int*)carve((size_t)EE * 4);
    float* ssrc = (float*)carve((size_t)N * HEADS * 4);
    float* sdst = (float*)carve((size_t)N * HEADS * 4);
    unsigned short* wf1 = (unsigned short*)carve((size_t)2 * 16 * 64 * 8 * 2);
    unsigned short* wf2 = (unsigned short*)carve((size_t)8 * 16 * 64 * 8 * 2);
    unsigned short* hf  = (unsigned short*)carve((size_t)20 * 64 * 8 * 2);
    float* c1   = (float*)carve((size_t)HID * 4);
    float* c2   = (float*)carve((size_t)HID * 4);
    float* cp   = (float*)carve((size_t)32 * 4);
    unsigned short* hbf = (unsigned short*)carve((size_t)N * HID * 2);
    float* tbuf = (float*)carve((size_t)N * HID * 4);

    // deg and cur are adjacent carvings -> single memset covers both
    hipMemsetAsync(deg, 0, ((size_t)N * 4 + 255 & ~(size_t)255) + (size_t)N * 4, stream);

    // fused weight prep (48 blocks, one launch)
    prep_kernel<<<48, 256, 0, stream>>>(
        W1, bn1_g, bn1_b, bn1_m, bn1_v,
        W2, bn2_g, bn2_b, bn2_m, bn2_v,
        bn3_g, bn3_b, bn3_m, bn3_v, skip_W, skip_b, p1_W, p1_b,
        wf1, wf2, hf, c1, c2, cp);

    // CSR
    int eblk = (EE + 255) / 256;
    degree_kernel<<<eblk, 256, 0, stream>>>(ei, deg, E, EE);
    scan_kernel<<<1, 1024, 0, stream>>>(deg, offs, N);
    scatter_kernel<<<eblk, 256, 0, stream>>>(ei, offs, cur, csr, E, EE);

    int gblk = (N + 63) / 64;
    int ablk = (N + 3) / 4;
    // layer 1
    gemm_mfma<64><<<gblk, 256, 0, stream>>>(x, wf1, c1, a1_src, a1_dst,
                                            hbf, ssrc, sdst, N);
    agg_kernel<<<ablk, 256, 0, stream>>>(hbf, ssrc, sdst, offs, csr, b1, tbuf, N);

    // layer 2
    gemm_mfma<HID><<<gblk, 256, 0, stream>>>(tbuf, wf2, c2, a2_src, a2_dst,
                                             hbf, ssrc, sdst, N);
    agg_kernel<<<ablk, 256, 0, stream>>>(hbf, ssrc, sdst, offs, csr, b2, tbuf, N);

    // head (fully folded)
    final_mfma<<<gblk, 256, 0, stream>>>(tbuf, x, hf, cp, p2_W, p2_b,
                                         (float*)d_out, N);
}

// Round 9
// 339.931 us; speedup vs baseline: 3.0055x; 1.1956x over previous
//
#include <hip/hip_runtime.h>
#include <hip/hip_bf16.h>
#include <math.h>
#include <stdint.h>

#define HID 256
#define HEADS 8
#define BN_EPS 1e-5f
#define NEG 0.2f
#define WCAP 96    // per-wave edge cache (deg ~ Poisson(16)+1; fallback beyond)
#define SEPT 8     // scan: elements per thread
#define SCHUNK (256 * SEPT)

typedef short sv8  __attribute__((ext_vector_type(8)));
typedef float f32x4 __attribute__((ext_vector_type(4)));

__device__ __forceinline__ float lrelu(float x) { return x > 0.f ? x : NEG * x; }
__device__ __forceinline__ float eluf(float x)  { return x > 0.f ? x : expm1f(x); }

__device__ __forceinline__ unsigned short f2bf(float f) {
    unsigned int u = __float_as_uint(f);
    u = (u + 0x7fffu + ((u >> 16) & 1u)) >> 16;   // RNE
    return (unsigned short)u;
}
__device__ __forceinline__ unsigned int pk2(float lo, float hi) {
    return (unsigned int)f2bf(lo) | ((unsigned int)f2bf(hi) << 16);
}

// ---------------- CSR build ----------------

__global__ __launch_bounds__(256) void degree_kernel(const int* __restrict__ ei,
                                                     int* __restrict__ deg,
                                                     int E, int EE) {
    int e = blockIdx.x * 256 + threadIdx.x;
    if (e >= EE) return;
    int d = (e < E) ? ei[E + e] : (e - E);
    atomicAdd(&deg[d], 1);
}

// parallel scan, phase 1: per-block sums
__global__ __launch_bounds__(256) void scan1_kernel(const int* __restrict__ deg,
                                                    int* __restrict__ bsum, int N) {
    __shared__ int part[256];
    int t = threadIdx.x;
    int base = blockIdx.x * SCHUNK + t * SEPT;
    int s = 0;
    if (base + SEPT <= N) {
        int4 a = *(const int4*)&deg[base];
        int4 c = *(const int4*)&deg[base + 4];
        s = a.x + a.y + a.z + a.w + c.x + c.y + c.z + c.w;
    } else {
#pragma unroll
        for (int i = 0; i < SEPT; ++i) {
            int j = base + i;
            if (j < N) s += deg[j];
        }
    }
    part[t] = s;
    __syncthreads();
    for (int d = 128; d > 0; d >>= 1) {
        if (t < d) part[t] += part[t + d];
        __syncthreads();
    }
    if (t == 0) bsum[blockIdx.x] = part[0];
}

// phase 2: exclusive scan of block sums (nb <= 256) + write offs[N]
__global__ __launch_bounds__(256) void scan2_kernel(int* __restrict__ bsum,
                                                    int* __restrict__ offs,
                                                    int nb, int N) {
    __shared__ int part[256];
    int t = threadIdx.x;
    int v = (t < nb) ? bsum[t] : 0;
    part[t] = v;
    __syncthreads();
    for (int d = 1; d < 256; d <<= 1) {
        int o = (t >= d) ? part[t - d] : 0;
        __syncthreads();
        part[t] += o;
        __syncthreads();
    }
    if (t < nb) bsum[t] = part[t] - v;          // exclusive
    if (t == 255) offs[N] = part[255];          // grand total
}

// phase 3: local re-scan + add block offset
__global__ __launch_bounds__(256) void scan3_kernel(const int* __restrict__ deg,
                                                    const int* __restrict__ bsum,
                                                    int* __restrict__ offs, int N) {
    __shared__ int part[256];
    int t = threadIdx.x;
    int base = blockIdx.x * SCHUNK + t * SEPT;
    int loc[SEPT];
    int s = 0;
#pragma unroll
    for (int i = 0; i < SEPT; ++i) {
        int j = base + i;
        int d = (j < N) ? deg[j] : 0;
        loc[i] = s;
        s += d;
    }
    part[t] = s;
    __syncthreads();
    for (int d = 1; d < 256; d <<= 1) {
        int o = (t >= d) ? part[t - d] : 0;
        __syncthreads();
        part[t] += o;
        __syncthreads();
    }
    int ex = part[t] - s + bsum[blockIdx.x];
#pragma unroll
    for (int i = 0; i < SEPT; ++i) {
        int j = base + i;
        if (j < N) offs[j] = ex + loc[i];
    }
}

__global__ __launch_bounds__(256) void scatter_kernel(const int* __restrict__ ei,
                                                      const int* __restrict__ offs,
                                                      int* __restrict__ cur,
                                                      int* __restrict__ csr_src,
                                                      int E, int EE) {
    int e = blockIdx.x * 256 + threadIdx.x;
    if (e >= EE) return;
    int s = (e < E) ? ei[e] : (e - E);
    int d = (e < E) ? ei[E + e] : (e - E);
    int pos = offs[d] + atomicAdd(&cur[d], 1);
    csr_src[pos] = s;
}

// ---------------- fused prologue: all weight prep in one launch ----------------
// fragment layout (verified R3-R6): tile per 16-col x 32-k; lane l holds
// M[k0 + 8*(l>>4) + j][c0 + (l&15)], j=0..7, packed bf16x8.

__device__ __forceinline__ void wfrag_body(const float* __restrict__ W,
                                           const float* __restrict__ g,
                                           const float* __restrict__ v,
                                           unsigned short* __restrict__ frag,
                                           int tile, int l) {
    int ct = tile & 15, kt = tile >> 4;
    int c = ct * 16 + (l & 15);
    int k0 = kt * 32 + (l >> 4) * 8;
    float val[8];
#pragma unroll
    for (int j = 0; j < 8; ++j) {
        float s = g[k0 + j] * rsqrtf(v[k0 + j] + BN_EPS);
        val[j] = W[(size_t)(k0 + j) * HID + c] * s;
    }
    uint4 o;
    o.x = pk2(val[0], val[1]);
    o.y = pk2(val[2], val[3]);
    o.z = pk2(val[4], val[5]);
    o.w = pk2(val[6], val[7]);
    *(uint4*)&frag[((size_t)tile * 64 + l) * 8] = o;
}

__global__ __launch_bounds__(256) void prep_kernel(
    const float* __restrict__ W1, const float* __restrict__ bn1_g,
    const float* __restrict__ bn1_b, const float* __restrict__ bn1_m,
    const float* __restrict__ bn1_v,
    const float* __restrict__ W2, const float* __restrict__ bn2_g,
    const float* __restrict__ bn2_b, const float* __restrict__ bn2_m,
    const float* __restrict__ bn2_v,
    const float* __restrict__ g3, const float* __restrict__ b3,
    const float* __restrict__ m3, const float* __restrict__ v3,
    const float* __restrict__ skip_W, const float* __restrict__ skip_b,
    const float* __restrict__ p1_W, const float* __restrict__ p1_b,
    unsigned short* __restrict__ wf1, unsigned short* __restrict__ wf2,
    unsigned short* __restrict__ hf, float* __restrict__ c1,
    float* __restrict__ c2, float* __restrict__ cp) {
    int b = blockIdx.x;
    int tid = threadIdx.x;
    int sub = tid >> 6, l = tid & 63;

    if (b < 8) {                       // wf1: 32 tiles (K=64)
        wfrag_body(W1, bn1_g, bn1_v, wf1, b * 4 + sub, l);
    } else if (b < 40) {               // wf2: 128 tiles (K=256)
        wfrag_body(W2, bn2_g, bn2_v, wf2, (b - 8) * 4 + sub, l);
    } else if (b < 45) {               // hf: 20 tiles, K=320 ([t|x] concat)
        int tile = (b - 40) * 4 + sub;
        int mt = tile & 1, kt = tile >> 1;
        int j = mt * 16 + (l & 15);
        int k0 = kt * 32 + (l >> 4) * 8;
        float val[8];
#pragma unroll
        for (int jj = 0; jj < 8; ++jj) {
            int c = k0 + jj;
            if (c < HID) {
                float s3 = g3[c] * rsqrtf(v3[c] + BN_EPS);
                val[jj] = s3 * p1_W[c * 32 + j];
            } else {                   // S' = skip_W @ p1_W computed inline
                float acc = 0.f;
                for (int cc = 0; cc < HID; ++cc)
                    acc = fmaf(skip_W[(size_t)(c - HID) * HID + cc],
                               p1_W[cc * 32 + j], acc);
                val[jj] = acc;
            }
        }
        uint4 o;
        o.x = pk2(val[0], val[1]);
        o.y = pk2(val[2], val[3]);
        o.z = pk2(val[4], val[5]);
        o.w = pk2(val[6], val[7]);
        *(uint4*)&hf[((size_t)tile * 64 + l) * 8] = o;
    } else if (b == 45) {              // c1 = (b1 - m1*s1) @ W1
        float acc = 0.f;
        for (int k = 0; k < 64; ++k) {
            float s = bn1_g[k] * rsqrtf(bn1_v[k] + BN_EPS);
            acc = fmaf(bn1_b[k] - bn1_m[k] * s, W1[(size_t)k * HID + tid], acc);
        }
        c1[tid] = acc;
    } else if (b == 46) {              // c2
        float acc = 0.f;
        for (int k = 0; k < HID; ++k) {
            float s = bn2_g[k] * rsqrtf(bn2_v[k] + BN_EPS);
            acc = fmaf(bn2_b[k] - bn2_m[k] * s, W2[(size_t)k * HID + tid], acc);
        }
        c2[tid] = acc;
    } else {                           // cp = (b3 - m3*s3 + skip_b) @ p1_W + p1_b
        if (tid < 32) {
            float acc = p1_b[tid];
            for (int c = 0; c < HID; ++c) {
                float s3 = g3[c] * rsqrtf(v3[c] + BN_EPS);
                acc = fmaf(b3[c] - m3[c] * s3 + skip_b[c], p1_W[c * 32 + tid], acc);
            }
            cp[tid] = acc;
        }
    }
}

// ---------------- MFMA GEMM (swapped): D[wcol][node] = W'^T-op x X-op ----------------
template <int K>
__global__ __launch_bounds__(256) void gemm_mfma(
    const float* __restrict__ in, const unsigned short* __restrict__ wfrag,
    const float* __restrict__ cvec,
    const float* __restrict__ a_src, const float* __restrict__ a_dst,
    unsigned short* __restrict__ h, float* __restrict__ s_src,
    float* __restrict__ s_dst, int N) {
    constexpr int KT = K / 32;
    constexpr int OPR = K / 8;
    __shared__ unsigned short xfrag[KT * 4 * 64 * 8];
    int tid = threadIdx.x;
    int w = tid >> 6, l = tid & 63;
    int gg = l >> 4, li = l & 15;
    int base = blockIdx.x * 64;

    for (int id = tid; id < 64 * OPR; id += 256) {
        int r = id / OPR, o = id % OPR;
        int node = min(base + r, N - 1);
        const float* p = &in[(size_t)node * K + o * 8];
        float4 f0 = *(const float4*)p;
        float4 f1 = *(const float4*)(p + 4);
        uint4 pkv;
        pkv.x = pk2(f0.x, f0.y);
        pkv.y = pk2(f0.z, f0.w);
        pkv.z = pk2(f1.x, f1.y);
        pkv.w = pk2(f1.z, f1.w);
        int kt = o >> 2, og = o & 3, nt = r >> 4;
        *(uint4*)&xfrag[(((kt * 4 + nt) * 64) + (r & 15) + 16 * og) * 8] = pkv;
    }
    __syncthreads();

    f32x4 acc[4][4];
#pragma unroll
    for (int mm = 0; mm < 4; ++mm) {
        float4 cv = *(const float4*)&cvec[64 * w + 16 * mm + 4 * gg];
#pragma unroll
        for (int nn = 0; nn < 4; ++nn) {
            acc[mm][nn][0] = cv.x; acc[mm][nn][1] = cv.y;
            acc[mm][nn][2] = cv.z; acc[mm][nn][3] = cv.w;
        }
    }

    for (int ks = 0; ks < KT; ++ks) {
        sv8 a[4], b[4];
#pragma unroll
        for (int mm = 0; mm < 4; ++mm)
            a[mm] = *(const sv8*)&wfrag[((size_t)(ks * 16 + w * 4 + mm) * 64 + l) * 8];
#pragma unroll
        for (int nn = 0; nn < 4; ++nn)
            b[nn] = *(const sv8*)&xfrag[((ks * 4 + nn) * 64 + l) * 8];
#pragma unroll
        for (int mm = 0; mm < 4; ++mm)
#pragma unroll
            for (int nn = 0; nn < 4; ++nn)
                acc[mm][nn] = __builtin_amdgcn_mfma_f32_16x16x32_bf16(
                    a[mm], b[nn], acc[mm][nn], 0, 0, 0);
    }

    float svp[4][2], sdp[4][2];
#pragma unroll
    for (int nn = 0; nn < 4; ++nn) { svp[nn][0]=0.f; svp[nn][1]=0.f; sdp[nn][0]=0.f; sdp[nn][1]=0.f; }

#pragma unroll
    for (int mm = 0; mm < 4; ++mm) {
        int cb = 64 * w + 16 * mm + 4 * gg;
        float4 as4 = *(const float4*)&a_src[cb];
        float4 ad4 = *(const float4*)&a_dst[cb];
        int hp = mm >> 1;
#pragma unroll
        for (int nn = 0; nn < 4; ++nn) {
            f32x4 A = acc[mm][nn];
            svp[nn][hp] += A[0]*as4.x + A[1]*as4.y + A[2]*as4.z + A[3]*as4.w;
            sdp[nn][hp] += A[0]*ad4.x + A[1]*ad4.y + A[2]*ad4.z + A[3]*ad4.w;
            int node = base + 16 * nn + li;
            if (node < N) {
                ushort4 pkv;
                pkv.x = f2bf(A[0]); pkv.y = f2bf(A[1]);
                pkv.z = f2bf(A[2]); pkv.w = f2bf(A[3]);
                *(ushort4*)&h[(size_t)node * HID + cb] = pkv;
            }
        }
    }
#pragma unroll
    for (int nn = 0; nn < 4; ++nn)
#pragma unroll
        for (int hp = 0; hp < 2; ++hp) {
            svp[nn][hp] += __shfl_xor(svp[nn][hp], 16);
            svp[nn][hp] += __shfl_xor(svp[nn][hp], 32);
            sdp[nn][hp] += __shfl_xor(sdp[nn][hp], 16);
            sdp[nn][hp] += __shfl_xor(sdp[nn][hp], 32);
        }
    if (gg == 0) {
#pragma unroll
        for (int nn = 0; nn < 4; ++nn) {
            int node = base + 16 * nn + li;
            if (node < N) {
#pragma unroll
                for (int hp = 0; hp < 2; ++hp) {
                    s_src[node * HEADS + 2 * w + hp] = svp[nn][hp];
                    s_dst[node * HEADS + 2 * w + hp] = sdp[nn][hp];
                }
            }
        }
    }
}

// ---------------- agg: one WAVE per dst node, zero block barriers ----------------
__global__ __launch_bounds__(256) void agg_kernel(
    const unsigned short* __restrict__ h, const float* __restrict__ s_src,
    const float* __restrict__ s_dst, const int* __restrict__ offs,
    const int* __restrict__ csr_src, const float* __restrict__ bias,
    float* __restrict__ outp, int N) {
    __shared__ float al_lds[4][WCAP][8];
    __shared__ int   u_lds[4][WCAP];
    __shared__ float mi_lds[4][16];     // [0..7]=max, [8..15]=inv
    int tid = threadIdx.x;
    int w = tid >> 6, l = tid & 63;
    int vtx = blockIdx.x * 4 + w;
    if (vtx >= N) return;               // wave-uniform
    int beg = offs[vtx], end = offs[vtx + 1];
    int deg = end - beg;
    int dc = min(deg, WCAP);

    int headA = l & 7, slot = l >> 3;
    float sdv = s_dst[vtx * HEADS + headA];

    // max pass (+ cache u and raw scores)
    float m = -3.0e38f;
    for (int e = slot; e < deg; e += 8) {
        int u = csr_src[beg + e];
        float sc = lrelu(s_src[u * HEADS + headA] + sdv);
        if (e < WCAP) {
            if (headA == 0) u_lds[w][e] = u;
            al_lds[w][e][headA] = sc;
        }
        m = fmaxf(m, sc);
    }
    m = fmaxf(m, __shfl_xor(m, 8));
    m = fmaxf(m, __shfl_xor(m, 16));
    m = fmaxf(m, __shfl_xor(m, 32));

    // exp+sum pass: one exp per (edge, head); alphas left unnormalized
    float s = 0.f;
    for (int e = slot; e < dc; e += 8) {
        float p = __expf(al_lds[w][e][headA] - m);
        al_lds[w][e][headA] = p;
        s += p;
    }
    for (int e = WCAP + slot; e < deg; e += 8) {   // fallback tail
        int u = csr_src[beg + e];
        s += __expf(lrelu(s_src[u * HEADS + headA] + sdv) - m);
    }
    s += __shfl_xor(s, 8);
    s += __shfl_xor(s, 16);
    s += __shfl_xor(s, 32);
    if (slot == 0) {
        mi_lds[w][headA] = m;
        mi_lds[w][8 + headA] = 1.f / s;
    }
    __builtin_amdgcn_wave_barrier();    // order LDS writes (pass A) vs reads (pass B)

    // pass B: serial edge walk, lane owns 4 cols
    int hd = l >> 3;
    float inv = mi_lds[w][8 + hd];
    float4 acc = {0.f, 0.f, 0.f, 0.f};
#pragma unroll 4
    for (int e = 0; e < dc; ++e) {
        int u = u_lds[w][e];
        float al = al_lds[w][e][hd];
        uint2 hv = *(const uint2*)&h[(size_t)u * HID + 4 * l];
        acc.x = fmaf(al, __uint_as_float(hv.x << 16), acc.x);
        acc.y = fmaf(al, __uint_as_float(hv.x & 0xffff0000u), acc.y);
        acc.z = fmaf(al, __uint_as_float(hv.y << 16), acc.z);
        acc.w = fmaf(al, __uint_as_float(hv.y & 0xffff0000u), acc.w);
    }
    if (deg > WCAP) {                   // fallback (never for this graph)
        float mh = mi_lds[w][hd];
        float sdh = s_dst[vtx * HEADS + hd];
        for (int e = WCAP; e < deg; ++e) {
            int u = csr_src[beg + e];
            float al = __expf(lrelu(s_src[u * HEADS + hd] + sdh) - mh);
            uint2 hv = *(const uint2*)&h[(size_t)u * HID + 4 * l];
            acc.x = fmaf(al, __uint_as_float(hv.x << 16), acc.x);
            acc.y = fmaf(al, __uint_as_float(hv.x & 0xffff0000u), acc.y);
            acc.z = fmaf(al, __uint_as_float(hv.y << 16), acc.z);
            acc.w = fmaf(al, __uint_as_float(hv.y & 0xffff0000u), acc.w);
        }
    }
    float4 bb = *(const float4*)&bias[4 * l];
    float4 o;
    o.x = eluf(acc.x * inv + bb.x);
    o.y = eluf(acc.y * inv + bb.y);
    o.z = eluf(acc.z * inv + bb.z);
    o.w = eluf(acc.w * inv + bb.w);
    *(float4*)&outp[(size_t)vtx * HID + 4 * l] = o;
}

// ---------------- head: q = [t|x] @ hfrag + c'; out = relu(q) @ p2_W + p2_b ----------
__global__ __launch_bounds__(256) void final_mfma(
    const float* __restrict__ t_in, const float* __restrict__ x,
    const unsigned short* __restrict__ hf, const float* __restrict__ cp,
    const float* __restrict__ p2_W, const float* __restrict__ p2_b,
    float* __restrict__ outp, int N) {
    constexpr int KT = 10;
    __shared__ unsigned short xfrag[KT * 4 * 64 * 8];
    int tid = threadIdx.x;
    int w = tid >> 6, l = tid & 63;
    int gg = l >> 4, li = l & 15;
    int base = blockIdx.x * 64;

    for (int id = tid; id < 64 * 40; id += 256) {
        int r = id / 40, o = id % 40;
        int node = min(base + r, N - 1);
        const float* p = (o < 32) ? &t_in[(size_t)node * HID + o * 8]
                                  : &x[(size_t)node * 64 + (o - 32) * 8];
        float4 f0 = *(const float4*)p;
        float4 f1 = *(const float4*)(p + 4);
        uint4 pkv;
        pkv.x = pk2(f0.x, f0.y);
        pkv.y = pk2(f0.z, f0.w);
        pkv.z = pk2(f1.x, f1.y);
        pkv.w = pk2(f1.z, f1.w);
        int kt = o >> 2, og = o & 3, nt = r >> 4;
        *(uint4*)&xfrag[(((kt * 4 + nt) * 64) + (r & 15) + 16 * og) * 8] = pkv;
    }
    __syncthreads();

    f32x4 acc[2];
#pragma unroll
    for (int mt = 0; mt < 2; ++mt) {
        float4 cv = *(const float4*)&cp[mt * 16 + 4 * gg];
        acc[mt][0] = cv.x; acc[mt][1] = cv.y; acc[mt][2] = cv.z; acc[mt][3] = cv.w;
    }

    for (int kt = 0; kt < KT; ++kt) {
        sv8 b = *(const sv8*)&xfrag[((kt * 4 + w) * 64 + l) * 8];
#pragma unroll
        for (int mt = 0; mt < 2; ++mt) {
            sv8 a = *(const sv8*)&hf[((size_t)(kt * 2 + mt) * 64 + l) * 8];
            acc[mt] = __builtin_amdgcn_mfma_f32_16x16x32_bf16(a, b, acc[mt], 0, 0, 0);
        }
    }

    float po = 0.f;
#pragma unroll
    for (int mt = 0; mt < 2; ++mt) {
        float4 p2v = *(const float4*)&p2_W[mt * 16 + 4 * gg];
        po += fmaxf(acc[mt][0], 0.f) * p2v.x;
        po += fmaxf(acc[mt][1], 0.f) * p2v.y;
        po += fmaxf(acc[mt][2], 0.f) * p2v.z;
        po += fmaxf(acc[mt][3], 0.f) * p2v.w;
    }
    po += __shfl_xor(po, 16);
    po += __shfl_xor(po, 32);
    int node = base + 16 * w + li;
    if (gg == 0 && node < N) outp[node] = po + p2_b[0];
}

// ---------------- launch ----------------

extern "C" void kernel_launch(void* const* d_in, const int* in_sizes, int n_in,
                              void* d_out, int out_size, void* d_ws, size_t ws_size,
                              hipStream_t stream) {
    const float* x      = (const float*)d_in[0];
    const int*   ei     = (const int*)  d_in[1];
    const float* bn1_g  = (const float*)d_in[2];
    const float* bn1_b  = (const float*)d_in[3];
    const float* bn1_m  = (const float*)d_in[4];
    const float* bn1_v  = (const float*)d_in[5];
    const float* W1     = (const float*)d_in[6];
    const float* a1_src = (const float*)d_in[7];
    const float* a1_dst = (const float*)d_in[8];
    const float* b1     = (const float*)d_in[9];
    const float* bn2_g  = (const float*)d_in[10];
    const float* bn2_b  = (const float*)d_in[11];
    const float* bn2_m  = (const float*)d_in[12];
    const float* bn2_v  = (const float*)d_in[13];
    const float* W2     = (const float*)d_in[14];
    const float* a2_src = (const float*)d_in[15];
    const float* a2_dst = (const float*)d_in[16];
    const float* b2     = (const float*)d_in[17];
    const float* bn3_g  = (const float*)d_in[18];
    const float* bn3_b  = (const float*)d_in[19];
    const float* bn3_m  = (const float*)d_in[20];
    const float* bn3_v  = (const float*)d_in[21];
    const float* skip_W = (const float*)d_in[22];
    const float* skip_b = (const float*)d_in[23];
    const float* p1_W   = (const float*)d_in[24];
    const float* p1_b   = (const float*)d_in[25];
    const float* p2_W   = (const float*)d_in[26];
    const float* p2_b   = (const float*)d_in[27];

    int N = in_sizes[0] / 64;
    int E = in_sizes[1] / 2;
    int EE = E + N;

    uintptr_t w = (uintptr_t)d_ws;
    auto carve = [&](size_t bytes) -> void* {
        uintptr_t p = w;
        w += (bytes + 255) & ~(size_t)255;
        return (void*)p;
    };
    int*   deg  = (int*)carve((size_t)N * 4);
    int*   cur  = (int*)carve((size_t)N * 4);
    int*   offs = (int*)carve(((size_t)N + 1) * 4);
    int*   csr  = (int*)carve((size_t)EE * 4);
    int*   bsum = (int*)carve((size_t)256 * 4);
    float* ssrc = (float*)carve((size_t)N * HEADS * 4);
    float* sdst = (float*)carve((size_t)N * HEADS * 4);
    unsigned short* wf1 = (unsigned short*)carve((size_t)2 * 16 * 64 * 8 * 2);
    unsigned short* wf2 = (unsigned short*)carve((size_t)8 * 16 * 64 * 8 * 2);
    unsigned short* hf  = (unsigned short*)carve((size_t)20 * 64 * 8 * 2);
    float* c1   = (float*)carve((size_t)HID * 4);
    float* c2   = (float*)carve((size_t)HID * 4);
    float* cp   = (float*)carve((size_t)32 * 4);
    unsigned short* hbf = (unsigned short*)carve((size_t)N * HID * 2);
    float* tbuf = (float*)carve((size_t)N * HID * 4);

    // deg and cur are adjacent carvings -> single memset covers both
    hipMemsetAsync(deg, 0, ((size_t)N * 4 + 255 & ~(size_t)255) + (size_t)N * 4, stream);

    // fused weight prep (48 blocks, one launch)
    prep_kernel<<<48, 256, 0, stream>>>(
        W1, bn1_g, bn1_b, bn1_m, bn1_v,
        W2, bn2_g, bn2_b, bn2_m, bn2_v,
        bn3_g, bn3_b, bn3_m, bn3_v, skip_W, skip_b, p1_W, p1_b,
        wf1, wf2, hf, c1, c2, cp);

    // CSR (parallel 3-phase scan)
    int eblk = (EE + 255) / 256;
    int nb = (N + SCHUNK - 1) / SCHUNK;
    degree_kernel<<<eblk, 256, 0, stream>>>(ei, deg, E, EE);
    scan1_kernel<<<nb, 256, 0, stream>>>(deg, bsum, N);
    scan2_kernel<<<1, 256, 0, stream>>>(bsum, offs, nb, N);
    scan3_kernel<<<nb, 256, 0, stream>>>(deg, bsum, offs, N);
    scatter_kernel<<<eblk, 256, 0, stream>>>(ei, offs, cur, csr, E, EE);

    int gblk = (N + 63) / 64;
    int ablk = (N + 3) / 4;
    // layer 1
    gemm_mfma<64><<<gblk, 256, 0, stream>>>(x, wf1, c1, a1_src, a1_dst,
                                            hbf, ssrc, sdst, N);
    agg_kernel<<<ablk, 256, 0, stream>>>(hbf, ssrc, sdst, offs, csr, b1, tbuf, N);

    // layer 2
    gemm_mfma<HID><<<gblk, 256, 0, stream>>>(tbuf, wf2, c2, a2_src, a2_dst,
                                             hbf, ssrc, sdst, N);
    agg_kernel<<<ablk, 256, 0, stream>>>(hbf, ssrc, sdst, offs, csr, b2, tbuf, N);

    // head (fully folded)
    final_mfma<<<gblk, 256, 0, stream>>>(tbuf, x, hf, cp, p2_W, p2_b,
                                         (float*)d_out, N);
}

// Round 10
// 333.969 us; speedup vs baseline: 3.0592x; 1.0179x over previous
//
#include <hip/hip_runtime.h>
#include <hip/hip_bf16.h>
#include <math.h>
#include <stdint.h>

#define HID 256
#define HEADS 8
#define BN_EPS 1e-5f
#define NEG 0.2f
#define WCAP 96    // per-wave edge cache (deg ~ Poisson(16)+1; fallback beyond)
#define SEPT 8     // scan: elements per thread
#define SCHUNK (256 * SEPT)

typedef short sv8  __attribute__((ext_vector_type(8)));
typedef float f32x4 __attribute__((ext_vector_type(4)));

__device__ __forceinline__ float lrelu(float x) { return x > 0.f ? x : NEG * x; }
__device__ __forceinline__ float eluf(float x)  { return x > 0.f ? x : expm1f(x); }

__device__ __forceinline__ unsigned short f2bf(float f) {
    unsigned int u = __float_as_uint(f);
    u = (u + 0x7fffu + ((u >> 16) & 1u)) >> 16;   // RNE
    return (unsigned short)u;
}
__device__ __forceinline__ unsigned int pk2(float lo, float hi) {
    return (unsigned int)f2bf(lo) | ((unsigned int)f2bf(hi) << 16);
}

// ---------------- CSR build ----------------

__global__ __launch_bounds__(256) void degree_kernel(const int* __restrict__ ei,
                                                     int* __restrict__ deg,
                                                     int E, int EE) {
    int e = blockIdx.x * 256 + threadIdx.x;
    if (e >= EE) return;
    int d = (e < E) ? ei[E + e] : (e - E);
    atomicAdd(&deg[d], 1);
}

__global__ __launch_bounds__(256) void scan1_kernel(const int* __restrict__ deg,
                                                    int* __restrict__ bsum, int N) {
    __shared__ int part[256];
    int t = threadIdx.x;
    int base = blockIdx.x * SCHUNK + t * SEPT;
    int s = 0;
    if (base + SEPT <= N) {
        int4 a = *(const int4*)&deg[base];
        int4 c = *(const int4*)&deg[base + 4];
        s = a.x + a.y + a.z + a.w + c.x + c.y + c.z + c.w;
    } else {
#pragma unroll
        for (int i = 0; i < SEPT; ++i) {
            int j = base + i;
            if (j < N) s += deg[j];
        }
    }
    part[t] = s;
    __syncthreads();
    for (int d = 128; d > 0; d >>= 1) {
        if (t < d) part[t] += part[t + d];
        __syncthreads();
    }
    if (t == 0) bsum[blockIdx.x] = part[0];
}

__global__ __launch_bounds__(256) void scan2_kernel(int* __restrict__ bsum,
                                                    int* __restrict__ offs,
                                                    int nb, int N) {
    __shared__ int part[256];
    int t = threadIdx.x;
    int v = (t < nb) ? bsum[t] : 0;
    part[t] = v;
    __syncthreads();
    for (int d = 1; d < 256; d <<= 1) {
        int o = (t >= d) ? part[t - d] : 0;
        __syncthreads();
        part[t] += o;
        __syncthreads();
    }
    if (t < nb) bsum[t] = part[t] - v;          // exclusive
    if (t == 255) offs[N] = part[255];          // grand total
}

__global__ __launch_bounds__(256) void scan3_kernel(const int* __restrict__ deg,
                                                    const int* __restrict__ bsum,
                                                    int* __restrict__ offs, int N) {
    __shared__ int part[256];
    int t = threadIdx.x;
    int base = blockIdx.x * SCHUNK + t * SEPT;
    int loc[SEPT];
    int s = 0;
#pragma unroll
    for (int i = 0; i < SEPT; ++i) {
        int j = base + i;
        int d = (j < N) ? deg[j] : 0;
        loc[i] = s;
        s += d;
    }
    part[t] = s;
    __syncthreads();
    for (int d = 1; d < 256; d <<= 1) {
        int o = (t >= d) ? part[t - d] : 0;
        __syncthreads();
        part[t] += o;
        __syncthreads();
    }
    int ex = part[t] - s + bsum[blockIdx.x];
#pragma unroll
    for (int i = 0; i < SEPT; ++i) {
        int j = base + i;
        if (j < N) offs[j] = ex + loc[i];
    }
}

__global__ __launch_bounds__(256) void scatter_kernel(const int* __restrict__ ei,
                                                      const int* __restrict__ offs,
                                                      int* __restrict__ cur,
                                                      int* __restrict__ csr_src,
                                                      int E, int EE) {
    int e = blockIdx.x * 256 + threadIdx.x;
    if (e >= EE) return;
    int s = (e < E) ? ei[e] : (e - E);
    int d = (e < E) ? ei[E + e] : (e - E);
    int pos = offs[d] + atomicAdd(&cur[d], 1);
    csr_src[pos] = s;
}

// ---------------- fused prologue: all weight prep in one launch ----------------
__device__ __forceinline__ void wfrag_body(const float* __restrict__ W,
                                           const float* __restrict__ g,
                                           const float* __restrict__ v,
                                           unsigned short* __restrict__ frag,
                                           int tile, int l) {
    int ct = tile & 15, kt = tile >> 4;
    int c = ct * 16 + (l & 15);
    int k0 = kt * 32 + (l >> 4) * 8;
    float val[8];
#pragma unroll
    for (int j = 0; j < 8; ++j) {
        float s = g[k0 + j] * rsqrtf(v[k0 + j] + BN_EPS);
        val[j] = W[(size_t)(k0 + j) * HID + c] * s;
    }
    uint4 o;
    o.x = pk2(val[0], val[1]);
    o.y = pk2(val[2], val[3]);
    o.z = pk2(val[4], val[5]);
    o.w = pk2(val[6], val[7]);
    *(uint4*)&frag[((size_t)tile * 64 + l) * 8] = o;
}

__global__ __launch_bounds__(256) void prep_kernel(
    const float* __restrict__ W1, const float* __restrict__ bn1_g,
    const float* __restrict__ bn1_b, const float* __restrict__ bn1_m,
    const float* __restrict__ bn1_v,
    const float* __restrict__ W2, const float* __restrict__ bn2_g,
    const float* __restrict__ bn2_b, const float* __restrict__ bn2_m,
    const float* __restrict__ bn2_v,
    const float* __restrict__ g3, const float* __restrict__ b3,
    const float* __restrict__ m3, const float* __restrict__ v3,
    const float* __restrict__ skip_W, const float* __restrict__ skip_b,
    const float* __restrict__ p1_W, const float* __restrict__ p1_b,
    unsigned short* __restrict__ wf1, unsigned short* __restrict__ wf2,
    unsigned short* __restrict__ hf, float* __restrict__ c1,
    float* __restrict__ c2, float* __restrict__ cp) {
    int b = blockIdx.x;
    int tid = threadIdx.x;
    int sub = tid >> 6, l = tid & 63;

    if (b < 8) {
        wfrag_body(W1, bn1_g, bn1_v, wf1, b * 4 + sub, l);
    } else if (b < 40) {
        wfrag_body(W2, bn2_g, bn2_v, wf2, (b - 8) * 4 + sub, l);
    } else if (b < 45) {               // hf: 20 tiles, K=320 ([t|x] concat)
        int tile = (b - 40) * 4 + sub;
        int mt = tile & 1, kt = tile >> 1;
        int j = mt * 16 + (l & 15);
        int k0 = kt * 32 + (l >> 4) * 8;
        float val[8];
#pragma unroll
        for (int jj = 0; jj < 8; ++jj) {
            int c = k0 + jj;
            if (c < HID) {
                float s3 = g3[c] * rsqrtf(v3[c] + BN_EPS);
                val[jj] = s3 * p1_W[c * 32 + j];
            } else {                   // S' = skip_W @ p1_W inline
                float acc = 0.f;
                for (int cc = 0; cc < HID; ++cc)
                    acc = fmaf(skip_W[(size_t)(c - HID) * HID + cc],
                               p1_W[cc * 32 + j], acc);
                val[jj] = acc;
            }
        }
        uint4 o;
        o.x = pk2(val[0], val[1]);
        o.y = pk2(val[2], val[3]);
        o.z = pk2(val[4], val[5]);
        o.w = pk2(val[6], val[7]);
        *(uint4*)&hf[((size_t)tile * 64 + l) * 8] = o;
    } else if (b == 45) {
        float acc = 0.f;
        for (int k = 0; k < 64; ++k) {
            float s = bn1_g[k] * rsqrtf(bn1_v[k] + BN_EPS);
            acc = fmaf(bn1_b[k] - bn1_m[k] * s, W1[(size_t)k * HID + tid], acc);
        }
        c1[tid] = acc;
    } else if (b == 46) {
        float acc = 0.f;
        for (int k = 0; k < HID; ++k) {
            float s = bn2_g[k] * rsqrtf(bn2_v[k] + BN_EPS);
            acc = fmaf(bn2_b[k] - bn2_m[k] * s, W2[(size_t)k * HID + tid], acc);
        }
        c2[tid] = acc;
    } else {
        if (tid < 32) {
            float acc = p1_b[tid];
            for (int c = 0; c < HID; ++c) {
                float s3 = g3[c] * rsqrtf(v3[c] + BN_EPS);
                acc = fmaf(b3[c] - m3[c] * s3 + skip_b[c], p1_W[c * 32 + tid], acc);
            }
            cp[tid] = acc;
        }
    }
}

// ---------------- MFMA GEMM (swapped): D[wcol][node] = W'^T-op x X-op ----------------
// BF16IN: input already bf16 (row-major) -> staging is a straight 16B copy.
template <int K, bool BF16IN>
__global__ __launch_bounds__(256) void gemm_mfma(
    const float* __restrict__ inf, const unsigned short* __restrict__ inb,
    const unsigned short* __restrict__ wfrag, const float* __restrict__ cvec,
    const float* __restrict__ a_src, const float* __restrict__ a_dst,
    unsigned short* __restrict__ h, float* __restrict__ s_src,
    float* __restrict__ s_dst, int N) {
    constexpr int KT = K / 32;
    constexpr int OPR = K / 8;
    __shared__ unsigned short xfrag[KT * 4 * 64 * 8];
    int tid = threadIdx.x;
    int w = tid >> 6, l = tid & 63;
    int gg = l >> 4, li = l & 15;
    int base = blockIdx.x * 64;

    for (int id = tid; id < 64 * OPR; id += 256) {
        int r = id / OPR, o = id % OPR;
        int node = min(base + r, N - 1);
        uint4 pkv;
        if constexpr (BF16IN) {
            pkv = *(const uint4*)&inb[(size_t)node * K + o * 8];
        } else {
            const float* p = &inf[(size_t)node * K + o * 8];
            float4 f0 = *(const float4*)p;
            float4 f1 = *(const float4*)(p + 4);
            pkv.x = pk2(f0.x, f0.y);
            pkv.y = pk2(f0.z, f0.w);
            pkv.z = pk2(f1.x, f1.y);
            pkv.w = pk2(f1.z, f1.w);
        }
        int kt = o >> 2, og = o & 3, nt = r >> 4;
        *(uint4*)&xfrag[(((kt * 4 + nt) * 64) + (r & 15) + 16 * og) * 8] = pkv;
    }
    __syncthreads();

    f32x4 acc[4][4];
#pragma unroll
    for (int mm = 0; mm < 4; ++mm) {
        float4 cv = *(const float4*)&cvec[64 * w + 16 * mm + 4 * gg];
#pragma unroll
        for (int nn = 0; nn < 4; ++nn) {
            acc[mm][nn][0] = cv.x; acc[mm][nn][1] = cv.y;
            acc[mm][nn][2] = cv.z; acc[mm][nn][3] = cv.w;
        }
    }

    for (int ks = 0; ks < KT; ++ks) {
        sv8 a[4], b[4];
#pragma unroll
        for (int mm = 0; mm < 4; ++mm)
            a[mm] = *(const sv8*)&wfrag[((size_t)(ks * 16 + w * 4 + mm) * 64 + l) * 8];
#pragma unroll
        for (int nn = 0; nn < 4; ++nn)
            b[nn] = *(const sv8*)&xfrag[((ks * 4 + nn) * 64 + l) * 8];
#pragma unroll
        for (int mm = 0; mm < 4; ++mm)
#pragma unroll
            for (int nn = 0; nn < 4; ++nn)
                acc[mm][nn] = __builtin_amdgcn_mfma_f32_16x16x32_bf16(
                    a[mm], b[nn], acc[mm][nn], 0, 0, 0);
    }

    float svp[4][2], sdp[4][2];
#pragma unroll
    for (int nn = 0; nn < 4; ++nn) { svp[nn][0]=0.f; svp[nn][1]=0.f; sdp[nn][0]=0.f; sdp[nn][1]=0.f; }

#pragma unroll
    for (int mm = 0; mm < 4; ++mm) {
        int cb = 64 * w + 16 * mm + 4 * gg;
        float4 as4 = *(const float4*)&a_src[cb];
        float4 ad4 = *(const float4*)&a_dst[cb];
        int hp = mm >> 1;
#pragma unroll
        for (int nn = 0; nn < 4; ++nn) {
            f32x4 A = acc[mm][nn];
            svp[nn][hp] += A[0]*as4.x + A[1]*as4.y + A[2]*as4.z + A[3]*as4.w;
            sdp[nn][hp] += A[0]*ad4.x + A[1]*ad4.y + A[2]*ad4.z + A[3]*ad4.w;
            int node = base + 16 * nn + li;
            if (node < N) {
                ushort4 pkv;
                pkv.x = f2bf(A[0]); pkv.y = f2bf(A[1]);
                pkv.z = f2bf(A[2]); pkv.w = f2bf(A[3]);
                *(ushort4*)&h[(size_t)node * HID + cb] = pkv;
            }
        }
    }
#pragma unroll
    for (int nn = 0; nn < 4; ++nn)
#pragma unroll
        for (int hp = 0; hp < 2; ++hp) {
            svp[nn][hp] += __shfl_xor(svp[nn][hp], 16);
            svp[nn][hp] += __shfl_xor(svp[nn][hp], 32);
            sdp[nn][hp] += __shfl_xor(sdp[nn][hp], 16);
            sdp[nn][hp] += __shfl_xor(sdp[nn][hp], 32);
        }
    if (gg == 0) {
#pragma unroll
        for (int nn = 0; nn < 4; ++nn) {
            int node = base + 16 * nn + li;
            if (node < N) {
#pragma unroll
                for (int hp = 0; hp < 2; ++hp) {
                    s_src[node * HEADS + 2 * w + hp] = svp[nn][hp];
                    s_dst[node * HEADS + 2 * w + hp] = sdp[nn][hp];
                }
            }
        }
    }
}

// ---------------- agg: one WAVE per dst node; bf16 output ----------------
// pass A: lane = slot*8 + head; 3-hop head reduce.
// pass B: two 32-lane groups walk alternate edges; lane owns 8 cols (16B loads);
//         groups combined via shfl_xor(32); deferred 1/sum; bf16 packed store.
__global__ __launch_bounds__(256) void agg_kernel(
    const unsigned short* __restrict__ h, const float* __restrict__ s_src,
    const float* __restrict__ s_dst, const int* __restrict__ offs,
    const int* __restrict__ csr_src, const float* __restrict__ bias,
    unsigned short* __restrict__ outp, int N) {
    __shared__ float al_lds[4][WCAP][8];
    __shared__ int   u_lds[4][WCAP];
    __shared__ float mi_lds[4][16];     // [0..7]=max, [8..15]=inv
    int tid = threadIdx.x;
    int w = tid >> 6, l = tid & 63;
    int vtx = blockIdx.x * 4 + w;
    if (vtx >= N) return;               // wave-uniform
    int beg = offs[vtx], end = offs[vtx + 1];
    int deg = end - beg;
    int dc = min(deg, WCAP);

    int headA = l & 7, slot = l >> 3;
    float sdv = s_dst[vtx * HEADS + headA];

    // max pass (+ cache u and raw scores)
    float m = -3.0e38f;
    for (int e = slot; e < deg; e += 8) {
        int u = csr_src[beg + e];
        float sc = lrelu(s_src[u * HEADS + headA] + sdv);
        if (e < WCAP) {
            if (headA == 0) u_lds[w][e] = u;
            al_lds[w][e][headA] = sc;
        }
        m = fmaxf(m, sc);
    }
    m = fmaxf(m, __shfl_xor(m, 8));
    m = fmaxf(m, __shfl_xor(m, 16));
    m = fmaxf(m, __shfl_xor(m, 32));

    // exp+sum pass: one exp per (edge, head); alphas left unnormalized
    float s = 0.f;
    for (int e = slot; e < dc; e += 8) {
        float p = __expf(al_lds[w][e][headA] - m);
        al_lds[w][e][headA] = p;
        s += p;
    }
    for (int e = WCAP + slot; e < deg; e += 8) {   // fallback tail
        int u = csr_src[beg + e];
        s += __expf(lrelu(s_src[u * HEADS + headA] + sdv) - m);
    }
    s += __shfl_xor(s, 8);
    s += __shfl_xor(s, 16);
    s += __shfl_xor(s, 32);
    if (slot == 0) {
        mi_lds[w][headA] = m;
        mi_lds[w][8 + headA] = 1.f / s;
    }
    __builtin_amdgcn_wave_barrier();    // order LDS writes (pass A) vs reads (pass B)

    // pass B
    int grp = l >> 5, gl = l & 31;
    int hd = gl >> 2;                   // cols 8*gl..8*gl+7 are in head gl>>2
    float4 a0 = {0.f, 0.f, 0.f, 0.f};
    float4 a1 = {0.f, 0.f, 0.f, 0.f};
#pragma unroll 2
    for (int e = grp; e < dc; e += 2) {
        int u = u_lds[w][e];
        float al = al_lds[w][e][hd];
        uint4 hv = *(const uint4*)&h[(size_t)u * HID + 8 * gl];
        a0.x = fmaf(al, __uint_as_float(hv.x << 16), a0.x);
        a0.y = fmaf(al, __uint_as_float(hv.x & 0xffff0000u), a0.y);
        a0.z = fmaf(al, __uint_as_float(hv.y << 16), a0.z);
        a0.w = fmaf(al, __uint_as_float(hv.y & 0xffff0000u), a0.w);
        a1.x = fmaf(al, __uint_as_float(hv.z << 16), a1.x);
        a1.y = fmaf(al, __uint_as_float(hv.z & 0xffff0000u), a1.y);
        a1.z = fmaf(al, __uint_as_float(hv.w << 16), a1.z);
        a1.w = fmaf(al, __uint_as_float(hv.w & 0xffff0000u), a1.w);
    }
    if (deg > WCAP) {                   // fallback (never for this graph)
        float mh = mi_lds[w][hd];
        float sdh = s_dst[vtx * HEADS + hd];
        for (int e = WCAP + grp; e < deg; e += 2) {
            int u = csr_src[beg + e];
            float al = __expf(lrelu(s_src[u * HEADS + hd] + sdh) - mh);
            uint4 hv = *(const uint4*)&h[(size_t)u * HID + 8 * gl];
            a0.x = fmaf(al, __uint_as_float(hv.x << 16), a0.x);
            a0.y = fmaf(al, __uint_as_float(hv.x & 0xffff0000u), a0.y);
            a0.z = fmaf(al, __uint_as_float(hv.y << 16), a0.z);
            a0.w = fmaf(al, __uint_as_float(hv.y & 0xffff0000u), a0.w);
            a1.x = fmaf(al, __uint_as_float(hv.z << 16), a1.x);
            a1.y = fmaf(al, __uint_as_float(hv.z & 0xffff0000u), a1.y);
            a1.z = fmaf(al, __uint_as_float(hv.w << 16), a1.z);
            a1.w = fmaf(al, __uint_as_float(hv.w & 0xffff0000u), a1.w);
        }
    }
    // combine groups (lanes l and l^32 hold the same columns)
    a0.x += __shfl_xor(a0.x, 32);
    a0.y += __shfl_xor(a0.y, 32);
    a0.z += __shfl_xor(a0.z, 32);
    a0.w += __shfl_xor(a0.w, 32);
    a1.x += __shfl_xor(a1.x, 32);
    a1.y += __shfl_xor(a1.y, 32);
    a1.z += __shfl_xor(a1.z, 32);
    a1.w += __shfl_xor(a1.w, 32);
    if (grp == 0) {
        float inv = mi_lds[w][8 + hd];
        float4 b0 = *(const float4*)&bias[8 * gl];
        float4 b1 = *(const float4*)&bias[8 * gl + 4];
        float o0 = eluf(a0.x * inv + b0.x);
        float o1 = eluf(a0.y * inv + b0.y);
        float o2 = eluf(a0.z * inv + b0.z);
        float o3 = eluf(a0.w * inv + b0.w);
        float o4 = eluf(a1.x * inv + b1.x);
        float o5 = eluf(a1.y * inv + b1.y);
        float o6 = eluf(a1.z * inv + b1.z);
        float o7 = eluf(a1.w * inv + b1.w);
        uint4 ov;
        ov.x = pk2(o0, o1);
        ov.y = pk2(o2, o3);
        ov.z = pk2(o4, o5);
        ov.w = pk2(o6, o7);
        *(uint4*)&outp[(size_t)vtx * HID + 8 * gl] = ov;
    }
}

// ---------------- head: q = [t|x] @ hfrag + c'; out = relu(q) @ p2_W + p2_b ----------
__global__ __launch_bounds__(256) void final_mfma(
    const unsigned short* __restrict__ t_in, const float* __restrict__ x,
    const unsigned short* __restrict__ hf, const float* __restrict__ cp,
    const float* __restrict__ p2_W, const float* __restrict__ p2_b,
    float* __restrict__ outp, int N) {
    constexpr int KT = 10;
    __shared__ unsigned short xfrag[KT * 4 * 64 * 8];
    int tid = threadIdx.x;
    int w = tid >> 6, l = tid & 63;
    int gg = l >> 4, li = l & 15;
    int base = blockIdx.x * 64;

    for (int id = tid; id < 64 * 40; id += 256) {
        int r = id / 40, o = id % 40;
        int node = min(base + r, N - 1);
        uint4 pkv;
        if (o < 32) {
            pkv = *(const uint4*)&t_in[(size_t)node * HID + o * 8];
        } else {
            const float* p = &x[(size_t)node * 64 + (o - 32) * 8];
            float4 f0 = *(const float4*)p;
            float4 f1 = *(const float4*)(p + 4);
            pkv.x = pk2(f0.x, f0.y);
            pkv.y = pk2(f0.z, f0.w);
            pkv.z = pk2(f1.x, f1.y);
            pkv.w = pk2(f1.z, f1.w);
        }
        int kt = o >> 2, og = o & 3, nt = r >> 4;
        *(uint4*)&xfrag[(((kt * 4 + nt) * 64) + (r & 15) + 16 * og) * 8] = pkv;
    }
    __syncthreads();

    f32x4 acc[2];
#pragma unroll
    for (int mt = 0; mt < 2; ++mt) {
        float4 cv = *(const float4*)&cp[mt * 16 + 4 * gg];
        acc[mt][0] = cv.x; acc[mt][1] = cv.y; acc[mt][2] = cv.z; acc[mt][3] = cv.w;
    }

    for (int kt = 0; kt < KT; ++kt) {
        sv8 b = *(const sv8*)&xfrag[((kt * 4 + w) * 64 + l) * 8];
#pragma unroll
        for (int mt = 0; mt < 2; ++mt) {
            sv8 a = *(const sv8*)&hf[((size_t)(kt * 2 + mt) * 64 + l) * 8];
            acc[mt] = __builtin_amdgcn_mfma_f32_16x16x32_bf16(a, b, acc[mt], 0, 0, 0);
        }
    }

    float po = 0.f;
#pragma unroll
    for (int mt = 0; mt < 2; ++mt) {
        float4 p2v = *(const float4*)&p2_W[mt * 16 + 4 * gg];
        po += fmaxf(acc[mt][0], 0.f) * p2v.x;
        po += fmaxf(acc[mt][1], 0.f) * p2v.y;
        po += fmaxf(acc[mt][2], 0.f) * p2v.z;
        po += fmaxf(acc[mt][3], 0.f) * p2v.w;
    }
    po += __shfl_xor(po, 16);
    po += __shfl_xor(po, 32);
    int node = base + 16 * w + li;
    if (gg == 0 && node < N) outp[node] = po + p2_b[0];
}

// ---------------- launch ----------------

extern "C" void kernel_launch(void* const* d_in, const int* in_sizes, int n_in,
                              void* d_out, int out_size, void* d_ws, size_t ws_size,
                              hipStream_t stream) {
    const float* x      = (const float*)d_in[0];
    const int*   ei     = (const int*)  d_in[1];
    const float* bn1_g  = (const float*)d_in[2];
    const float* bn1_b  = (const float*)d_in[3];
    const float* bn1_m  = (const float*)d_in[4];
    const float* bn1_v  = (const float*)d_in[5];
    const float* W1     = (const float*)d_in[6];
    const float* a1_src = (const float*)d_in[7];
    const float* a1_dst = (const float*)d_in[8];
    const float* b1     = (const float*)d_in[9];
    const float* bn2_g  = (const float*)d_in[10];
    const float* bn2_b  = (const float*)d_in[11];
    const float* bn2_m  = (const float*)d_in[12];
    const float* bn2_v  = (const float*)d_in[13];
    const float* W2     = (const float*)d_in[14];
    const float* a2_src = (const float*)d_in[15];
    const float* a2_dst = (const float*)d_in[16];
    const float* b2     = (const float*)d_in[17];
    const float* bn3_g  = (const float*)d_in[18];
    const float* bn3_b  = (const float*)d_in[19];
    const float* bn3_m  = (const float*)d_in[20];
    const float* bn3_v  = (const float*)d_in[21];
    const float* skip_W = (const float*)d_in[22];
    const float* skip_b = (const float*)d_in[23];
    const float* p1_W   = (const float*)d_in[24];
    const float* p1_b   = (const float*)d_in[25];
    const float* p2_W   = (const float*)d_in[26];
    const float* p2_b   = (const float*)d_in[27];

    int N = in_sizes[0] / 64;
    int E = in_sizes[1] / 2;
    int EE = E + N;

    uintptr_t w = (uintptr_t)d_ws;
    auto carve = [&](size_t bytes) -> void* {
        uintptr_t p = w;
        w += (bytes + 255) & ~(size_t)255;
        return (void*)p;
    };
    int*   deg  = (int*)carve((size_t)N * 4);
    int*   cur  = (int*)carve((size_t)N * 4);
    int*   offs = (int*)carve(((size_t)N + 1) * 4);
    int*   csr  = (int*)carve((size_t)EE * 4);
    int*   bsum = (int*)carve((size_t)256 * 4);
    float* ssrc = (float*)carve((size_t)N * HEADS * 4);
    float* sdst = (float*)carve((size_t)N * HEADS * 4);
    unsigned short* wf1 = (unsigned short*)carve((size_t)2 * 16 * 64 * 8 * 2);
    unsigned short* wf2 = (unsigned short*)carve((size_t)8 * 16 * 64 * 8 * 2);
    unsigned short* hf  = (unsigned short*)carve((size_t)20 * 64 * 8 * 2);
    float* c1   = (float*)carve((size_t)HID * 4);
    float* c2   = (float*)carve((size_t)HID * 4);
    float* cp   = (float*)carve((size_t)32 * 4);
    unsigned short* hbf = (unsigned short*)carve((size_t)N * HID * 2);
    unsigned short* tbuf = (unsigned short*)carve((size_t)N * HID * 2);

    // deg and cur are adjacent carvings -> single memset covers both
    hipMemsetAsync(deg, 0, ((size_t)N * 4 + 255 & ~(size_t)255) + (size_t)N * 4, stream);

    // fused weight prep
    prep_kernel<<<48, 256, 0, stream>>>(
        W1, bn1_g, bn1_b, bn1_m, bn1_v,
        W2, bn2_g, bn2_b, bn2_m, bn2_v,
        bn3_g, bn3_b, bn3_m, bn3_v, skip_W, skip_b, p1_W, p1_b,
        wf1, wf2, hf, c1, c2, cp);

    // CSR (parallel 3-phase scan)
    int eblk = (EE + 255) / 256;
    int nb = (N + SCHUNK - 1) / SCHUNK;
    degree_kernel<<<eblk, 256, 0, stream>>>(ei, deg, E, EE);
    scan1_kernel<<<nb, 256, 0, stream>>>(deg, bsum, N);
    scan2_kernel<<<1, 256, 0, stream>>>(bsum, offs, nb, N);
    scan3_kernel<<<nb, 256, 0, stream>>>(deg, bsum, offs, N);
    scatter_kernel<<<eblk, 256, 0, stream>>>(ei, offs, cur, csr, E, EE);

    int gblk = (N + 63) / 64;
    int ablk = (N + 3) / 4;
    // layer 1
    gemm_mfma<64, false><<<gblk, 256, 0, stream>>>(x, nullptr, wf1, c1,
                                                   a1_src, a1_dst,
                                                   hbf, ssrc, sdst, N);
    agg_kernel<<<ablk, 256, 0, stream>>>(hbf, ssrc, sdst, offs, csr, b1, tbuf, N);

    // layer 2 (bf16 input)
    gemm_mfma<HID, true><<<gblk, 256, 0, stream>>>(nullptr, tbuf, wf2, c2,
                                                   a2_src, a2_dst,
                                                   hbf, ssrc, sdst, N);
    agg_kernel<<<ablk, 256, 0, stream>>>(hbf, ssrc, sdst, offs, csr, b2, tbuf, N);

    // head (fully folded, bf16 t)
    final_mfma<<<gblk, 256, 0, stream>>>(tbuf, x, hf, cp, p2_W, p2_b,
                                         (float*)d_out, N);
}